// Round 4
// baseline (1521.430 us; speedup 1.0000x reference)
//
#include <hip/hip_runtime.h>
#include <math.h>

#define EPSF 1e-8f
#define LN_EPS 1e-5f
#define BL_MARGIN 0.008f   // > 2^-8 hard bound on bf16 cosine-sim error

typedef unsigned int  u32;
typedef unsigned short u16;

// round-to-nearest-even fp32 -> bf16 (finite inputs)
static __device__ inline u16 f2bf(float f) {
    u32 u = __float_as_uint(f);
    u = (u + 0x7FFFu + ((u >> 16) & 1u)) >> 16;
    return (u16)u;
}
static __device__ inline float bf_lo(u32 u) { return __uint_as_float(u << 16); }
static __device__ inline float bf_hi(u32 u) { return __uint_as_float(u & 0xFFFF0000u); }

// ---------------- node kernels ----------------

__global__ __launch_bounds__(256) void node_norm_k(const float* __restrict__ feat,
                                                   float* __restrict__ nrm, int n) {
    int wid  = (blockIdx.x * 256 + threadIdx.x) >> 6;
    int lane = threadIdx.x & 63;
    if (wid >= n) return;
    float2 v = *(const float2*)(feat + (size_t)wid * 128 + lane * 2);
    float s = v.x * v.x + v.y * v.y;
    #pragma unroll
    for (int off = 32; off; off >>= 1) s += __shfl_xor(s, off, 64);
    if (lane == 0) nrm[wid] = fmaxf(sqrtf(s), EPSF);
}

__global__ __launch_bounds__(256) void node_b_k(const float* __restrict__ deg1,
                                                float* __restrict__ dinv1, int n) {
    int i = blockIdx.x * 256 + threadIdx.x;
    if (i >= n) return;
    float d = deg1[i];
    dinv1[i] = (d > 0.0f) ? 1.0f / sqrtf(d) : 0.0f;
}

// cast fp32 features -> bf16 (RTNE); n8 = total elems / 8
__global__ __launch_bounds__(256) void cast_bf_k(const float* __restrict__ in,
                                                 u16* __restrict__ out, int n8) {
    int i = blockIdx.x * 256 + threadIdx.x;
    if (i >= n8) return;
    float4 a = ((const float4*)in)[2 * i];
    float4 b = ((const float4*)in)[2 * i + 1];
    ushort4 p0, p1;
    p0.x = f2bf(a.x); p0.y = f2bf(a.y); p0.z = f2bf(a.z); p0.w = f2bf(a.w);
    p1.x = f2bf(b.x); p1.y = f2bf(b.y); p1.z = f2bf(b.z); p1.w = f2bf(b.w);
    ((ushort4*)out)[2 * i]     = p0;
    ((ushort4*)out)[2 * i + 1] = p1;
}

// ---------------- one-time CSR build ----------------

__global__ __launch_bounds__(256) void count_k(const int* __restrict__ col,
                                               int* __restrict__ cntAll, int ecnt) {
    int e = blockIdx.x * 256 + threadIdx.x;
    if (e < ecnt) atomicAdd(&cntAll[col[e]], 1);
}

__global__ __launch_bounds__(256) void scan1_k(const int* __restrict__ cnt,
    int* __restrict__ colStart, int* __restrict__ bsum, int n) {
    __shared__ int tmp[256];
    int i = blockIdx.x * 256 + threadIdx.x;
    int v = (i < n) ? cnt[i] : 0;
    tmp[threadIdx.x] = v; __syncthreads();
    for (int off = 1; off < 256; off <<= 1) {
        int t = (threadIdx.x >= off) ? tmp[threadIdx.x - off] : 0;
        __syncthreads();
        tmp[threadIdx.x] += t;
        __syncthreads();
    }
    if (i < n) colStart[i] = tmp[threadIdx.x] - v;   // exclusive
    if (threadIdx.x == 255) bsum[blockIdx.x] = tmp[255];
}

__global__ __launch_bounds__(512) void scan2_k(int* __restrict__ bsum, int nb) {
    __shared__ int tmp[512];
    int v = (threadIdx.x < nb) ? bsum[threadIdx.x] : 0;
    tmp[threadIdx.x] = v; __syncthreads();
    for (int off = 1; off < 512; off <<= 1) {
        int t = (threadIdx.x >= off) ? tmp[threadIdx.x - off] : 0;
        __syncthreads();
        tmp[threadIdx.x] += t;
        __syncthreads();
    }
    if (threadIdx.x < nb) bsum[threadIdx.x] = tmp[threadIdx.x] - v;  // exclusive
}

__global__ __launch_bounds__(256) void scan3_k(int* __restrict__ colStart,
    const int* __restrict__ bsum, int n) {
    int i = blockIdx.x * 256 + threadIdx.x;
    if (i < n) colStart[i] += bsum[blockIdx.x];
}

__global__ __launch_bounds__(256) void fill_k(const int* __restrict__ row,
    const int* __restrict__ col, const int* __restrict__ startAll,
    int* __restrict__ cur, int* __restrict__ rowAll, int ecnt) {
    int e = blockIdx.x * 256 + threadIdx.x;
    if (e >= ecnt) return;
    int c = col[e];
    int p = startAll[c] + atomicAdd(&cur[c], 1);
    rowAll[p] = row[e];
}

// ---------------- edge phase A: bf16 cosine sims, 4 edges/wave ----------------
// one wave per col node; 4 edges in flight (16 lanes x 8 bf16 each).
// Borderline edges (|sim-0.1| < BL_MARGIN) deferred to fp32 recheck.
__global__ __launch_bounds__(256) void edge_dot_bf_k(const u32* __restrict__ fbf,
    const int* __restrict__ rowAll, const int* __restrict__ startAll,
    const int* __restrict__ cntAll, const float* __restrict__ nrm,
    float* __restrict__ sims, float* __restrict__ deg1,
    int2* __restrict__ blist, int* __restrict__ blcnt, int n) {
    int wid  = (blockIdx.x * 256 + threadIdx.x) >> 6;
    int lane = threadIdx.x & 63;
    if (wid >= n) return;
    int s0 = startAll[wid], cnt = cntAll[wid];
    int q = lane >> 4, l = lane & 15;
    uint4 fcu = *(const uint4*)(fbf + (size_t)wid * 64 + l * 4);
    float c0 = bf_lo(fcu.x), c1 = bf_hi(fcu.x), c2 = bf_lo(fcu.y), c3 = bf_hi(fcu.y);
    float c4 = bf_lo(fcu.z), c5 = bf_hi(fcu.z), c6 = bf_lo(fcu.w), c7 = bf_hi(fcu.w);
    float nc = nrm[wid];
    for (int jj = 0; jj < cnt; jj += 4) {
        int j = jj + q;
        if (j < cnt) {
            int r = rowAll[s0 + j];
            uint4 fu = *(const uint4*)(fbf + (size_t)r * 64 + l * 4);
            float p = bf_lo(fu.x) * c0 + bf_hi(fu.x) * c1
                    + bf_lo(fu.y) * c2 + bf_hi(fu.y) * c3
                    + bf_lo(fu.z) * c4 + bf_hi(fu.z) * c5
                    + bf_lo(fu.w) * c6 + bf_hi(fu.w) * c7;
            #pragma unroll
            for (int off = 8; off; off >>= 1) p += __shfl_xor(p, off, 64);
            if (l == 0) {
                float sim = p / (nrm[r] * nc);
                if (fabsf(sim - 0.1f) < BL_MARGIN) {
                    int idx = atomicAdd(blcnt, 1);
                    blist[idx] = make_int2(s0 + j, wid);
                } else {
                    float kv = (sim >= 0.1f) ? sim : 0.0f;
                    sims[s0 + j] = kv;
                    if (kv > 0.0f) atomicAdd(&deg1[r], kv);
                }
            }
        }
    }
}

// fp32 recheck of borderline edges: exact keep decision + sim value
__global__ __launch_bounds__(256) void recheck_k(const float* __restrict__ feat,
    const int* __restrict__ rowAll, const int2* __restrict__ blist,
    const int* __restrict__ blcnt, const float* __restrict__ nrm,
    float* __restrict__ sims, float* __restrict__ deg1) {
    int tot = *blcnt;
    int gid = blockIdx.x * 256 + threadIdx.x;
    int stride = (int)gridDim.x * 8;       // edges per grid pass (256/32 per block)
    int l = gid & 31;
    for (int e = gid >> 5; e < tot; e += stride) {
        int2 b = blist[e];
        int pos = b.x, c = b.y;
        int r = rowAll[pos];
        float4 fa = *(const float4*)(feat + (size_t)r * 128 + l * 4);
        float4 fb = *(const float4*)(feat + (size_t)c * 128 + l * 4);
        float s = fa.x * fb.x + fa.y * fb.y + fa.z * fb.z + fa.w * fb.w;
        #pragma unroll
        for (int off = 16; off; off >>= 1) s += __shfl_xor(s, off, 64);
        if (l == 0) {
            float sim = s / (nrm[r] * nrm[c]);
            float kv = (sim >= 0.1f) ? sim : 0.0f;
            sims[pos] = kv;
            if (kv > 0.0f) atomicAdd(&deg1[r], kv);
        }
    }
}

// ---------------- edge phase B: vals + in-wave deg2 + compaction ----------------
__global__ __launch_bounds__(256) void edge_c_csr_k(const float* __restrict__ sims,
    const int* __restrict__ rowAll, const int* __restrict__ startAll,
    const int* __restrict__ cntAll, const float* __restrict__ dinv1,
    int2* __restrict__ kv, int* __restrict__ cntK, float* __restrict__ dinv2,
    float* __restrict__ cself, int n) {
    int wid  = (blockIdx.x * 256 + threadIdx.x) >> 6;
    int lane = threadIdx.x & 63;
    if (wid >= n) return;
    int s0 = startAll[wid], cnt = cntAll[wid];
    float d1c = dinv1[wid];
    float vsum = 0.0f; int kc = 0;
    for (int jj = 0; jj < cnt; jj += 64) {
        int j = jj + lane;
        bool keep = false; int r = 0; float v = 0.0f;
        if (j < cnt) {
            float s = sims[s0 + j];
            if (s > 0.0f) { r = rowAll[s0 + j]; v = expf(dinv1[r] * s * d1c); keep = true; }
        }
        unsigned long long m = __ballot(keep ? 1 : 0);
        if (keep) {
            int pre = __popcll(m & ((1ull << lane) - 1ull));
            int2 pk; pk.x = r; pk.y = __float_as_int(v);
            kv[s0 + kc + pre] = pk;
            vsum += v;
        }
        kc += __popcll(m);
    }
    #pragma unroll
    for (int off = 32; off; off >>= 1) vsum += __shfl_xor(vsum, off, 64);
    if (lane == 0) {
        float ws_ = expf(1.0f / ((float)kc + 1.0f));   // self-loop weight
        float dg = ws_ + vsum;                         // always > 0
        float di = 1.0f / sqrtf(dg);
        dinv2[wid] = di;
        cself[wid] = di * ws_;      // self term uses dinv2-scaled h, so one di here
        cntK[wid]  = kc;
    }
}

// ---------------- GEMMs (K=128), output scaled by dinv2[n] ----------------

__global__ __launch_bounds__(256) void gemm128_k(const float* __restrict__ A,
    const float* __restrict__ W, const float* __restrict__ scale,
    float* __restrict__ out, int n) {
    __shared__ float Ws[128 * 128];
    for (int i = threadIdx.x; i < 128 * 128 / 4; i += 256)
        ((float4*)Ws)[i] = ((const float4*)W)[i];
    __syncthreads();
    int nid = blockIdx.x * 8 + (int)(threadIdx.x >> 5);
    if (nid >= n) return;
    int dbase = (threadIdx.x & 31) * 4;
    const float4* a = (const float4*)(A + (size_t)nid * 128);
    float ax = 0.f, ay = 0.f, az = 0.f, aw = 0.f;
    #pragma unroll 4
    for (int k4 = 0; k4 < 32; ++k4) {
        float4 av = a[k4];
        const float* wr = Ws + (k4 * 4) * 128 + dbase;
        float4 w0 = *(const float4*)(wr);
        float4 w1 = *(const float4*)(wr + 128);
        float4 w2 = *(const float4*)(wr + 256);
        float4 w3 = *(const float4*)(wr + 384);
        ax += av.x * w0.x; ay += av.x * w0.y; az += av.x * w0.z; aw += av.x * w0.w;
        ax += av.y * w1.x; ay += av.y * w1.y; az += av.y * w1.z; aw += av.y * w1.w;
        ax += av.z * w2.x; ay += av.z * w2.y; az += av.z * w2.z; aw += av.z * w2.w;
        ax += av.w * w3.x; ay += av.w * w3.y; az += av.w * w3.z; aw += av.w * w3.w;
    }
    float sc = scale[nid];
    float4 r; r.x = ax * sc; r.y = ay * sc; r.z = az * sc; r.w = aw * sc;
    *(float4*)(out + (size_t)nid * 128 + dbase) = r;
}

// DOUT=64 variant, bf16 output
__global__ __launch_bounds__(256) void gemm64_bf_k(const float* __restrict__ A,
    const float* __restrict__ W, const float* __restrict__ scale,
    u16* __restrict__ outbf, int n) {
    __shared__ float Ws[128 * 64];
    for (int i = threadIdx.x; i < 128 * 64 / 4; i += 256)
        ((float4*)Ws)[i] = ((const float4*)W)[i];
    __syncthreads();
    int nid = blockIdx.x * 16 + (int)(threadIdx.x >> 4);
    if (nid >= n) return;
    int dbase = (threadIdx.x & 15) * 4;
    const float4* a = (const float4*)(A + (size_t)nid * 128);
    float ax = 0.f, ay = 0.f, az = 0.f, aw = 0.f;
    #pragma unroll 4
    for (int k4 = 0; k4 < 32; ++k4) {
        float4 av = a[k4];
        const float* wr = Ws + (k4 * 4) * 64 + dbase;
        float4 w0 = *(const float4*)(wr);
        float4 w1 = *(const float4*)(wr + 64);
        float4 w2 = *(const float4*)(wr + 128);
        float4 w3 = *(const float4*)(wr + 192);
        ax += av.x * w0.x; ay += av.x * w0.y; az += av.x * w0.z; aw += av.x * w0.w;
        ax += av.y * w1.x; ay += av.y * w1.y; az += av.y * w1.z; aw += av.y * w1.w;
        ax += av.z * w2.x; ay += av.z * w2.y; az += av.z * w2.z; aw += av.z * w2.w;
        ax += av.w * w3.x; ay += av.w * w3.y; az += av.w * w3.z; aw += av.w * w3.w;
    }
    float sc = scale[nid];
    ushort4 r; r.x = f2bf(ax * sc); r.y = f2bf(ay * sc);
    r.z = f2bf(az * sc); r.w = f2bf(aw * sc);
    *(ushort4*)(outbf + (size_t)nid * 64 + dbase) = r;
}

// ---------------- fused gather epilogues ----------------

// layer 1: x = dinv2[c]*sum(val*hs[row]) + cself*hs[c] + bias; LN; ReLU
// writes h2 (fp32) and h2bf (bf16, for layer-2 sims)
__global__ __launch_bounds__(256) void gather_ln_k(const float* __restrict__ hs,
    const int2* __restrict__ kv, const int* __restrict__ startAll,
    const int* __restrict__ cntK, const float* __restrict__ dinv2,
    const float* __restrict__ cself, const float* __restrict__ bias,
    const float* __restrict__ g, const float* __restrict__ bln,
    float* __restrict__ outbuf, u16* __restrict__ outbf, int n) {
    int wid  = (blockIdx.x * 256 + threadIdx.x) >> 6;
    int lane = threadIdx.x & 63;
    if (wid >= n) return;
    int s0 = startAll[wid], k = cntK[wid];
    float a0 = 0.f, a1 = 0.f;
    int j = 0;
    for (; j + 1 < k; j += 2) {
        int2 p0 = kv[s0 + j], p1 = kv[s0 + j + 1];
        float2 h0 = *(const float2*)(hs + (size_t)p0.x * 128 + lane * 2);
        float2 h1 = *(const float2*)(hs + (size_t)p1.x * 128 + lane * 2);
        float v0 = __int_as_float(p0.y), v1 = __int_as_float(p1.y);
        a0 += v0 * h0.x + v1 * h1.x;
        a1 += v0 * h0.y + v1 * h1.y;
    }
    if (j < k) {
        int2 p0 = kv[s0 + j];
        float2 h0 = *(const float2*)(hs + (size_t)p0.x * 128 + lane * 2);
        float v0 = __int_as_float(p0.y);
        a0 += v0 * h0.x; a1 += v0 * h0.y;
    }
    float di = dinv2[wid], cs = cself[wid];
    float2 hsv = *(const float2*)(hs + (size_t)wid * 128 + lane * 2);
    float2 vb  = *(const float2*)(bias + lane * 2);
    float x0 = di * a0 + cs * hsv.x + vb.x;
    float x1 = di * a1 + cs * hsv.y + vb.y;
    float s = x0 + x1;
    #pragma unroll
    for (int off = 32; off; off >>= 1) s += __shfl_xor(s, off, 64);
    float mu = s * (1.0f / 128.0f);
    float d0 = x0 - mu, d1 = x1 - mu;
    float vv = d0 * d0 + d1 * d1;
    #pragma unroll
    for (int off = 32; off; off >>= 1) vv += __shfl_xor(vv, off, 64);
    float rstd = 1.0f / sqrtf(vv * (1.0f / 128.0f) + LN_EPS);
    float2 vg  = *(const float2*)(g + lane * 2);
    float2 vbl = *(const float2*)(bln + lane * 2);
    float y0 = fmaxf(d0 * rstd * vg.x + vbl.x, 0.0f);
    float y1 = fmaxf(d1 * rstd * vg.y + vbl.y, 0.0f);
    *(float2*)(outbuf + (size_t)wid * 128 + lane * 2) = make_float2(y0, y1);
    ushort2 ob; ob.x = f2bf(y0); ob.y = f2bf(y1);
    *(ushort2*)(outbf + (size_t)wid * 128 + lane * 2) = ob;
}

// layer 2: v = dinv2[c]*sum(val*g2s[row]) + cself*g2s[c] + b2; log_softmax
// g2s is bf16 (pre-scaled by dinv2[row])
__global__ __launch_bounds__(256) void gather_lsm_bf_k(const u16* __restrict__ g2s,
    const int2* __restrict__ kv, const int* __restrict__ startAll,
    const int* __restrict__ cntK, const float* __restrict__ dinv2,
    const float* __restrict__ cself, const float* __restrict__ b2,
    float* __restrict__ out, int n) {
    int wid  = (blockIdx.x * 256 + threadIdx.x) >> 6;
    int lane = threadIdx.x & 63;
    if (wid >= n) return;
    int s0 = startAll[wid], k = cntK[wid];
    float acc = 0.f;
    int j = 0;
    for (; j + 1 < k; j += 2) {
        int2 p0 = kv[s0 + j], p1 = kv[s0 + j + 1];
        float g0 = __uint_as_float((u32)g2s[(size_t)p0.x * 64 + lane] << 16);
        float g1 = __uint_as_float((u32)g2s[(size_t)p1.x * 64 + lane] << 16);
        acc += __int_as_float(p0.y) * g0 + __int_as_float(p1.y) * g1;
    }
    if (j < k) {
        int2 p0 = kv[s0 + j];
        float g0 = __uint_as_float((u32)g2s[(size_t)p0.x * 64 + lane] << 16);
        acc += __int_as_float(p0.y) * g0;
    }
    float gs = __uint_as_float((u32)g2s[(size_t)wid * 64 + lane] << 16);
    float v = dinv2[wid] * acc + cself[wid] * gs + b2[lane];
    float m = v;
    #pragma unroll
    for (int off = 32; off; off >>= 1) m = fmaxf(m, __shfl_xor(m, off, 64));
    float e = expf(v - m);
    float s = e;
    #pragma unroll
    for (int off = 32; off; off >>= 1) s += __shfl_xor(s, off, 64);
    out[(size_t)wid * 64 + lane] = v - m - logf(s);
}

// ---------------- launch ----------------

extern "C" void kernel_launch(void* const* d_in, const int* in_sizes, int n_in,
                              void* d_out, int out_size, void* d_ws, size_t ws_size,
                              hipStream_t stream) {
    (void)n_in; (void)out_size; (void)ws_size;
    const float* x   = (const float*)d_in[0];
    const int*   row = (const int*)d_in[1];
    const int*   col = (const int*)d_in[2];
    const float* W1  = (const float*)d_in[3];
    const float* b1  = (const float*)d_in[4];
    const float* lng = (const float*)d_in[5];
    const float* lnb = (const float*)d_in[6];
    const float* W2  = (const float*)d_in[7];
    const float* b2  = (const float*)d_in[8];
    float* out = (float*)d_out;

    const int N = in_sizes[0] / 128;
    const int E = in_sizes[1];

    int*   cntAll   = (int*)d_ws;
    int*   startAll = cntAll + N;
    int*   bsum     = startAll + N;            // 512 ints
    float* nrm      = (float*)(bsum + 512);
    int*   blcnt    = (int*)(nrm + N);         // ---- zero region: blcnt(4) + deg1[N]
    float* deg1     = (float*)(blcnt + 4);
    float* dinv1    = deg1 + N;
    float* dinv2    = dinv1 + N;
    float* cself    = dinv2 + N;
    int*   cntK     = (int*)(cself + N);       // CSR-build cursor, then kept counts
    int*   rowAll   = cntK + N;                // [E]
    int2*  kvp      = (int2*)(rowAll + E);     // [E]: borderline list, then packed (row,val)
    u32*   fbf      = (u32*)(kvp + E);         // [64N] u32 = [128N] bf16; reused as h2bf
    u16*   g2sbf    = (u16*)(fbf + (size_t)64 * N);  // [64N] bf16
    float* big      = (float*)(g2sbf + (size_t)64 * N);
    float* sims     = big;                     // [E]  (dead before hs is written)
    float* hs       = big;                     // [128N] layer-1 scaled h
    float* h2       = big + (size_t)128 * N;   // [128N] layer-1 output (persists)

    const int nodeBlocks = (N + 255) / 256;
    const int waveBlocks = (N + 3) / 4;
    const int edgeBlocks = (E + 255) / 256;
    const int scanBlocks = nodeBlocks;         // <= 512 for N <= 131072

    // ---- one-time CSR build (shared by both layers) ----
    hipMemsetAsync(cntAll, 0, (size_t)N * sizeof(int), stream);
    count_k<<<edgeBlocks, 256, 0, stream>>>(col, cntAll, E);
    scan1_k<<<scanBlocks, 256, 0, stream>>>(cntAll, startAll, bsum, N);
    scan2_k<<<1, 512, 0, stream>>>(bsum, scanBlocks);
    scan3_k<<<scanBlocks, 256, 0, stream>>>(startAll, bsum, N);
    hipMemsetAsync(cntK, 0, (size_t)N * sizeof(int), stream);
    fill_k<<<edgeBlocks, 256, 0, stream>>>(row, col, startAll, cntK, rowAll, E);

    // ================= layer 1 =================
    hipMemsetAsync(blcnt, 0, (4 + (size_t)N) * sizeof(int), stream);
    cast_bf_k<<<(N * 16 + 255) / 256, 256, 0, stream>>>(x, (u16*)fbf, N * 16);
    node_norm_k<<<waveBlocks, 256, 0, stream>>>(x, nrm, N);
    edge_dot_bf_k<<<waveBlocks, 256, 0, stream>>>(fbf, rowAll, startAll, cntAll, nrm,
                                                  sims, deg1, kvp, blcnt, N);
    recheck_k<<<1024, 256, 0, stream>>>(x, rowAll, kvp, blcnt, nrm, sims, deg1);
    node_b_k<<<nodeBlocks, 256, 0, stream>>>(deg1, dinv1, N);
    edge_c_csr_k<<<waveBlocks, 256, 0, stream>>>(sims, rowAll, startAll, cntAll, dinv1,
                                                 kvp, cntK, dinv2, cself, N);
    gemm128_k<<<(N + 7) / 8, 256, 0, stream>>>(x, W1, dinv2, hs, N);
    gather_ln_k<<<waveBlocks, 256, 0, stream>>>(hs, kvp, startAll, cntK, dinv2, cself,
                                                b1, lng, lnb, h2, (u16*)fbf, N);

    // ================= layer 2 =================
    hipMemsetAsync(blcnt, 0, (4 + (size_t)N) * sizeof(int), stream);
    node_norm_k<<<waveBlocks, 256, 0, stream>>>(h2, nrm, N);
    edge_dot_bf_k<<<waveBlocks, 256, 0, stream>>>(fbf, rowAll, startAll, cntAll, nrm,
                                                  sims, deg1, kvp, blcnt, N);
    recheck_k<<<1024, 256, 0, stream>>>(h2, rowAll, kvp, blcnt, nrm, sims, deg1);
    node_b_k<<<nodeBlocks, 256, 0, stream>>>(deg1, dinv1, N);
    edge_c_csr_k<<<waveBlocks, 256, 0, stream>>>(sims, rowAll, startAll, cntAll, dinv1,
                                                 kvp, cntK, dinv2, cself, N);
    gemm64_bf_k<<<(N + 15) / 16, 256, 0, stream>>>(h2, W2, dinv2, g2sbf, N);
    gather_lsm_bf_k<<<waveBlocks, 256, 0, stream>>>(g2sbf, kvp, startAll, cntK, dinv2,
                                                    cself, b2, out, N);
}

// Round 5
// 877.155 us; speedup vs baseline: 1.7345x; 1.7345x over previous
//
#include <hip/hip_runtime.h>
#include <math.h>

#define EPSF 1e-8f
#define LN_EPS 1e-5f
#define BL_MARGIN 0.008f   // > 2^-8 hard bound on bf16 cosine-sim error

typedef unsigned int  u32;
typedef unsigned short u16;

// round-to-nearest-even fp32 -> bf16 (finite inputs)
static __device__ inline u16 f2bf(float f) {
    u32 u = __float_as_uint(f);
    u = (u + 0x7FFFu + ((u >> 16) & 1u)) >> 16;
    return (u16)u;
}
static __device__ inline float bf_lo(u32 u) { return __uint_as_float(u << 16); }
static __device__ inline float bf_hi(u32 u) { return __uint_as_float(u & 0xFFFF0000u); }

// ---------------- node kernels ----------------

__global__ __launch_bounds__(256) void node_norm_k(const float* __restrict__ feat,
                                                   float* __restrict__ nrm, int n) {
    int wid  = (blockIdx.x * 256 + threadIdx.x) >> 6;
    int lane = threadIdx.x & 63;
    if (wid >= n) return;
    float2 v = *(const float2*)(feat + (size_t)wid * 128 + lane * 2);
    float s = v.x * v.x + v.y * v.y;
    #pragma unroll
    for (int off = 32; off; off >>= 1) s += __shfl_xor(s, off, 64);
    if (lane == 0) nrm[wid] = fmaxf(sqrtf(s), EPSF);
}

__global__ __launch_bounds__(256) void node_b_k(const float* __restrict__ deg1,
                                                float* __restrict__ dinv1, int n) {
    int i = blockIdx.x * 256 + threadIdx.x;
    if (i >= n) return;
    float d = deg1[i];
    dinv1[i] = (d > 0.0f) ? 1.0f / sqrtf(d) : 0.0f;
}

// cast fp32 features -> bf16 (RTNE); n8 = total elems / 8
__global__ __launch_bounds__(256) void cast_bf_k(const float* __restrict__ in,
                                                 u16* __restrict__ out, int n8) {
    int i = blockIdx.x * 256 + threadIdx.x;
    if (i >= n8) return;
    float4 a = ((const float4*)in)[2 * i];
    float4 b = ((const float4*)in)[2 * i + 1];
    ushort4 p0, p1;
    p0.x = f2bf(a.x); p0.y = f2bf(a.y); p0.z = f2bf(a.z); p0.w = f2bf(a.w);
    p1.x = f2bf(b.x); p1.y = f2bf(b.y); p1.z = f2bf(b.z); p1.w = f2bf(b.w);
    ((ushort4*)out)[2 * i]     = p0;
    ((ushort4*)out)[2 * i + 1] = p1;
}

// ---------------- one-time CSR build ----------------

__global__ __launch_bounds__(256) void count_k(const int* __restrict__ col,
                                               int* __restrict__ cntAll, int ecnt) {
    int e = blockIdx.x * 256 + threadIdx.x;
    if (e < ecnt) atomicAdd(&cntAll[col[e]], 1);
}

__global__ __launch_bounds__(256) void scan1_k(const int* __restrict__ cnt,
    int* __restrict__ colStart, int* __restrict__ bsum, int n) {
    __shared__ int tmp[256];
    int i = blockIdx.x * 256 + threadIdx.x;
    int v = (i < n) ? cnt[i] : 0;
    tmp[threadIdx.x] = v; __syncthreads();
    for (int off = 1; off < 256; off <<= 1) {
        int t = (threadIdx.x >= off) ? tmp[threadIdx.x - off] : 0;
        __syncthreads();
        tmp[threadIdx.x] += t;
        __syncthreads();
    }
    if (i < n) colStart[i] = tmp[threadIdx.x] - v;   // exclusive
    if (threadIdx.x == 255) bsum[blockIdx.x] = tmp[255];
}

__global__ __launch_bounds__(512) void scan2_k(int* __restrict__ bsum, int nb) {
    __shared__ int tmp[512];
    int v = (threadIdx.x < nb) ? bsum[threadIdx.x] : 0;
    tmp[threadIdx.x] = v; __syncthreads();
    for (int off = 1; off < 512; off <<= 1) {
        int t = (threadIdx.x >= off) ? tmp[threadIdx.x - off] : 0;
        __syncthreads();
        tmp[threadIdx.x] += t;
        __syncthreads();
    }
    if (threadIdx.x < nb) bsum[threadIdx.x] = tmp[threadIdx.x] - v;  // exclusive
}

__global__ __launch_bounds__(256) void scan3_k(int* __restrict__ colStart,
    const int* __restrict__ bsum, int n) {
    int i = blockIdx.x * 256 + threadIdx.x;
    if (i < n) colStart[i] += bsum[blockIdx.x];
}

__global__ __launch_bounds__(256) void fill_k(const int* __restrict__ row,
    const int* __restrict__ col, const int* __restrict__ startAll,
    int* __restrict__ cur, int* __restrict__ rowAll, int ecnt) {
    int e = blockIdx.x * 256 + threadIdx.x;
    if (e >= ecnt) return;
    int c = col[e];
    int p = startAll[c] + atomicAdd(&cur[c], 1);
    rowAll[p] = row[e];
}

// ---------------- edge phase A: bf16 cosine sims, 4 edges/wave ----------------
// one wave per col node; 4 edges in flight (16 lanes x 8 bf16 each).
// Borderline edges (|sim-0.1| < BL_MARGIN) recomputed INLINE in fp32 — no global
// counter/list (single-address atomic in the hot loop serialized the whole kernel
// in round 4: vmcnt is FIFO, every wave convoyed behind one L2 line).
__global__ __launch_bounds__(256) void edge_dot_bf_k(const u32* __restrict__ fbf,
    const float* __restrict__ feat32,
    const int* __restrict__ rowAll, const int* __restrict__ startAll,
    const int* __restrict__ cntAll, const float* __restrict__ nrm,
    float* __restrict__ sims, float* __restrict__ deg1, int n) {
    int wid  = (blockIdx.x * 256 + threadIdx.x) >> 6;
    int lane = threadIdx.x & 63;
    if (wid >= n) return;
    int s0 = startAll[wid], cnt = cntAll[wid];
    int q = lane >> 4, l = lane & 15;
    uint4 fcu = *(const uint4*)(fbf + (size_t)wid * 64 + l * 4);
    float c0 = bf_lo(fcu.x), c1 = bf_hi(fcu.x), c2 = bf_lo(fcu.y), c3 = bf_hi(fcu.y);
    float c4 = bf_lo(fcu.z), c5 = bf_hi(fcu.z), c6 = bf_lo(fcu.w), c7 = bf_hi(fcu.w);
    float nc = nrm[wid];
    for (int jj = 0; jj < cnt; jj += 4) {
        int j = jj + q;
        if (j < cnt) {
            int r = rowAll[s0 + j];
            uint4 fu = *(const uint4*)(fbf + (size_t)r * 64 + l * 4);
            float p = bf_lo(fu.x) * c0 + bf_hi(fu.x) * c1
                    + bf_lo(fu.y) * c2 + bf_hi(fu.y) * c3
                    + bf_lo(fu.z) * c4 + bf_hi(fu.z) * c5
                    + bf_lo(fu.w) * c6 + bf_hi(fu.w) * c7;
            #pragma unroll
            for (int off = 8; off; off >>= 1) p += __shfl_xor(p, off, 64);
            float rn = 1.0f / (nrm[r] * nc);
            float sim = p * rn;
            if (fabsf(sim - 0.1f) < BL_MARGIN) {
                // exact fp32 recompute of this edge (16 lanes x 8 floats/endpoint)
                const float4* fr = (const float4*)(feat32 + (size_t)r * 128);
                const float4* fc = (const float4*)(feat32 + (size_t)wid * 128);
                float4 a0 = fr[l * 2], a1 = fr[l * 2 + 1];
                float4 b0 = fc[l * 2], b1 = fc[l * 2 + 1];
                float s2 = a0.x * b0.x + a0.y * b0.y + a0.z * b0.z + a0.w * b0.w
                         + a1.x * b1.x + a1.y * b1.y + a1.z * b1.z + a1.w * b1.w;
                #pragma unroll
                for (int off = 8; off; off >>= 1) s2 += __shfl_xor(s2, off, 64);
                sim = s2 * rn;
            }
            float kv = (sim >= 0.1f) ? sim : 0.0f;
            if (l == 0) {
                sims[s0 + j] = kv;
                if (kv > 0.0f) atomicAdd(&deg1[r], kv);
            }
        }
    }
}

// ---------------- edge phase B: vals + in-wave deg2 + compaction ----------------
__global__ __launch_bounds__(256) void edge_c_csr_k(const float* __restrict__ sims,
    const int* __restrict__ rowAll, const int* __restrict__ startAll,
    const int* __restrict__ cntAll, const float* __restrict__ dinv1,
    int2* __restrict__ kv, int* __restrict__ cntK, float* __restrict__ dinv2,
    float* __restrict__ cself, int n) {
    int wid  = (blockIdx.x * 256 + threadIdx.x) >> 6;
    int lane = threadIdx.x & 63;
    if (wid >= n) return;
    int s0 = startAll[wid], cnt = cntAll[wid];
    float d1c = dinv1[wid];
    float vsum = 0.0f; int kc = 0;
    for (int jj = 0; jj < cnt; jj += 64) {
        int j = jj + lane;
        bool keep = false; int r = 0; float v = 0.0f;
        if (j < cnt) {
            float s = sims[s0 + j];
            if (s > 0.0f) { r = rowAll[s0 + j]; v = expf(dinv1[r] * s * d1c); keep = true; }
        }
        unsigned long long m = __ballot(keep ? 1 : 0);
        if (keep) {
            int pre = __popcll(m & ((1ull << lane) - 1ull));
            int2 pk; pk.x = r; pk.y = __float_as_int(v);
            kv[s0 + kc + pre] = pk;
            vsum += v;
        }
        kc += __popcll(m);
    }
    #pragma unroll
    for (int off = 32; off; off >>= 1) vsum += __shfl_xor(vsum, off, 64);
    if (lane == 0) {
        float ws_ = expf(1.0f / ((float)kc + 1.0f));   // self-loop weight
        float dg = ws_ + vsum;                         // always > 0
        float di = 1.0f / sqrtf(dg);
        dinv2[wid] = di;
        cself[wid] = di * ws_;      // self term uses dinv2-scaled h, so one di here
        cntK[wid]  = kc;
    }
}

// ---------------- GEMMs (K=128), output scaled by dinv2[n] ----------------

__global__ __launch_bounds__(256) void gemm128_k(const float* __restrict__ A,
    const float* __restrict__ W, const float* __restrict__ scale,
    float* __restrict__ out, int n) {
    __shared__ float Ws[128 * 128];
    for (int i = threadIdx.x; i < 128 * 128 / 4; i += 256)
        ((float4*)Ws)[i] = ((const float4*)W)[i];
    __syncthreads();
    int nid = blockIdx.x * 8 + (int)(threadIdx.x >> 5);
    if (nid >= n) return;
    int dbase = (threadIdx.x & 31) * 4;
    const float4* a = (const float4*)(A + (size_t)nid * 128);
    float ax = 0.f, ay = 0.f, az = 0.f, aw = 0.f;
    #pragma unroll 4
    for (int k4 = 0; k4 < 32; ++k4) {
        float4 av = a[k4];
        const float* wr = Ws + (k4 * 4) * 128 + dbase;
        float4 w0 = *(const float4*)(wr);
        float4 w1 = *(const float4*)(wr + 128);
        float4 w2 = *(const float4*)(wr + 256);
        float4 w3 = *(const float4*)(wr + 384);
        ax += av.x * w0.x; ay += av.x * w0.y; az += av.x * w0.z; aw += av.x * w0.w;
        ax += av.y * w1.x; ay += av.y * w1.y; az += av.y * w1.z; aw += av.y * w1.w;
        ax += av.z * w2.x; ay += av.z * w2.y; az += av.z * w2.z; aw += av.z * w2.w;
        ax += av.w * w3.x; ay += av.w * w3.y; az += av.w * w3.z; aw += av.w * w3.w;
    }
    float sc = scale[nid];
    float4 r; r.x = ax * sc; r.y = ay * sc; r.z = az * sc; r.w = aw * sc;
    *(float4*)(out + (size_t)nid * 128 + dbase) = r;
}

// DOUT=64 variant, bf16 output
__global__ __launch_bounds__(256) void gemm64_bf_k(const float* __restrict__ A,
    const float* __restrict__ W, const float* __restrict__ scale,
    u16* __restrict__ outbf, int n) {
    __shared__ float Ws[128 * 64];
    for (int i = threadIdx.x; i < 128 * 64 / 4; i += 256)
        ((float4*)Ws)[i] = ((const float4*)W)[i];
    __syncthreads();
    int nid = blockIdx.x * 16 + (int)(threadIdx.x >> 4);
    if (nid >= n) return;
    int dbase = (threadIdx.x & 15) * 4;
    const float4* a = (const float4*)(A + (size_t)nid * 128);
    float ax = 0.f, ay = 0.f, az = 0.f, aw = 0.f;
    #pragma unroll 4
    for (int k4 = 0; k4 < 32; ++k4) {
        float4 av = a[k4];
        const float* wr = Ws + (k4 * 4) * 64 + dbase;
        float4 w0 = *(const float4*)(wr);
        float4 w1 = *(const float4*)(wr + 64);
        float4 w2 = *(const float4*)(wr + 128);
        float4 w3 = *(const float4*)(wr + 192);
        ax += av.x * w0.x; ay += av.x * w0.y; az += av.x * w0.z; aw += av.x * w0.w;
        ax += av.y * w1.x; ay += av.y * w1.y; az += av.y * w1.z; aw += av.y * w1.w;
        ax += av.z * w2.x; ay += av.z * w2.y; az += av.z * w2.z; aw += av.z * w2.w;
        ax += av.w * w3.x; ay += av.w * w3.y; az += av.w * w3.z; aw += av.w * w3.w;
    }
    float sc = scale[nid];
    ushort4 r; r.x = f2bf(ax * sc); r.y = f2bf(ay * sc);
    r.z = f2bf(az * sc); r.w = f2bf(aw * sc);
    *(ushort4*)(outbf + (size_t)nid * 64 + dbase) = r;
}

// ---------------- fused gather epilogues ----------------

// layer 1: x = dinv2[c]*sum(val*hs[row]) + cself*hs[c] + bias; LN; ReLU
// writes h2 (fp32) and h2bf (bf16, for layer-2 sims)
__global__ __launch_bounds__(256) void gather_ln_k(const float* __restrict__ hs,
    const int2* __restrict__ kv, const int* __restrict__ startAll,
    const int* __restrict__ cntK, const float* __restrict__ dinv2,
    const float* __restrict__ cself, const float* __restrict__ bias,
    const float* __restrict__ g, const float* __restrict__ bln,
    float* __restrict__ outbuf, u16* __restrict__ outbf, int n) {
    int wid  = (blockIdx.x * 256 + threadIdx.x) >> 6;
    int lane = threadIdx.x & 63;
    if (wid >= n) return;
    int s0 = startAll[wid], k = cntK[wid];
    float a0 = 0.f, a1 = 0.f;
    int j = 0;
    for (; j + 1 < k; j += 2) {
        int2 p0 = kv[s0 + j], p1 = kv[s0 + j + 1];
        float2 h0 = *(const float2*)(hs + (size_t)p0.x * 128 + lane * 2);
        float2 h1 = *(const float2*)(hs + (size_t)p1.x * 128 + lane * 2);
        float v0 = __int_as_float(p0.y), v1 = __int_as_float(p1.y);
        a0 += v0 * h0.x + v1 * h1.x;
        a1 += v0 * h0.y + v1 * h1.y;
    }
    if (j < k) {
        int2 p0 = kv[s0 + j];
        float2 h0 = *(const float2*)(hs + (size_t)p0.x * 128 + lane * 2);
        float v0 = __int_as_float(p0.y);
        a0 += v0 * h0.x; a1 += v0 * h0.y;
    }
    float di = dinv2[wid], cs = cself[wid];
    float2 hsv = *(const float2*)(hs + (size_t)wid * 128 + lane * 2);
    float2 vb  = *(const float2*)(bias + lane * 2);
    float x0 = di * a0 + cs * hsv.x + vb.x;
    float x1 = di * a1 + cs * hsv.y + vb.y;
    float s = x0 + x1;
    #pragma unroll
    for (int off = 32; off; off >>= 1) s += __shfl_xor(s, off, 64);
    float mu = s * (1.0f / 128.0f);
    float d0 = x0 - mu, d1 = x1 - mu;
    float vv = d0 * d0 + d1 * d1;
    #pragma unroll
    for (int off = 32; off; off >>= 1) vv += __shfl_xor(vv, off, 64);
    float rstd = 1.0f / sqrtf(vv * (1.0f / 128.0f) + LN_EPS);
    float2 vg  = *(const float2*)(g + lane * 2);
    float2 vbl = *(const float2*)(bln + lane * 2);
    float y0 = fmaxf(d0 * rstd * vg.x + vbl.x, 0.0f);
    float y1 = fmaxf(d1 * rstd * vg.y + vbl.y, 0.0f);
    *(float2*)(outbuf + (size_t)wid * 128 + lane * 2) = make_float2(y0, y1);
    ushort2 ob; ob.x = f2bf(y0); ob.y = f2bf(y1);
    *(ushort2*)(outbf + (size_t)wid * 128 + lane * 2) = ob;
}

// layer 2: v = dinv2[c]*sum(val*g2s[row]) + cself*g2s[c] + b2; log_softmax
// g2s is bf16 (pre-scaled by dinv2[row])
__global__ __launch_bounds__(256) void gather_lsm_bf_k(const u16* __restrict__ g2s,
    const int2* __restrict__ kv, const int* __restrict__ startAll,
    const int* __restrict__ cntK, const float* __restrict__ dinv2,
    const float* __restrict__ cself, const float* __restrict__ b2,
    float* __restrict__ out, int n) {
    int wid  = (blockIdx.x * 256 + threadIdx.x) >> 6;
    int lane = threadIdx.x & 63;
    if (wid >= n) return;
    int s0 = startAll[wid], k = cntK[wid];
    float acc = 0.f;
    int j = 0;
    for (; j + 1 < k; j += 2) {
        int2 p0 = kv[s0 + j], p1 = kv[s0 + j + 1];
        float g0 = __uint_as_float((u32)g2s[(size_t)p0.x * 64 + lane] << 16);
        float g1 = __uint_as_float((u32)g2s[(size_t)p1.x * 64 + lane] << 16);
        acc += __int_as_float(p0.y) * g0 + __int_as_float(p1.y) * g1;
    }
    if (j < k) {
        int2 p0 = kv[s0 + j];
        float g0 = __uint_as_float((u32)g2s[(size_t)p0.x * 64 + lane] << 16);
        acc += __int_as_float(p0.y) * g0;
    }
    float gs = __uint_as_float((u32)g2s[(size_t)wid * 64 + lane] << 16);
    float v = dinv2[wid] * acc + cself[wid] * gs + b2[lane];
    float m = v;
    #pragma unroll
    for (int off = 32; off; off >>= 1) m = fmaxf(m, __shfl_xor(m, off, 64));
    float e = expf(v - m);
    float s = e;
    #pragma unroll
    for (int off = 32; off; off >>= 1) s += __shfl_xor(s, off, 64);
    out[(size_t)wid * 64 + lane] = v - m - logf(s);
}

// ---------------- launch ----------------

extern "C" void kernel_launch(void* const* d_in, const int* in_sizes, int n_in,
                              void* d_out, int out_size, void* d_ws, size_t ws_size,
                              hipStream_t stream) {
    (void)n_in; (void)out_size; (void)ws_size;
    const float* x   = (const float*)d_in[0];
    const int*   row = (const int*)d_in[1];
    const int*   col = (const int*)d_in[2];
    const float* W1  = (const float*)d_in[3];
    const float* b1  = (const float*)d_in[4];
    const float* lng = (const float*)d_in[5];
    const float* lnb = (const float*)d_in[6];
    const float* W2  = (const float*)d_in[7];
    const float* b2  = (const float*)d_in[8];
    float* out = (float*)d_out;

    const int N = in_sizes[0] / 128;
    const int E = in_sizes[1];

    int*   cntAll   = (int*)d_ws;
    int*   startAll = cntAll + N;
    int*   bsum     = startAll + N;            // 512 ints
    float* nrm      = (float*)(bsum + 512);
    float* deg1     = nrm + N;                 // zeroed per layer
    float* dinv1    = deg1 + N;
    float* dinv2    = dinv1 + N;
    float* cself    = dinv2 + N;
    int*   cntK     = (int*)(cself + N);       // CSR-build cursor, then kept counts
    int*   rowAll   = cntK + N;                // [E]
    int2*  kvp      = (int2*)(rowAll + E);     // [E] packed (row, val)
    u32*   fbf      = (u32*)(kvp + E);         // [64N] u32 = [128N] bf16; reused as h2bf
    u16*   g2sbf    = (u16*)(fbf + (size_t)64 * N);  // [64N] bf16
    float* big      = (float*)(g2sbf + (size_t)64 * N);
    float* sims     = big;                     // [E]  (dead before hs is written)
    float* hs       = big;                     // [128N] layer-1 scaled h
    float* h2       = big + (size_t)128 * N;   // [128N] layer-1 output (persists)

    const int nodeBlocks = (N + 255) / 256;
    const int waveBlocks = (N + 3) / 4;
    const int edgeBlocks = (E + 255) / 256;
    const int scanBlocks = nodeBlocks;         // <= 512 for N <= 131072

    // ---- one-time CSR build (shared by both layers) ----
    hipMemsetAsync(cntAll, 0, (size_t)N * sizeof(int), stream);
    count_k<<<edgeBlocks, 256, 0, stream>>>(col, cntAll, E);
    scan1_k<<<scanBlocks, 256, 0, stream>>>(cntAll, startAll, bsum, N);
    scan2_k<<<1, 512, 0, stream>>>(bsum, scanBlocks);
    scan3_k<<<scanBlocks, 256, 0, stream>>>(startAll, bsum, N);
    hipMemsetAsync(cntK, 0, (size_t)N * sizeof(int), stream);
    fill_k<<<edgeBlocks, 256, 0, stream>>>(row, col, startAll, cntK, rowAll, E);

    // ================= layer 1 =================
    hipMemsetAsync(deg1, 0, (size_t)N * sizeof(float), stream);
    cast_bf_k<<<(N * 16 + 255) / 256, 256, 0, stream>>>(x, (u16*)fbf, N * 16);
    node_norm_k<<<waveBlocks, 256, 0, stream>>>(x, nrm, N);
    edge_dot_bf_k<<<waveBlocks, 256, 0, stream>>>(fbf, x, rowAll, startAll, cntAll, nrm,
                                                  sims, deg1, N);
    node_b_k<<<nodeBlocks, 256, 0, stream>>>(deg1, dinv1, N);
    edge_c_csr_k<<<waveBlocks, 256, 0, stream>>>(sims, rowAll, startAll, cntAll, dinv1,
                                                 kvp, cntK, dinv2, cself, N);
    gemm128_k<<<(N + 7) / 8, 256, 0, stream>>>(x, W1, dinv2, hs, N);
    gather_ln_k<<<waveBlocks, 256, 0, stream>>>(hs, kvp, startAll, cntK, dinv2, cself,
                                                b1, lng, lnb, h2, (u16*)fbf, N);

    // ================= layer 2 =================
    hipMemsetAsync(deg1, 0, (size_t)N * sizeof(float), stream);
    node_norm_k<<<waveBlocks, 256, 0, stream>>>(h2, nrm, N);
    edge_dot_bf_k<<<waveBlocks, 256, 0, stream>>>(fbf, h2, rowAll, startAll, cntAll, nrm,
                                                  sims, deg1, N);
    node_b_k<<<nodeBlocks, 256, 0, stream>>>(deg1, dinv1, N);
    edge_c_csr_k<<<waveBlocks, 256, 0, stream>>>(sims, rowAll, startAll, cntAll, dinv1,
                                                 kvp, cntK, dinv2, cself, N);
    gemm64_bf_k<<<(N + 15) / 16, 256, 0, stream>>>(h2, W2, dinv2, g2sbf, N);
    gather_lsm_bf_k<<<waveBlocks, 256, 0, stream>>>(g2sbf, kvp, startAll, cntK, dinv2,
                                                    cself, b2, out, N);
}

// Round 6
// 816.050 us; speedup vs baseline: 1.8644x; 1.0749x over previous
//
#include <hip/hip_runtime.h>
#include <math.h>

#define EPSF 1e-8f
#define LN_EPS 1e-5f
#define BL_MARGIN 0.008f   // > 2^-8 hard bound on bf16 cosine-sim error

typedef unsigned int  u32;
typedef unsigned short u16;

// round-to-nearest-even fp32 -> bf16 (finite inputs)
static __device__ inline u16 f2bf(float f) {
    u32 u = __float_as_uint(f);
    u = (u + 0x7FFFu + ((u >> 16) & 1u)) >> 16;
    return (u16)u;
}
static __device__ inline float bf_lo(u32 u) { return __uint_as_float(u << 16); }
static __device__ inline float bf_hi(u32 u) { return __uint_as_float(u & 0xFFFF0000u); }

// ---------------- node kernels ----------------

__global__ __launch_bounds__(256) void node_norm_k(const float* __restrict__ feat,
                                                   float* __restrict__ nrm, int n) {
    int wid  = (blockIdx.x * 256 + threadIdx.x) >> 6;
    int lane = threadIdx.x & 63;
    if (wid >= n) return;
    float2 v = *(const float2*)(feat + (size_t)wid * 128 + lane * 2);
    float s = v.x * v.x + v.y * v.y;
    #pragma unroll
    for (int off = 32; off; off >>= 1) s += __shfl_xor(s, off, 64);
    if (lane == 0) nrm[wid] = fmaxf(sqrtf(s), EPSF);
}

__global__ __launch_bounds__(256) void node_b_k(const float* __restrict__ deg1,
                                                float* __restrict__ dinv1, int n) {
    int i = blockIdx.x * 256 + threadIdx.x;
    if (i >= n) return;
    float d = deg1[i];
    dinv1[i] = (d > 0.0f) ? 1.0f / sqrtf(d) : 0.0f;
}

// cast fp32 features -> bf16 (RTNE); n8 = total elems / 8
__global__ __launch_bounds__(256) void cast_bf_k(const float* __restrict__ in,
                                                 u16* __restrict__ out, int n8) {
    int i = blockIdx.x * 256 + threadIdx.x;
    if (i >= n8) return;
    float4 a = ((const float4*)in)[2 * i];
    float4 b = ((const float4*)in)[2 * i + 1];
    ushort4 p0, p1;
    p0.x = f2bf(a.x); p0.y = f2bf(a.y); p0.z = f2bf(a.z); p0.w = f2bf(a.w);
    p1.x = f2bf(b.x); p1.y = f2bf(b.y); p1.z = f2bf(b.z); p1.w = f2bf(b.w);
    ((ushort4*)out)[2 * i]     = p0;
    ((ushort4*)out)[2 * i + 1] = p1;
}

// ---------------- one-time CSR build ----------------

__global__ __launch_bounds__(256) void count_k(const int* __restrict__ col,
                                               int* __restrict__ cntAll, int ecnt) {
    int e = blockIdx.x * 256 + threadIdx.x;
    if (e < ecnt) atomicAdd(&cntAll[col[e]], 1);
}

__global__ __launch_bounds__(256) void scan1_k(const int* __restrict__ cnt,
    int* __restrict__ colStart, int* __restrict__ bsum, int n) {
    __shared__ int tmp[256];
    int i = blockIdx.x * 256 + threadIdx.x;
    int v = (i < n) ? cnt[i] : 0;
    tmp[threadIdx.x] = v; __syncthreads();
    for (int off = 1; off < 256; off <<= 1) {
        int t = (threadIdx.x >= off) ? tmp[threadIdx.x - off] : 0;
        __syncthreads();
        tmp[threadIdx.x] += t;
        __syncthreads();
    }
    if (i < n) colStart[i] = tmp[threadIdx.x] - v;   // exclusive
    if (threadIdx.x == 255) bsum[blockIdx.x] = tmp[255];
}

__global__ __launch_bounds__(512) void scan2_k(int* __restrict__ bsum, int nb) {
    __shared__ int tmp[512];
    int v = (threadIdx.x < nb) ? bsum[threadIdx.x] : 0;
    tmp[threadIdx.x] = v; __syncthreads();
    for (int off = 1; off < 512; off <<= 1) {
        int t = (threadIdx.x >= off) ? tmp[threadIdx.x - off] : 0;
        __syncthreads();
        tmp[threadIdx.x] += t;
        __syncthreads();
    }
    if (threadIdx.x < nb) bsum[threadIdx.x] = tmp[threadIdx.x] - v;  // exclusive
}

__global__ __launch_bounds__(256) void scan3_k(int* __restrict__ colStart,
    const int* __restrict__ bsum, int n) {
    int i = blockIdx.x * 256 + threadIdx.x;
    if (i < n) colStart[i] += bsum[blockIdx.x];
}

__global__ __launch_bounds__(256) void fill_k(const int* __restrict__ row,
    const int* __restrict__ col, const int* __restrict__ startAll,
    int* __restrict__ cur, int* __restrict__ rowAll, int ecnt) {
    int e = blockIdx.x * 256 + threadIdx.x;
    if (e >= ecnt) return;
    int c = col[e];
    int p = startAll[c] + atomicAdd(&cur[c], 1);
    rowAll[p] = row[e];
}

// ---------------- edge phase A: bf16 cosine sims, 4 edges/wave ----------------
// one wave per col node; 4 edges in flight (16 lanes x 8 bf16 each).
// Borderline edges recomputed INLINE in fp32 (global counter/list convoyed in r4).
__global__ __launch_bounds__(256) void edge_dot_bf_k(const u32* __restrict__ fbf,
    const float* __restrict__ feat32,
    const int* __restrict__ rowAll, const int* __restrict__ startAll,
    const int* __restrict__ cntAll, const float* __restrict__ nrm,
    float* __restrict__ sims, float* __restrict__ deg1, int n) {
    int wid  = (blockIdx.x * 256 + threadIdx.x) >> 6;
    int lane = threadIdx.x & 63;
    if (wid >= n) return;
    int s0 = startAll[wid], cnt = cntAll[wid];
    int q = lane >> 4, l = lane & 15;
    uint4 fcu = *(const uint4*)(fbf + (size_t)wid * 64 + l * 4);
    float c0 = bf_lo(fcu.x), c1 = bf_hi(fcu.x), c2 = bf_lo(fcu.y), c3 = bf_hi(fcu.y);
    float c4 = bf_lo(fcu.z), c5 = bf_hi(fcu.z), c6 = bf_lo(fcu.w), c7 = bf_hi(fcu.w);
    float nc = nrm[wid];
    for (int jj = 0; jj < cnt; jj += 4) {
        int j = jj + q;
        if (j < cnt) {
            int r = rowAll[s0 + j];
            uint4 fu = *(const uint4*)(fbf + (size_t)r * 64 + l * 4);
            float p = bf_lo(fu.x) * c0 + bf_hi(fu.x) * c1
                    + bf_lo(fu.y) * c2 + bf_hi(fu.y) * c3
                    + bf_lo(fu.z) * c4 + bf_hi(fu.z) * c5
                    + bf_lo(fu.w) * c6 + bf_hi(fu.w) * c7;
            #pragma unroll
            for (int off = 8; off; off >>= 1) p += __shfl_xor(p, off, 64);
            float rn = 1.0f / (nrm[r] * nc);
            float sim = p * rn;
            if (fabsf(sim - 0.1f) < BL_MARGIN) {
                // exact fp32 recompute of this edge (16 lanes x 8 floats/endpoint)
                const float4* fr = (const float4*)(feat32 + (size_t)r * 128);
                const float4* fc = (const float4*)(feat32 + (size_t)wid * 128);
                float4 a0 = fr[l * 2], a1 = fr[l * 2 + 1];
                float4 b0 = fc[l * 2], b1 = fc[l * 2 + 1];
                float s2 = a0.x * b0.x + a0.y * b0.y + a0.z * b0.z + a0.w * b0.w
                         + a1.x * b1.x + a1.y * b1.y + a1.z * b1.z + a1.w * b1.w;
                #pragma unroll
                for (int off = 8; off; off >>= 1) s2 += __shfl_xor(s2, off, 64);
                sim = s2 * rn;
            }
            float kv = (sim >= 0.1f) ? sim : 0.0f;
            if (l == 0) {
                sims[s0 + j] = kv;
                if (kv > 0.0f) atomicAdd(&deg1[r], kv);
            }
        }
    }
}

// ---------------- edge phase B: vals + in-wave deg2 + compaction ----------------
__global__ __launch_bounds__(256) void edge_c_csr_k(const float* __restrict__ sims,
    const int* __restrict__ rowAll, const int* __restrict__ startAll,
    const int* __restrict__ cntAll, const float* __restrict__ dinv1,
    int2* __restrict__ kv, int* __restrict__ cntK, float* __restrict__ dinv2,
    float* __restrict__ cself, int n) {
    int wid  = (blockIdx.x * 256 + threadIdx.x) >> 6;
    int lane = threadIdx.x & 63;
    if (wid >= n) return;
    int s0 = startAll[wid], cnt = cntAll[wid];
    float d1c = dinv1[wid];
    float vsum = 0.0f; int kc = 0;
    for (int jj = 0; jj < cnt; jj += 64) {
        int j = jj + lane;
        bool keep = false; int r = 0; float v = 0.0f;
        if (j < cnt) {
            float s = sims[s0 + j];
            if (s > 0.0f) { r = rowAll[s0 + j]; v = expf(dinv1[r] * s * d1c); keep = true; }
        }
        unsigned long long m = __ballot(keep ? 1 : 0);
        if (keep) {
            int pre = __popcll(m & ((1ull << lane) - 1ull));
            int2 pk; pk.x = r; pk.y = __float_as_int(v);
            kv[s0 + kc + pre] = pk;
            vsum += v;
        }
        kc += __popcll(m);
    }
    #pragma unroll
    for (int off = 32; off; off >>= 1) vsum += __shfl_xor(vsum, off, 64);
    if (lane == 0) {
        float ws_ = expf(1.0f / ((float)kc + 1.0f));   // self-loop weight
        float dg = ws_ + vsum;                         // always > 0
        float di = 1.0f / sqrtf(dg);
        dinv2[wid] = di;
        cself[wid] = di * ws_;      // self term uses dinv2-scaled h, so one di here
        cntK[wid]  = kc;
    }
}

// ---------------- GEMMs (K=128), register-tiled: 4 nodes x 4 outputs / thread ----
// LDS W reads amortized over 4 nodes (r5: 1-node version was LDS-read bound,
// 6.4 GB LDS traffic, VALUBusy 23%). Accumulation order over k unchanged.

__global__ __launch_bounds__(256) void gemm128_k(const float* __restrict__ A,
    const float* __restrict__ W, const float* __restrict__ scale,
    float* __restrict__ out, int n) {
    __shared__ float Ws[128 * 128];
    for (int i = threadIdx.x; i < 128 * 128 / 4; i += 256)
        ((float4*)Ws)[i] = ((const float4*)W)[i];
    __syncthreads();
    const int TPN = 32;                       // threads per 4-node group
    int group = threadIdx.x / TPN;            // 8 groups -> 32 nodes/block
    int tin   = threadIdx.x % TPN;
    int nid   = (blockIdx.x * 8 + group) * 4;
    if (nid >= n) return;
    int dbase = tin * 4;
    int nm1 = n - 1;
    const float4* a0 = (const float4*)(A + (size_t)min(nid,     nm1) * 128);
    const float4* a1 = (const float4*)(A + (size_t)min(nid + 1, nm1) * 128);
    const float4* a2 = (const float4*)(A + (size_t)min(nid + 2, nm1) * 128);
    const float4* a3 = (const float4*)(A + (size_t)min(nid + 3, nm1) * 128);
    float4 acc0 = {0,0,0,0}, acc1 = {0,0,0,0}, acc2 = {0,0,0,0}, acc3 = {0,0,0,0};
    #pragma unroll 2
    for (int k4 = 0; k4 < 32; ++k4) {
        const float* wr = Ws + (k4 * 4) * 128 + dbase;
        float4 w0 = *(const float4*)(wr);
        float4 w1 = *(const float4*)(wr + 128);
        float4 w2 = *(const float4*)(wr + 256);
        float4 w3 = *(const float4*)(wr + 384);
        float4 v0 = a0[k4], v1 = a1[k4], v2 = a2[k4], v3 = a3[k4];
        acc0.x += v0.x*w0.x + v0.y*w1.x + v0.z*w2.x + v0.w*w3.x;
        acc0.y += v0.x*w0.y + v0.y*w1.y + v0.z*w2.y + v0.w*w3.y;
        acc0.z += v0.x*w0.z + v0.y*w1.z + v0.z*w2.z + v0.w*w3.z;
        acc0.w += v0.x*w0.w + v0.y*w1.w + v0.z*w2.w + v0.w*w3.w;
        acc1.x += v1.x*w0.x + v1.y*w1.x + v1.z*w2.x + v1.w*w3.x;
        acc1.y += v1.x*w0.y + v1.y*w1.y + v1.z*w2.y + v1.w*w3.y;
        acc1.z += v1.x*w0.z + v1.y*w1.z + v1.z*w2.z + v1.w*w3.z;
        acc1.w += v1.x*w0.w + v1.y*w1.w + v1.z*w2.w + v1.w*w3.w;
        acc2.x += v2.x*w0.x + v2.y*w1.x + v2.z*w2.x + v2.w*w3.x;
        acc2.y += v2.x*w0.y + v2.y*w1.y + v2.z*w2.y + v2.w*w3.y;
        acc2.z += v2.x*w0.z + v2.y*w1.z + v2.z*w2.z + v2.w*w3.z;
        acc2.w += v2.x*w0.w + v2.y*w1.w + v2.z*w2.w + v2.w*w3.w;
        acc3.x += v3.x*w0.x + v3.y*w1.x + v3.z*w2.x + v3.w*w3.x;
        acc3.y += v3.x*w0.y + v3.y*w1.y + v3.z*w2.y + v3.w*w3.y;
        acc3.z += v3.x*w0.z + v3.y*w1.z + v3.z*w2.z + v3.w*w3.z;
        acc3.w += v3.x*w0.w + v3.y*w1.w + v3.z*w2.w + v3.w*w3.w;
    }
    float4 accs[4] = {acc0, acc1, acc2, acc3};
    #pragma unroll
    for (int i = 0; i < 4; ++i) {
        if (nid + i < n) {
            float sc = scale[nid + i];
            float4 r; r.x = accs[i].x * sc; r.y = accs[i].y * sc;
            r.z = accs[i].z * sc; r.w = accs[i].w * sc;
            *(float4*)(out + (size_t)(nid + i) * 128 + dbase) = r;
        }
    }
}

// DOUT=64 variant, bf16 output
__global__ __launch_bounds__(256) void gemm64_bf_k(const float* __restrict__ A,
    const float* __restrict__ W, const float* __restrict__ scale,
    u16* __restrict__ outbf, int n) {
    __shared__ float Ws[128 * 64];
    for (int i = threadIdx.x; i < 128 * 64 / 4; i += 256)
        ((float4*)Ws)[i] = ((const float4*)W)[i];
    __syncthreads();
    const int TPN = 16;                       // threads per 4-node group
    int group = threadIdx.x / TPN;            // 16 groups -> 64 nodes/block
    int tin   = threadIdx.x % TPN;
    int nid   = (blockIdx.x * 16 + group) * 4;
    if (nid >= n) return;
    int dbase = tin * 4;
    int nm1 = n - 1;
    const float4* a0 = (const float4*)(A + (size_t)min(nid,     nm1) * 128);
    const float4* a1 = (const float4*)(A + (size_t)min(nid + 1, nm1) * 128);
    const float4* a2 = (const float4*)(A + (size_t)min(nid + 2, nm1) * 128);
    const float4* a3 = (const float4*)(A + (size_t)min(nid + 3, nm1) * 128);
    float4 acc0 = {0,0,0,0}, acc1 = {0,0,0,0}, acc2 = {0,0,0,0}, acc3 = {0,0,0,0};
    #pragma unroll 2
    for (int k4 = 0; k4 < 32; ++k4) {
        const float* wr = Ws + (k4 * 4) * 64 + dbase;
        float4 w0 = *(const float4*)(wr);
        float4 w1 = *(const float4*)(wr + 64);
        float4 w2 = *(const float4*)(wr + 128);
        float4 w3 = *(const float4*)(wr + 192);
        float4 v0 = a0[k4], v1 = a1[k4], v2 = a2[k4], v3 = a3[k4];
        acc0.x += v0.x*w0.x + v0.y*w1.x + v0.z*w2.x + v0.w*w3.x;
        acc0.y += v0.x*w0.y + v0.y*w1.y + v0.z*w2.y + v0.w*w3.y;
        acc0.z += v0.x*w0.z + v0.y*w1.z + v0.z*w2.z + v0.w*w3.z;
        acc0.w += v0.x*w0.w + v0.y*w1.w + v0.z*w2.w + v0.w*w3.w;
        acc1.x += v1.x*w0.x + v1.y*w1.x + v1.z*w2.x + v1.w*w3.x;
        acc1.y += v1.x*w0.y + v1.y*w1.y + v1.z*w2.y + v1.w*w3.y;
        acc1.z += v1.x*w0.z + v1.y*w1.z + v1.z*w2.z + v1.w*w3.z;
        acc1.w += v1.x*w0.w + v1.y*w1.w + v1.z*w2.w + v1.w*w3.w;
        acc2.x += v2.x*w0.x + v2.y*w1.x + v2.z*w2.x + v2.w*w3.x;
        acc2.y += v2.x*w0.y + v2.y*w1.y + v2.z*w2.y + v2.w*w3.y;
        acc2.z += v2.x*w0.z + v2.y*w1.z + v2.z*w2.z + v2.w*w3.z;
        acc2.w += v2.x*w0.w + v2.y*w1.w + v2.z*w2.w + v2.w*w3.w;
        acc3.x += v3.x*w0.x + v3.y*w1.x + v3.z*w2.x + v3.w*w3.x;
        acc3.y += v3.x*w0.y + v3.y*w1.y + v3.z*w2.y + v3.w*w3.y;
        acc3.z += v3.x*w0.z + v3.y*w1.z + v3.z*w2.z + v3.w*w3.z;
        acc3.w += v3.x*w0.w + v3.y*w1.w + v3.z*w2.w + v3.w*w3.w;
    }
    float4 accs[4] = {acc0, acc1, acc2, acc3};
    #pragma unroll
    for (int i = 0; i < 4; ++i) {
        if (nid + i < n) {
            float sc = scale[nid + i];
            ushort4 r; r.x = f2bf(accs[i].x * sc); r.y = f2bf(accs[i].y * sc);
            r.z = f2bf(accs[i].z * sc); r.w = f2bf(accs[i].w * sc);
            *(ushort4*)(outbf + (size_t)(nid + i) * 64 + dbase) = r;
        }
    }
}

// ---------------- fused gather epilogues ----------------

// layer 1: x = dinv2[c]*sum(val*hs[row]) + cself*hs[c] + bias; LN; ReLU
// writes h2 (fp32) and h2bf (bf16, for layer-2 sims)
__global__ __launch_bounds__(256) void gather_ln_k(const float* __restrict__ hs,
    const int2* __restrict__ kv, const int* __restrict__ startAll,
    const int* __restrict__ cntK, const float* __restrict__ dinv2,
    const float* __restrict__ cself, const float* __restrict__ bias,
    const float* __restrict__ g, const float* __restrict__ bln,
    float* __restrict__ outbuf, u16* __restrict__ outbf, int n) {
    int wid  = (blockIdx.x * 256 + threadIdx.x) >> 6;
    int lane = threadIdx.x & 63;
    if (wid >= n) return;
    int s0 = startAll[wid], k = cntK[wid];
    float a0 = 0.f, a1 = 0.f;
    int j = 0;
    for (; j + 1 < k; j += 2) {
        int2 p0 = kv[s0 + j], p1 = kv[s0 + j + 1];
        float2 h0 = *(const float2*)(hs + (size_t)p0.x * 128 + lane * 2);
        float2 h1 = *(const float2*)(hs + (size_t)p1.x * 128 + lane * 2);
        float v0 = __int_as_float(p0.y), v1 = __int_as_float(p1.y);
        a0 += v0 * h0.x + v1 * h1.x;
        a1 += v0 * h0.y + v1 * h1.y;
    }
    if (j < k) {
        int2 p0 = kv[s0 + j];
        float2 h0 = *(const float2*)(hs + (size_t)p0.x * 128 + lane * 2);
        float v0 = __int_as_float(p0.y);
        a0 += v0 * h0.x; a1 += v0 * h0.y;
    }
    float di = dinv2[wid], cs = cself[wid];
    float2 hsv = *(const float2*)(hs + (size_t)wid * 128 + lane * 2);
    float2 vb  = *(const float2*)(bias + lane * 2);
    float x0 = di * a0 + cs * hsv.x + vb.x;
    float x1 = di * a1 + cs * hsv.y + vb.y;
    float s = x0 + x1;
    #pragma unroll
    for (int off = 32; off; off >>= 1) s += __shfl_xor(s, off, 64);
    float mu = s * (1.0f / 128.0f);
    float d0 = x0 - mu, d1 = x1 - mu;
    float vv = d0 * d0 + d1 * d1;
    #pragma unroll
    for (int off = 32; off; off >>= 1) vv += __shfl_xor(vv, off, 64);
    float rstd = 1.0f / sqrtf(vv * (1.0f / 128.0f) + LN_EPS);
    float2 vg  = *(const float2*)(g + lane * 2);
    float2 vbl = *(const float2*)(bln + lane * 2);
    float y0 = fmaxf(d0 * rstd * vg.x + vbl.x, 0.0f);
    float y1 = fmaxf(d1 * rstd * vg.y + vbl.y, 0.0f);
    *(float2*)(outbuf + (size_t)wid * 128 + lane * 2) = make_float2(y0, y1);
    ushort2 ob; ob.x = f2bf(y0); ob.y = f2bf(y1);
    *(ushort2*)(outbf + (size_t)wid * 128 + lane * 2) = ob;
}

// layer 2: v = dinv2[c]*sum(val*g2s[row]) + cself*g2s[c] + b2; log_softmax
// g2s is bf16 (pre-scaled by dinv2[row])
__global__ __launch_bounds__(256) void gather_lsm_bf_k(const u16* __restrict__ g2s,
    const int2* __restrict__ kv, const int* __restrict__ startAll,
    const int* __restrict__ cntK, const float* __restrict__ dinv2,
    const float* __restrict__ cself, const float* __restrict__ b2,
    float* __restrict__ out, int n) {
    int wid  = (blockIdx.x * 256 + threadIdx.x) >> 6;
    int lane = threadIdx.x & 63;
    if (wid >= n) return;
    int s0 = startAll[wid], k = cntK[wid];
    float acc = 0.f;
    int j = 0;
    for (; j + 1 < k; j += 2) {
        int2 p0 = kv[s0 + j], p1 = kv[s0 + j + 1];
        float g0 = __uint_as_float((u32)g2s[(size_t)p0.x * 64 + lane] << 16);
        float g1 = __uint_as_float((u32)g2s[(size_t)p1.x * 64 + lane] << 16);
        acc += __int_as_float(p0.y) * g0 + __int_as_float(p1.y) * g1;
    }
    if (j < k) {
        int2 p0 = kv[s0 + j];
        float g0 = __uint_as_float((u32)g2s[(size_t)p0.x * 64 + lane] << 16);
        acc += __int_as_float(p0.y) * g0;
    }
    float gs = __uint_as_float((u32)g2s[(size_t)wid * 64 + lane] << 16);
    float v = dinv2[wid] * acc + cself[wid] * gs + b2[lane];
    float m = v;
    #pragma unroll
    for (int off = 32; off; off >>= 1) m = fmaxf(m, __shfl_xor(m, off, 64));
    float e = expf(v - m);
    float s = e;
    #pragma unroll
    for (int off = 32; off; off >>= 1) s += __shfl_xor(s, off, 64);
    out[(size_t)wid * 64 + lane] = v - m - logf(s);
}

// ---------------- launch ----------------

extern "C" void kernel_launch(void* const* d_in, const int* in_sizes, int n_in,
                              void* d_out, int out_size, void* d_ws, size_t ws_size,
                              hipStream_t stream) {
    (void)n_in; (void)out_size; (void)ws_size;
    const float* x   = (const float*)d_in[0];
    const int*   row = (const int*)d_in[1];
    const int*   col = (const int*)d_in[2];
    const float* W1  = (const float*)d_in[3];
    const float* b1  = (const float*)d_in[4];
    const float* lng = (const float*)d_in[5];
    const float* lnb = (const float*)d_in[6];
    const float* W2  = (const float*)d_in[7];
    const float* b2  = (const float*)d_in[8];
    float* out = (float*)d_out;

    const int N = in_sizes[0] / 128;
    const int E = in_sizes[1];

    int*   cntAll   = (int*)d_ws;
    int*   startAll = cntAll + N;
    int*   bsum     = startAll + N;            // 512 ints
    float* nrm      = (float*)(bsum + 512);
    float* deg1     = nrm + N;                 // zeroed per layer
    float* dinv1    = deg1 + N;
    float* dinv2    = dinv1 + N;
    float* cself    = dinv2 + N;
    int*   cntK     = (int*)(cself + N);       // CSR-build cursor, then kept counts
    int*   rowAll   = cntK + N;                // [E]
    int2*  kvp      = (int2*)(rowAll + E);     // [E] packed (row, val)
    u32*   fbf      = (u32*)(kvp + E);         // [64N] u32 = [128N] bf16; reused as h2bf
    u16*   g2sbf    = (u16*)(fbf + (size_t)64 * N);  // [64N] bf16
    float* big      = (float*)(g2sbf + (size_t)64 * N);
    float* sims     = big;                     // [E]  (dead before hs is written)
    float* hs       = big;                     // [128N] layer-1 scaled h
    float* h2       = big + (size_t)128 * N;   // [128N] layer-1 output (persists)

    const int nodeBlocks = (N + 255) / 256;
    const int waveBlocks = (N + 3) / 4;
    const int edgeBlocks = (E + 255) / 256;
    const int scanBlocks = nodeBlocks;         // <= 512 for N <= 131072

    // ---- one-time CSR build (shared by both layers) ----
    hipMemsetAsync(cntAll, 0, (size_t)N * sizeof(int), stream);
    count_k<<<edgeBlocks, 256, 0, stream>>>(col, cntAll, E);
    scan1_k<<<scanBlocks, 256, 0, stream>>>(cntAll, startAll, bsum, N);
    scan2_k<<<1, 512, 0, stream>>>(bsum, scanBlocks);
    scan3_k<<<scanBlocks, 256, 0, stream>>>(startAll, bsum, N);
    hipMemsetAsync(cntK, 0, (size_t)N * sizeof(int), stream);
    fill_k<<<edgeBlocks, 256, 0, stream>>>(row, col, startAll, cntK, rowAll, E);

    // ================= layer 1 =================
    hipMemsetAsync(deg1, 0, (size_t)N * sizeof(float), stream);
    cast_bf_k<<<(N * 16 + 255) / 256, 256, 0, stream>>>(x, (u16*)fbf, N * 16);
    node_norm_k<<<waveBlocks, 256, 0, stream>>>(x, nrm, N);
    edge_dot_bf_k<<<waveBlocks, 256, 0, stream>>>(fbf, x, rowAll, startAll, cntAll, nrm,
                                                  sims, deg1, N);
    node_b_k<<<nodeBlocks, 256, 0, stream>>>(deg1, dinv1, N);
    edge_c_csr_k<<<waveBlocks, 256, 0, stream>>>(sims, rowAll, startAll, cntAll, dinv1,
                                                 kvp, cntK, dinv2, cself, N);
    gemm128_k<<<(N + 31) / 32, 256, 0, stream>>>(x, W1, dinv2, hs, N);
    gather_ln_k<<<waveBlocks, 256, 0, stream>>>(hs, kvp, startAll, cntK, dinv2, cself,
                                                b1, lng, lnb, h2, (u16*)fbf, N);

    // ================= layer 2 =================
    hipMemsetAsync(deg1, 0, (size_t)N * sizeof(float), stream);
    node_norm_k<<<waveBlocks, 256, 0, stream>>>(h2, nrm, N);
    edge_dot_bf_k<<<waveBlocks, 256, 0, stream>>>(fbf, h2, rowAll, startAll, cntAll, nrm,
                                                  sims, deg1, N);
    node_b_k<<<nodeBlocks, 256, 0, stream>>>(deg1, dinv1, N);
    edge_c_csr_k<<<waveBlocks, 256, 0, stream>>>(sims, rowAll, startAll, cntAll, dinv1,
                                                 kvp, cntK, dinv2, cself, N);
    gemm64_bf_k<<<(N + 63) / 64, 256, 0, stream>>>(h2, W2, dinv2, g2sbf, N);
    gather_lsm_bf_k<<<waveBlocks, 256, 0, stream>>>(g2sbf, kvp, startAll, cntK, dinv2,
                                                    cself, b2, out, N);
}

// Round 7
// 769.930 us; speedup vs baseline: 1.9761x; 1.0599x over previous
//
#include <hip/hip_runtime.h>
#include <math.h>

#define EPSF 1e-8f
#define LN_EPS 1e-5f
#define BL_MARGIN 0.002f   // > 2^-10 hard bound on fp16 cosine-sim error

typedef unsigned int  u32;
typedef unsigned short u16;
typedef _Float16 h2_t __attribute__((ext_vector_type(2)));

static __device__ inline u32 pack_h2(float a, float b) {
    h2_t h; h.x = (_Float16)a; h.y = (_Float16)b;
    return __builtin_bit_cast(u32, h);
}
static __device__ inline float h2f(u16 h) {
    return (float)__builtin_bit_cast(_Float16, h);
}
static __device__ inline float fdot2_u32(u32 a, u32 b, float c) {
    return __builtin_amdgcn_fdot2(__builtin_bit_cast(h2_t, a),
                                  __builtin_bit_cast(h2_t, b), c, false);
}

// ---------------- layer-1 prep: cast x -> fp16 AND compute row norms ----------------
// one wave per node: float2/lane -> half2/lane + wave-reduced L2 norm
__global__ __launch_bounds__(256) void cast_norm_k(const float* __restrict__ feat,
    u32* __restrict__ fhf, float* __restrict__ nrm, int n) {
    int wid  = (blockIdx.x * 256 + threadIdx.x) >> 6;
    int lane = threadIdx.x & 63;
    if (wid >= n) return;
    float2 v = *(const float2*)(feat + (size_t)wid * 128 + lane * 2);
    fhf[(size_t)wid * 64 + lane] = pack_h2(v.x, v.y);
    float s = v.x * v.x + v.y * v.y;
    #pragma unroll
    for (int off = 32; off; off >>= 1) s += __shfl_xor(s, off, 64);
    if (lane == 0) nrm[wid] = fmaxf(sqrtf(s), EPSF);
}

// ---------------- one-time CSR build ----------------

__global__ __launch_bounds__(256) void count_k(const int* __restrict__ col,
                                               int* __restrict__ cntAll, int ecnt) {
    int e = blockIdx.x * 256 + threadIdx.x;
    if (e < ecnt) atomicAdd(&cntAll[col[e]], 1);
}

__global__ __launch_bounds__(256) void scan1_k(const int* __restrict__ cnt,
    int* __restrict__ colStart, int* __restrict__ bsum, int n) {
    __shared__ int tmp[256];
    int i = blockIdx.x * 256 + threadIdx.x;
    int v = (i < n) ? cnt[i] : 0;
    tmp[threadIdx.x] = v; __syncthreads();
    for (int off = 1; off < 256; off <<= 1) {
        int t = (threadIdx.x >= off) ? tmp[threadIdx.x - off] : 0;
        __syncthreads();
        tmp[threadIdx.x] += t;
        __syncthreads();
    }
    if (i < n) colStart[i] = tmp[threadIdx.x] - v;   // exclusive
    if (threadIdx.x == 255) bsum[blockIdx.x] = tmp[255];
}

__global__ __launch_bounds__(512) void scan2_k(int* __restrict__ bsum, int nb) {
    __shared__ int tmp[512];
    int v = (threadIdx.x < nb) ? bsum[threadIdx.x] : 0;
    tmp[threadIdx.x] = v; __syncthreads();
    for (int off = 1; off < 512; off <<= 1) {
        int t = (threadIdx.x >= off) ? tmp[threadIdx.x - off] : 0;
        __syncthreads();
        tmp[threadIdx.x] += t;
        __syncthreads();
    }
    if (threadIdx.x < nb) bsum[threadIdx.x] = tmp[threadIdx.x] - v;  // exclusive
}

__global__ __launch_bounds__(256) void scan3_k(int* __restrict__ colStart,
    const int* __restrict__ bsum, int n) {
    int i = blockIdx.x * 256 + threadIdx.x;
    if (i < n) colStart[i] += bsum[blockIdx.x];
}

__global__ __launch_bounds__(256) void fill_k(const int* __restrict__ row,
    const int* __restrict__ col, const int* __restrict__ startAll,
    int* __restrict__ cur, int* __restrict__ rowAll, int ecnt) {
    int e = blockIdx.x * 256 + threadIdx.x;
    if (e >= ecnt) return;
    int c = col[e];
    int p = startAll[c] + atomicAdd(&cur[c], 1);
    rowAll[p] = row[e];
}

// ---------------- edge phase A: fp16 cosine sims via v_dot2, 4 edges/wave --------
// one wave per col node; 4 edges in flight (16 lanes x 8 halves each).
// Borderline edges recomputed INLINE in fp32 (global counter/list convoyed in r4).
__global__ __launch_bounds__(256) void edge_dot_hf_k(const u32* __restrict__ fhf,
    const float* __restrict__ feat32,
    const int* __restrict__ rowAll, const int* __restrict__ startAll,
    const int* __restrict__ cntAll, const float* __restrict__ nrm,
    float* __restrict__ sims, float* __restrict__ deg1, int n) {
    int wid  = (blockIdx.x * 256 + threadIdx.x) >> 6;
    int lane = threadIdx.x & 63;
    if (wid >= n) return;
    int s0 = startAll[wid], cnt = cntAll[wid];
    int q = lane >> 4, l = lane & 15;
    uint4 fc = *(const uint4*)(fhf + (size_t)wid * 64 + l * 4);
    float nc = nrm[wid];
    for (int jj = 0; jj < cnt; jj += 4) {
        int j = jj + q;
        if (j < cnt) {
            int r = rowAll[s0 + j];
            uint4 fu = *(const uint4*)(fhf + (size_t)r * 64 + l * 4);
            float p = fdot2_u32(fu.x, fc.x, 0.0f);
            p = fdot2_u32(fu.y, fc.y, p);
            p = fdot2_u32(fu.z, fc.z, p);
            p = fdot2_u32(fu.w, fc.w, p);
            #pragma unroll
            for (int off = 8; off; off >>= 1) p += __shfl_xor(p, off, 64);
            float rn = 1.0f / (nrm[r] * nc);
            float sim = p * rn;
            if (fabsf(sim - 0.1f) < BL_MARGIN) {
                // exact fp32 recompute of this edge (16 lanes x 8 floats/endpoint)
                const float4* fr = (const float4*)(feat32 + (size_t)r * 128);
                const float4* fcc = (const float4*)(feat32 + (size_t)wid * 128);
                float4 a0 = fr[l * 2], a1 = fr[l * 2 + 1];
                float4 b0 = fcc[l * 2], b1 = fcc[l * 2 + 1];
                float s2 = a0.x * b0.x + a0.y * b0.y + a0.z * b0.z + a0.w * b0.w
                         + a1.x * b1.x + a1.y * b1.y + a1.z * b1.z + a1.w * b1.w;
                #pragma unroll
                for (int off = 8; off; off >>= 1) s2 += __shfl_xor(s2, off, 64);
                sim = s2 * rn;
            }
            float kv = (sim >= 0.1f) ? sim : 0.0f;
            if (l == 0) {
                sims[s0 + j] = kv;
                if (kv > 0.0f) atomicAdd(&deg1[r], kv);
            }
        }
    }
}

// ---------------- edge phase B: vals + in-wave deg2 + compaction ----------------
// dinv1 computed inline from deg1 (deg1[r] > 0 guaranteed for kept edges)
__global__ __launch_bounds__(256) void edge_c_csr_k(const float* __restrict__ sims,
    const int* __restrict__ rowAll, const int* __restrict__ startAll,
    const int* __restrict__ cntAll, const float* __restrict__ deg1,
    int2* __restrict__ kv, int* __restrict__ cntK, float* __restrict__ dinv2,
    float* __restrict__ cself, int n) {
    int wid  = (blockIdx.x * 256 + threadIdx.x) >> 6;
    int lane = threadIdx.x & 63;
    if (wid >= n) return;
    int s0 = startAll[wid], cnt = cntAll[wid];
    float degc = deg1[wid];
    float d1c = (degc > 0.0f) ? 1.0f / sqrtf(degc) : 0.0f;
    float vsum = 0.0f; int kc = 0;
    for (int jj = 0; jj < cnt; jj += 64) {
        int j = jj + lane;
        bool keep = false; int r = 0; float v = 0.0f;
        if (j < cnt) {
            float s = sims[s0 + j];
            if (s > 0.0f) {
                r = rowAll[s0 + j];
                float dr = 1.0f / sqrtf(deg1[r]);     // deg1[r] >= s >= 0.1
                v = expf(dr * s * d1c);
                keep = true;
            }
        }
        unsigned long long m = __ballot(keep ? 1 : 0);
        if (keep) {
            int pre = __popcll(m & ((1ull << lane) - 1ull));
            int2 pk; pk.x = r; pk.y = __float_as_int(v);
            kv[s0 + kc + pre] = pk;
            vsum += v;
        }
        kc += __popcll(m);
    }
    #pragma unroll
    for (int off = 32; off; off >>= 1) vsum += __shfl_xor(vsum, off, 64);
    if (lane == 0) {
        float ws_ = expf(1.0f / ((float)kc + 1.0f));   // self-loop weight
        float dg = ws_ + vsum;                         // always > 0
        float di = 1.0f / sqrtf(dg);
        dinv2[wid] = di;
        cself[wid] = di * ws_;      // self term uses dinv2-scaled h, so one di here
        cntK[wid]  = kc;
    }
}

// ---------------- GEMMs (K=128), register-tiled: 4 nodes x 4 outputs / thread ----

__global__ __launch_bounds__(256) void gemm128_k(const float* __restrict__ A,
    const float* __restrict__ W, const float* __restrict__ scale,
    float* __restrict__ out, int n) {
    __shared__ float Ws[128 * 128];
    for (int i = threadIdx.x; i < 128 * 128 / 4; i += 256)
        ((float4*)Ws)[i] = ((const float4*)W)[i];
    __syncthreads();
    const int TPN = 32;
    int group = threadIdx.x / TPN;            // 8 groups -> 32 nodes/block
    int tin   = threadIdx.x % TPN;
    int nid   = (blockIdx.x * 8 + group) * 4;
    if (nid >= n) return;
    int dbase = tin * 4;
    int nm1 = n - 1;
    const float4* a0 = (const float4*)(A + (size_t)min(nid,     nm1) * 128);
    const float4* a1 = (const float4*)(A + (size_t)min(nid + 1, nm1) * 128);
    const float4* a2 = (const float4*)(A + (size_t)min(nid + 2, nm1) * 128);
    const float4* a3 = (const float4*)(A + (size_t)min(nid + 3, nm1) * 128);
    float4 acc0 = {0,0,0,0}, acc1 = {0,0,0,0}, acc2 = {0,0,0,0}, acc3 = {0,0,0,0};
    #pragma unroll 2
    for (int k4 = 0; k4 < 32; ++k4) {
        const float* wr = Ws + (k4 * 4) * 128 + dbase;
        float4 w0 = *(const float4*)(wr);
        float4 w1 = *(const float4*)(wr + 128);
        float4 w2 = *(const float4*)(wr + 256);
        float4 w3 = *(const float4*)(wr + 384);
        float4 v0 = a0[k4], v1 = a1[k4], v2 = a2[k4], v3 = a3[k4];
        acc0.x += v0.x*w0.x + v0.y*w1.x + v0.z*w2.x + v0.w*w3.x;
        acc0.y += v0.x*w0.y + v0.y*w1.y + v0.z*w2.y + v0.w*w3.y;
        acc0.z += v0.x*w0.z + v0.y*w1.z + v0.z*w2.z + v0.w*w3.z;
        acc0.w += v0.x*w0.w + v0.y*w1.w + v0.z*w2.w + v0.w*w3.w;
        acc1.x += v1.x*w0.x + v1.y*w1.x + v1.z*w2.x + v1.w*w3.x;
        acc1.y += v1.x*w0.y + v1.y*w1.y + v1.z*w2.y + v1.w*w3.y;
        acc1.z += v1.x*w0.z + v1.y*w1.z + v1.z*w2.z + v1.w*w3.z;
        acc1.w += v1.x*w0.w + v1.y*w1.w + v1.z*w2.w + v1.w*w3.w;
        acc2.x += v2.x*w0.x + v2.y*w1.x + v2.z*w2.x + v2.w*w3.x;
        acc2.y += v2.x*w0.y + v2.y*w1.y + v2.z*w2.y + v2.w*w3.y;
        acc2.z += v2.x*w0.z + v2.y*w1.z + v2.z*w2.z + v2.w*w3.z;
        acc2.w += v2.x*w0.w + v2.y*w1.w + v2.z*w2.w + v2.w*w3.w;
        acc3.x += v3.x*w0.x + v3.y*w1.x + v3.z*w2.x + v3.w*w3.x;
        acc3.y += v3.x*w0.y + v3.y*w1.y + v3.z*w2.y + v3.w*w3.y;
        acc3.z += v3.x*w0.z + v3.y*w1.z + v3.z*w2.z + v3.w*w3.z;
        acc3.w += v3.x*w0.w + v3.y*w1.w + v3.z*w2.w + v3.w*w3.w;
    }
    float4 accs[4] = {acc0, acc1, acc2, acc3};
    #pragma unroll
    for (int i = 0; i < 4; ++i) {
        if (nid + i < n) {
            float sc = scale[nid + i];
            float4 r; r.x = accs[i].x * sc; r.y = accs[i].y * sc;
            r.z = accs[i].z * sc; r.w = accs[i].w * sc;
            *(float4*)(out + (size_t)(nid + i) * 128 + dbase) = r;
        }
    }
}

// DOUT=64 variant, fp16 output
__global__ __launch_bounds__(256) void gemm64_hf_k(const float* __restrict__ A,
    const float* __restrict__ W, const float* __restrict__ scale,
    u32* __restrict__ outhf, int n) {
    __shared__ float Ws[128 * 64];
    for (int i = threadIdx.x; i < 128 * 64 / 4; i += 256)
        ((float4*)Ws)[i] = ((const float4*)W)[i];
    __syncthreads();
    const int TPN = 16;
    int group = threadIdx.x / TPN;            // 16 groups -> 64 nodes/block
    int tin   = threadIdx.x % TPN;
    int nid   = (blockIdx.x * 16 + group) * 4;
    if (nid >= n) return;
    int dbase = tin * 4;
    int nm1 = n - 1;
    const float4* a0 = (const float4*)(A + (size_t)min(nid,     nm1) * 128);
    const float4* a1 = (const float4*)(A + (size_t)min(nid + 1, nm1) * 128);
    const float4* a2 = (const float4*)(A + (size_t)min(nid + 2, nm1) * 128);
    const float4* a3 = (const float4*)(A + (size_t)min(nid + 3, nm1) * 128);
    float4 acc0 = {0,0,0,0}, acc1 = {0,0,0,0}, acc2 = {0,0,0,0}, acc3 = {0,0,0,0};
    #pragma unroll 2
    for (int k4 = 0; k4 < 32; ++k4) {
        const float* wr = Ws + (k4 * 4) * 64 + dbase;
        float4 w0 = *(const float4*)(wr);
        float4 w1 = *(const float4*)(wr + 64);
        float4 w2 = *(const float4*)(wr + 128);
        float4 w3 = *(const float4*)(wr + 192);
        float4 v0 = a0[k4], v1 = a1[k4], v2 = a2[k4], v3 = a3[k4];
        acc0.x += v0.x*w0.x + v0.y*w1.x + v0.z*w2.x + v0.w*w3.x;
        acc0.y += v0.x*w0.y + v0.y*w1.y + v0.z*w2.y + v0.w*w3.y;
        acc0.z += v0.x*w0.z + v0.y*w1.z + v0.z*w2.z + v0.w*w3.z;
        acc0.w += v0.x*w0.w + v0.y*w1.w + v0.z*w2.w + v0.w*w3.w;
        acc1.x += v1.x*w0.x + v1.y*w1.x + v1.z*w2.x + v1.w*w3.x;
        acc1.y += v1.x*w0.y + v1.y*w1.y + v1.z*w2.y + v1.w*w3.y;
        acc1.z += v1.x*w0.z + v1.y*w1.z + v1.z*w2.z + v1.w*w3.z;
        acc1.w += v1.x*w0.w + v1.y*w1.w + v1.z*w2.w + v1.w*w3.w;
        acc2.x += v2.x*w0.x + v2.y*w1.x + v2.z*w2.x + v2.w*w3.x;
        acc2.y += v2.x*w0.y + v2.y*w1.y + v2.z*w2.y + v2.w*w3.y;
        acc2.z += v2.x*w0.z + v2.y*w1.z + v2.z*w2.z + v2.w*w3.z;
        acc2.w += v2.x*w0.w + v2.y*w1.w + v2.z*w2.w + v2.w*w3.w;
        acc3.x += v3.x*w0.x + v3.y*w1.x + v3.z*w2.x + v3.w*w3.x;
        acc3.y += v3.x*w0.y + v3.y*w1.y + v3.z*w2.y + v3.w*w3.y;
        acc3.z += v3.x*w0.z + v3.y*w1.z + v3.z*w2.z + v3.w*w3.z;
        acc3.w += v3.x*w0.w + v3.y*w1.w + v3.z*w2.w + v3.w*w3.w;
    }
    float4 accs[4] = {acc0, acc1, acc2, acc3};
    #pragma unroll
    for (int i = 0; i < 4; ++i) {
        if (nid + i < n) {
            float sc = scale[nid + i];
            u32 o0 = pack_h2(accs[i].x * sc, accs[i].y * sc);
            u32 o1 = pack_h2(accs[i].z * sc, accs[i].w * sc);
            *(uint2*)(outhf + (size_t)(nid + i) * 32 + tin * 2) = make_uint2(o0, o1);
        }
    }
}

// ---------------- fused gather epilogues ----------------

// layer 1: x = dinv2[c]*sum(val*hs[row]) + cself*hs[c] + bias; LN; ReLU
// writes h2 (fp32), h2hf (fp16, layer-2 sims), and nrm (layer-2 norms)
__global__ __launch_bounds__(256) void gather_ln_k(const float* __restrict__ hs,
    const int2* __restrict__ kv, const int* __restrict__ startAll,
    const int* __restrict__ cntK, const float* __restrict__ dinv2,
    const float* __restrict__ cself, const float* __restrict__ bias,
    const float* __restrict__ g, const float* __restrict__ bln,
    float* __restrict__ outbuf, u32* __restrict__ outhf,
    float* __restrict__ nrm, int n) {
    int wid  = (blockIdx.x * 256 + threadIdx.x) >> 6;
    int lane = threadIdx.x & 63;
    if (wid >= n) return;
    int s0 = startAll[wid], k = cntK[wid];
    float a0 = 0.f, a1 = 0.f;
    int j = 0;
    for (; j + 3 < k; j += 4) {
        int2 p0 = kv[s0 + j], p1 = kv[s0 + j + 1];
        int2 p2 = kv[s0 + j + 2], p3 = kv[s0 + j + 3];
        float2 h0 = *(const float2*)(hs + (size_t)p0.x * 128 + lane * 2);
        float2 h1 = *(const float2*)(hs + (size_t)p1.x * 128 + lane * 2);
        float2 h2v = *(const float2*)(hs + (size_t)p2.x * 128 + lane * 2);
        float2 h3 = *(const float2*)(hs + (size_t)p3.x * 128 + lane * 2);
        float v0 = __int_as_float(p0.y), v1 = __int_as_float(p1.y);
        float v2 = __int_as_float(p2.y), v3 = __int_as_float(p3.y);
        a0 += v0 * h0.x + v1 * h1.x + v2 * h2v.x + v3 * h3.x;
        a1 += v0 * h0.y + v1 * h1.y + v2 * h2v.y + v3 * h3.y;
    }
    for (; j < k; ++j) {
        int2 p0 = kv[s0 + j];
        float2 h0 = *(const float2*)(hs + (size_t)p0.x * 128 + lane * 2);
        float v0 = __int_as_float(p0.y);
        a0 += v0 * h0.x; a1 += v0 * h0.y;
    }
    float di = dinv2[wid], cs = cself[wid];
    float2 hsv = *(const float2*)(hs + (size_t)wid * 128 + lane * 2);
    float2 vb  = *(const float2*)(bias + lane * 2);
    float x0 = di * a0 + cs * hsv.x + vb.x;
    float x1 = di * a1 + cs * hsv.y + vb.y;
    float s = x0 + x1;
    #pragma unroll
    for (int off = 32; off; off >>= 1) s += __shfl_xor(s, off, 64);
    float mu = s * (1.0f / 128.0f);
    float d0 = x0 - mu, d1 = x1 - mu;
    float vv = d0 * d0 + d1 * d1;
    #pragma unroll
    for (int off = 32; off; off >>= 1) vv += __shfl_xor(vv, off, 64);
    float rstd = 1.0f / sqrtf(vv * (1.0f / 128.0f) + LN_EPS);
    float2 vg  = *(const float2*)(g + lane * 2);
    float2 vbl = *(const float2*)(bln + lane * 2);
    float y0 = fmaxf(d0 * rstd * vg.x + vbl.x, 0.0f);
    float y1 = fmaxf(d1 * rstd * vg.y + vbl.y, 0.0f);
    *(float2*)(outbuf + (size_t)wid * 128 + lane * 2) = make_float2(y0, y1);
    outhf[(size_t)wid * 64 + lane] = pack_h2(y0, y1);
    float ns = y0 * y0 + y1 * y1;
    #pragma unroll
    for (int off = 32; off; off >>= 1) ns += __shfl_xor(ns, off, 64);
    if (lane == 0) nrm[wid] = fmaxf(sqrtf(ns), EPSF);
}

// layer 2: v = dinv2[c]*sum(val*g2s[row]) + cself*g2s[c] + b2; log_softmax
// g2s is fp16 (pre-scaled by dinv2[row]); 4 gathers in flight
__global__ __launch_bounds__(256) void gather_lsm_hf_k(const u16* __restrict__ g2s,
    const int2* __restrict__ kv, const int* __restrict__ startAll,
    const int* __restrict__ cntK, const float* __restrict__ dinv2,
    const float* __restrict__ cself, const float* __restrict__ b2,
    float* __restrict__ out, int n) {
    int wid  = (blockIdx.x * 256 + threadIdx.x) >> 6;
    int lane = threadIdx.x & 63;
    if (wid >= n) return;
    int s0 = startAll[wid], k = cntK[wid];
    float acc = 0.f;
    int j = 0;
    for (; j + 3 < k; j += 4) {
        int2 p0 = kv[s0 + j], p1 = kv[s0 + j + 1];
        int2 p2 = kv[s0 + j + 2], p3 = kv[s0 + j + 3];
        float g0 = h2f(g2s[(size_t)p0.x * 64 + lane]);
        float g1 = h2f(g2s[(size_t)p1.x * 64 + lane]);
        float g2 = h2f(g2s[(size_t)p2.x * 64 + lane]);
        float g3 = h2f(g2s[(size_t)p3.x * 64 + lane]);
        acc += __int_as_float(p0.y) * g0 + __int_as_float(p1.y) * g1
             + __int_as_float(p2.y) * g2 + __int_as_float(p3.y) * g3;
    }
    for (; j < k; ++j) {
        int2 p0 = kv[s0 + j];
        acc += __int_as_float(p0.y) * h2f(g2s[(size_t)p0.x * 64 + lane]);
    }
    float gs = h2f(g2s[(size_t)wid * 64 + lane]);
    float v = dinv2[wid] * acc + cself[wid] * gs + b2[lane];
    float m = v;
    #pragma unroll
    for (int off = 32; off; off >>= 1) m = fmaxf(m, __shfl_xor(m, off, 64));
    float e = expf(v - m);
    float s = e;
    #pragma unroll
    for (int off = 32; off; off >>= 1) s += __shfl_xor(s, off, 64);
    out[(size_t)wid * 64 + lane] = v - m - logf(s);
}

// ---------------- launch ----------------

extern "C" void kernel_launch(void* const* d_in, const int* in_sizes, int n_in,
                              void* d_out, int out_size, void* d_ws, size_t ws_size,
                              hipStream_t stream) {
    (void)n_in; (void)out_size; (void)ws_size;
    const float* x   = (const float*)d_in[0];
    const int*   row = (const int*)d_in[1];
    const int*   col = (const int*)d_in[2];
    const float* W1  = (const float*)d_in[3];
    const float* b1  = (const float*)d_in[4];
    const float* lng = (const float*)d_in[5];
    const float* lnb = (const float*)d_in[6];
    const float* W2  = (const float*)d_in[7];
    const float* b2  = (const float*)d_in[8];
    float* out = (float*)d_out;

    const int N = in_sizes[0] / 128;
    const int E = in_sizes[1];

    int*   cntAll   = (int*)d_ws;
    int*   startAll = cntAll + N;
    int*   bsum     = startAll + N;            // 512 ints
    float* nrm      = (float*)(bsum + 512);
    float* deg1     = nrm + N;                 // zeroed per layer
    float* dinv2    = deg1 + N;
    float* cself    = dinv2 + N;
    int*   cntK     = (int*)(cself + N);       // CSR-build cursor, then kept counts
    int*   rowAll   = cntK + N;                // [E]
    int2*  kvp      = (int2*)(rowAll + E);     // [E] packed (row, val)
    u32*   fhf      = (u32*)(kvp + E);         // [64N] u32 = [128N] fp16; reused as h2hf
    u16*   g2shf    = (u16*)(fhf + (size_t)64 * N);  // [64N] fp16
    float* big      = (float*)(g2shf + (size_t)64 * N);
    float* sims     = big;                     // [E]  (dead before hs is written)
    float* hs       = big;                     // [128N] layer-1 scaled h
    float* h2       = big + (size_t)128 * N;   // [128N] layer-1 output (persists)

    const int nodeBlocks = (N + 255) / 256;
    const int waveBlocks = (N + 3) / 4;
    const int edgeBlocks = (E + 255) / 256;
    const int scanBlocks = nodeBlocks;         // <= 512 for N <= 131072

    // ---- one-time CSR build (shared by both layers) ----
    hipMemsetAsync(cntAll, 0, (size_t)N * sizeof(int), stream);
    count_k<<<edgeBlocks, 256, 0, stream>>>(col, cntAll, E);
    scan1_k<<<scanBlocks, 256, 0, stream>>>(cntAll, startAll, bsum, N);
    scan2_k<<<1, 512, 0, stream>>>(bsum, scanBlocks);
    scan3_k<<<scanBlocks, 256, 0, stream>>>(startAll, bsum, N);
    hipMemsetAsync(cntK, 0, (size_t)N * sizeof(int), stream);
    fill_k<<<edgeBlocks, 256, 0, stream>>>(row, col, startAll, cntK, rowAll, E);

    // ================= layer 1 =================
    hipMemsetAsync(deg1, 0, (size_t)N * sizeof(float), stream);
    cast_norm_k<<<waveBlocks, 256, 0, stream>>>(x, fhf, nrm, N);
    edge_dot_hf_k<<<waveBlocks, 256, 0, stream>>>(fhf, x, rowAll, startAll, cntAll, nrm,
                                                  sims, deg1, N);
    edge_c_csr_k<<<waveBlocks, 256, 0, stream>>>(sims, rowAll, startAll, cntAll, deg1,
                                                 kvp, cntK, dinv2, cself, N);
    gemm128_k<<<(N + 31) / 32, 256, 0, stream>>>(x, W1, dinv2, hs, N);
    gather_ln_k<<<waveBlocks, 256, 0, stream>>>(hs, kvp, startAll, cntK, dinv2, cself,
                                                b1, lng, lnb, h2, fhf, nrm, N);

    // ================= layer 2 =================
    hipMemsetAsync(deg1, 0, (size_t)N * sizeof(float), stream);
    edge_dot_hf_k<<<waveBlocks, 256, 0, stream>>>(fhf, h2, rowAll, startAll, cntAll, nrm,
                                                  sims, deg1, N);
    edge_c_csr_k<<<waveBlocks, 256, 0, stream>>>(sims, rowAll, startAll, cntAll, deg1,
                                                 kvp, cntK, dinv2, cself, N);
    gemm64_hf_k<<<(N + 63) / 64, 256, 0, stream>>>(h2, W2, dinv2, (u32*)g2shf, N);
    gather_lsm_hf_k<<<waveBlocks, 256, 0, stream>>>(g2shf, kvp, startAll, cntK, dinv2,
                                                    cself, b2, out, N);
}

// Round 8
// 759.292 us; speedup vs baseline: 2.0037x; 1.0140x over previous
//
#include <hip/hip_runtime.h>
#include <math.h>

#define EPSF 1e-8f
#define LN_EPS 1e-5f
#define BL_MARGIN 0.002f   // > bound on fp16 unit-vector cosine-sim error (~1.5e-3)

typedef unsigned int  u32;
typedef unsigned short u16;
typedef _Float16 h2_t __attribute__((ext_vector_type(2)));

static __device__ inline u32 pack_h2(float a, float b) {
    h2_t h; h.x = (_Float16)a; h.y = (_Float16)b;
    return __builtin_bit_cast(u32, h);
}
static __device__ inline float h2f(u16 h) {
    return (float)__builtin_bit_cast(_Float16, h);
}
static __device__ inline float fdot2_u32(u32 a, u32 b, float c) {
    return __builtin_amdgcn_fdot2(__builtin_bit_cast(h2_t, a),
                                  __builtin_bit_cast(h2_t, b), c, false);
}

// ---------------- layer-1 prep: norms + UNIT-vector fp16 cast ----------------
// one wave per node: sim = dot(unit_a, unit_b) downstream — no nrm gather per edge
__global__ __launch_bounds__(256) void cast_norm_k(const float* __restrict__ feat,
    u32* __restrict__ fhf, float* __restrict__ nrm, int n) {
    int wid  = (blockIdx.x * 256 + threadIdx.x) >> 6;
    int lane = threadIdx.x & 63;
    if (wid >= n) return;
    float2 v = *(const float2*)(feat + (size_t)wid * 128 + lane * 2);
    float s = v.x * v.x + v.y * v.y;
    #pragma unroll
    for (int off = 32; off; off >>= 1) s += __shfl_xor(s, off, 64);
    float nv = fmaxf(sqrtf(s), EPSF);
    float inv = 1.0f / nv;
    fhf[(size_t)wid * 64 + lane] = pack_h2(v.x * inv, v.y * inv);
    if (lane == 0) nrm[wid] = nv;
}

// ---------------- one-time CSR build ----------------

__global__ __launch_bounds__(256) void count_k(const int* __restrict__ col,
                                               int* __restrict__ cntAll, int ecnt) {
    int e = blockIdx.x * 256 + threadIdx.x;
    if (e < ecnt) atomicAdd(&cntAll[col[e]], 1);
}

__global__ __launch_bounds__(256) void scan1_k(const int* __restrict__ cnt,
    int* __restrict__ colStart, int* __restrict__ bsum, int n) {
    __shared__ int tmp[256];
    int i = blockIdx.x * 256 + threadIdx.x;
    int v = (i < n) ? cnt[i] : 0;
    tmp[threadIdx.x] = v; __syncthreads();
    for (int off = 1; off < 256; off <<= 1) {
        int t = (threadIdx.x >= off) ? tmp[threadIdx.x - off] : 0;
        __syncthreads();
        tmp[threadIdx.x] += t;
        __syncthreads();
    }
    if (i < n) colStart[i] = tmp[threadIdx.x] - v;   // exclusive
    if (threadIdx.x == 255) bsum[blockIdx.x] = tmp[255];
}

__global__ __launch_bounds__(512) void scan2_k(int* __restrict__ bsum, int nb) {
    __shared__ int tmp[512];
    int v = (threadIdx.x < nb) ? bsum[threadIdx.x] : 0;
    tmp[threadIdx.x] = v; __syncthreads();
    for (int off = 1; off < 512; off <<= 1) {
        int t = (threadIdx.x >= off) ? tmp[threadIdx.x - off] : 0;
        __syncthreads();
        tmp[threadIdx.x] += t;
        __syncthreads();
    }
    if (threadIdx.x < nb) bsum[threadIdx.x] = tmp[threadIdx.x] - v;  // exclusive
}

__global__ __launch_bounds__(256) void scan3_k(int* __restrict__ colStart,
    const int* __restrict__ bsum, int n) {
    int i = blockIdx.x * 256 + threadIdx.x;
    if (i < n) colStart[i] += bsum[blockIdx.x];
}

__global__ __launch_bounds__(256) void fill_k(const int* __restrict__ row,
    const int* __restrict__ col, const int* __restrict__ startAll,
    int* __restrict__ cur, int* __restrict__ rowAll, int ecnt) {
    int e = blockIdx.x * 256 + threadIdx.x;
    if (e >= ecnt) return;
    int c = col[e];
    int p = startAll[c] + atomicAdd(&cur[c], 1);
    rowAll[p] = row[e];
}

// ---------------- edge phase A: fp16 unit-vector sims, 8 edges in flight --------
// one wave per col node; 2 edges per 16-lane group concurrently (MLP: 8x16B
// outstanding per wave — r7 was latency-bound at 4). Borderline edges
// recomputed inline in fp32 (nrm used only there).
__global__ __launch_bounds__(256) void edge_dot_hf_k(const u32* __restrict__ fhf,
    const float* __restrict__ feat32,
    const int* __restrict__ rowAll, const int* __restrict__ startAll,
    const int* __restrict__ cntAll, const float* __restrict__ nrm,
    float* __restrict__ sims, float* __restrict__ deg1, int n) {
    int wid  = (blockIdx.x * 256 + threadIdx.x) >> 6;
    int lane = threadIdx.x & 63;
    if (wid >= n) return;
    int s0 = startAll[wid], cnt = cntAll[wid];
    if (cnt == 0) return;
    int q = lane >> 4, l = lane & 15;
    uint4 fc = *(const uint4*)(fhf + (size_t)wid * 64 + l * 4);
    float nc = nrm[wid];
    int cm1 = cnt - 1;
    for (int jj = 0; jj < cnt; jj += 8) {
        int j0 = jj + q, j1 = jj + 4 + q;
        bool a0 = j0 < cnt, a1 = j1 < cnt;
        int r0 = rowAll[s0 + min(j0, cm1)];
        int r1 = rowAll[s0 + min(j1, cm1)];
        uint4 f0 = *(const uint4*)(fhf + (size_t)r0 * 64 + l * 4);
        uint4 f1 = *(const uint4*)(fhf + (size_t)r1 * 64 + l * 4);
        float p0 = fdot2_u32(f0.x, fc.x, 0.0f);
        float p1 = fdot2_u32(f1.x, fc.x, 0.0f);
        p0 = fdot2_u32(f0.y, fc.y, p0);
        p1 = fdot2_u32(f1.y, fc.y, p1);
        p0 = fdot2_u32(f0.z, fc.z, p0);
        p1 = fdot2_u32(f1.z, fc.z, p1);
        p0 = fdot2_u32(f0.w, fc.w, p0);
        p1 = fdot2_u32(f1.w, fc.w, p1);
        #pragma unroll
        for (int off = 8; off; off >>= 1) {
            p0 += __shfl_xor(p0, off, 64);
            p1 += __shfl_xor(p1, off, 64);
        }
        if (a0 && fabsf(p0 - 0.1f) < BL_MARGIN) {
            const float4* fr = (const float4*)(feat32 + (size_t)r0 * 128);
            const float4* fq = (const float4*)(feat32 + (size_t)wid * 128);
            float4 x0 = fr[l * 2], x1 = fr[l * 2 + 1];
            float4 y0 = fq[l * 2], y1 = fq[l * 2 + 1];
            float s2 = x0.x*y0.x + x0.y*y0.y + x0.z*y0.z + x0.w*y0.w
                     + x1.x*y1.x + x1.y*y1.y + x1.z*y1.z + x1.w*y1.w;
            #pragma unroll
            for (int off = 8; off; off >>= 1) s2 += __shfl_xor(s2, off, 64);
            p0 = s2 / (nrm[r0] * nc);
        }
        if (a1 && fabsf(p1 - 0.1f) < BL_MARGIN) {
            const float4* fr = (const float4*)(feat32 + (size_t)r1 * 128);
            const float4* fq = (const float4*)(feat32 + (size_t)wid * 128);
            float4 x0 = fr[l * 2], x1 = fr[l * 2 + 1];
            float4 y0 = fq[l * 2], y1 = fq[l * 2 + 1];
            float s2 = x0.x*y0.x + x0.y*y0.y + x0.z*y0.z + x0.w*y0.w
                     + x1.x*y1.x + x1.y*y1.y + x1.z*y1.z + x1.w*y1.w;
            #pragma unroll
            for (int off = 8; off; off >>= 1) s2 += __shfl_xor(s2, off, 64);
            p1 = s2 / (nrm[r1] * nc);
        }
        if (l == 0) {
            if (a0) {
                float kv = (p0 >= 0.1f) ? p0 : 0.0f;
                sims[s0 + j0] = kv;
                if (kv > 0.0f) atomicAdd(&deg1[r0], kv);
            }
            if (a1) {
                float kv = (p1 >= 0.1f) ? p1 : 0.0f;
                sims[s0 + j1] = kv;
                if (kv > 0.0f) atomicAdd(&deg1[r1], kv);
            }
        }
    }
}

// ---------------- edge phase B: vals + in-wave deg2 + compaction ----------------
__global__ __launch_bounds__(256) void edge_c_csr_k(const float* __restrict__ sims,
    const int* __restrict__ rowAll, const int* __restrict__ startAll,
    const int* __restrict__ cntAll, const float* __restrict__ deg1,
    int2* __restrict__ kv, int* __restrict__ cntK, float* __restrict__ dinv2,
    float* __restrict__ cself, int n) {
    int wid  = (blockIdx.x * 256 + threadIdx.x) >> 6;
    int lane = threadIdx.x & 63;
    if (wid >= n) return;
    int s0 = startAll[wid], cnt = cntAll[wid];
    float degc = deg1[wid];
    float d1c = (degc > 0.0f) ? 1.0f / sqrtf(degc) : 0.0f;
    float vsum = 0.0f; int kc = 0;
    for (int jj = 0; jj < cnt; jj += 64) {
        int j = jj + lane;
        bool keep = false; int r = 0; float v = 0.0f;
        if (j < cnt) {
            float s = sims[s0 + j];
            if (s > 0.0f) {
                r = rowAll[s0 + j];
                float dr = 1.0f / sqrtf(deg1[r]);     // deg1[r] >= s >= 0.1
                v = expf(dr * s * d1c);
                keep = true;
            }
        }
        unsigned long long m = __ballot(keep ? 1 : 0);
        if (keep) {
            int pre = __popcll(m & ((1ull << lane) - 1ull));
            int2 pk; pk.x = r; pk.y = __float_as_int(v);
            kv[s0 + kc + pre] = pk;
            vsum += v;
        }
        kc += __popcll(m);
    }
    #pragma unroll
    for (int off = 32; off; off >>= 1) vsum += __shfl_xor(vsum, off, 64);
    if (lane == 0) {
        float ws_ = expf(1.0f / ((float)kc + 1.0f));   // self-loop weight
        float dg = ws_ + vsum;                         // always > 0
        float di = 1.0f / sqrtf(dg);
        dinv2[wid] = di;
        cself[wid] = di * ws_;      // self term uses dinv2-scaled h, so one di here
        cntK[wid]  = kc;
    }
}

// ---------------- GEMMs (K=128), register-tiled: 4 nodes x 4 outputs / thread ----

__global__ __launch_bounds__(256) void gemm128_k(const float* __restrict__ A,
    const float* __restrict__ W, const float* __restrict__ scale,
    float* __restrict__ out, int n) {
    __shared__ float Ws[128 * 128];
    for (int i = threadIdx.x; i < 128 * 128 / 4; i += 256)
        ((float4*)Ws)[i] = ((const float4*)W)[i];
    __syncthreads();
    const int TPN = 32;
    int group = threadIdx.x / TPN;            // 8 groups -> 32 nodes/block
    int tin   = threadIdx.x % TPN;
    int nid   = (blockIdx.x * 8 + group) * 4;
    if (nid >= n) return;
    int dbase = tin * 4;
    int nm1 = n - 1;
    const float4* a0 = (const float4*)(A + (size_t)min(nid,     nm1) * 128);
    const float4* a1 = (const float4*)(A + (size_t)min(nid + 1, nm1) * 128);
    const float4* a2 = (const float4*)(A + (size_t)min(nid + 2, nm1) * 128);
    const float4* a3 = (const float4*)(A + (size_t)min(nid + 3, nm1) * 128);
    float4 acc0 = {0,0,0,0}, acc1 = {0,0,0,0}, acc2 = {0,0,0,0}, acc3 = {0,0,0,0};
    #pragma unroll 2
    for (int k4 = 0; k4 < 32; ++k4) {
        const float* wr = Ws + (k4 * 4) * 128 + dbase;
        float4 w0 = *(const float4*)(wr);
        float4 w1 = *(const float4*)(wr + 128);
        float4 w2 = *(const float4*)(wr + 256);
        float4 w3 = *(const float4*)(wr + 384);
        float4 v0 = a0[k4], v1 = a1[k4], v2 = a2[k4], v3 = a3[k4];
        acc0.x += v0.x*w0.x + v0.y*w1.x + v0.z*w2.x + v0.w*w3.x;
        acc0.y += v0.x*w0.y + v0.y*w1.y + v0.z*w2.y + v0.w*w3.y;
        acc0.z += v0.x*w0.z + v0.y*w1.z + v0.z*w2.z + v0.w*w3.z;
        acc0.w += v0.x*w0.w + v0.y*w1.w + v0.z*w2.w + v0.w*w3.w;
        acc1.x += v1.x*w0.x + v1.y*w1.x + v1.z*w2.x + v1.w*w3.x;
        acc1.y += v1.x*w0.y + v1.y*w1.y + v1.z*w2.y + v1.w*w3.y;
        acc1.z += v1.x*w0.z + v1.y*w1.z + v1.z*w2.z + v1.w*w3.z;
        acc1.w += v1.x*w0.w + v1.y*w1.w + v1.z*w2.w + v1.w*w3.w;
        acc2.x += v2.x*w0.x + v2.y*w1.x + v2.z*w2.x + v2.w*w3.x;
        acc2.y += v2.x*w0.y + v2.y*w1.y + v2.z*w2.y + v2.w*w3.y;
        acc2.z += v2.x*w0.z + v2.y*w1.z + v2.z*w2.z + v2.w*w3.z;
        acc2.w += v2.x*w0.w + v2.y*w1.w + v2.z*w2.w + v2.w*w3.w;
        acc3.x += v3.x*w0.x + v3.y*w1.x + v3.z*w2.x + v3.w*w3.x;
        acc3.y += v3.x*w0.y + v3.y*w1.y + v3.z*w2.y + v3.w*w3.y;
        acc3.z += v3.x*w0.z + v3.y*w1.z + v3.z*w2.z + v3.w*w3.z;
        acc3.w += v3.x*w0.w + v3.y*w1.w + v3.z*w2.w + v3.w*w3.w;
    }
    float4 accs[4] = {acc0, acc1, acc2, acc3};
    #pragma unroll
    for (int i = 0; i < 4; ++i) {
        if (nid + i < n) {
            float sc = scale[nid + i];
            float4 r; r.x = accs[i].x * sc; r.y = accs[i].y * sc;
            r.z = accs[i].z * sc; r.w = accs[i].w * sc;
            *(float4*)(out + (size_t)(nid + i) * 128 + dbase) = r;
        }
    }
}

// DOUT=64 variant, fp16 output
__global__ __launch_bounds__(256) void gemm64_hf_k(const float* __restrict__ A,
    const float* __restrict__ W, const float* __restrict__ scale,
    u32* __restrict__ outhf, int n) {
    __shared__ float Ws[128 * 64];
    for (int i = threadIdx.x; i < 128 * 64 / 4; i += 256)
        ((float4*)Ws)[i] = ((const float4*)W)[i];
    __syncthreads();
    const int TPN = 16;
    int group = threadIdx.x / TPN;            // 16 groups -> 64 nodes/block
    int tin   = threadIdx.x % TPN;
    int nid   = (blockIdx.x * 16 + group) * 4;
    if (nid >= n) return;
    int dbase = tin * 4;
    int nm1 = n - 1;
    const float4* a0 = (const float4*)(A + (size_t)min(nid,     nm1) * 128);
    const float4* a1 = (const float4*)(A + (size_t)min(nid + 1, nm1) * 128);
    const float4* a2 = (const float4*)(A + (size_t)min(nid + 2, nm1) * 128);
    const float4* a3 = (const float4*)(A + (size_t)min(nid + 3, nm1) * 128);
    float4 acc0 = {0,0,0,0}, acc1 = {0,0,0,0}, acc2 = {0,0,0,0}, acc3 = {0,0,0,0};
    #pragma unroll 2
    for (int k4 = 0; k4 < 32; ++k4) {
        const float* wr = Ws + (k4 * 4) * 64 + dbase;
        float4 w0 = *(const float4*)(wr);
        float4 w1 = *(const float4*)(wr + 64);
        float4 w2 = *(const float4*)(wr + 128);
        float4 w3 = *(const float4*)(wr + 192);
        float4 v0 = a0[k4], v1 = a1[k4], v2 = a2[k4], v3 = a3[k4];
        acc0.x += v0.x*w0.x + v0.y*w1.x + v0.z*w2.x + v0.w*w3.x;
        acc0.y += v0.x*w0.y + v0.y*w1.y + v0.z*w2.y + v0.w*w3.y;
        acc0.z += v0.x*w0.z + v0.y*w1.z + v0.z*w2.z + v0.w*w3.z;
        acc0.w += v0.x*w0.w + v0.y*w1.w + v0.z*w2.w + v0.w*w3.w;
        acc1.x += v1.x*w0.x + v1.y*w1.x + v1.z*w2.x + v1.w*w3.x;
        acc1.y += v1.x*w0.y + v1.y*w1.y + v1.z*w2.y + v1.w*w3.y;
        acc1.z += v1.x*w0.z + v1.y*w1.z + v1.z*w2.z + v1.w*w3.z;
        acc1.w += v1.x*w0.w + v1.y*w1.w + v1.z*w2.w + v1.w*w3.w;
        acc2.x += v2.x*w0.x + v2.y*w1.x + v2.z*w2.x + v2.w*w3.x;
        acc2.y += v2.x*w0.y + v2.y*w1.y + v2.z*w2.y + v2.w*w3.y;
        acc2.z += v2.x*w0.z + v2.y*w1.z + v2.z*w2.z + v2.w*w3.z;
        acc2.w += v2.x*w0.w + v2.y*w1.w + v2.z*w2.w + v2.w*w3.w;
        acc3.x += v3.x*w0.x + v3.y*w1.x + v3.z*w2.x + v3.w*w3.x;
        acc3.y += v3.x*w0.y + v3.y*w1.y + v3.z*w2.y + v3.w*w3.y;
        acc3.z += v3.x*w0.z + v3.y*w1.z + v3.z*w2.z + v3.w*w3.z;
        acc3.w += v3.x*w0.w + v3.y*w1.w + v3.z*w2.w + v3.w*w3.w;
    }
    float4 accs[4] = {acc0, acc1, acc2, acc3};
    #pragma unroll
    for (int i = 0; i < 4; ++i) {
        if (nid + i < n) {
            float sc = scale[nid + i];
            u32 o0 = pack_h2(accs[i].x * sc, accs[i].y * sc);
            u32 o1 = pack_h2(accs[i].z * sc, accs[i].w * sc);
            *(uint2*)(outhf + (size_t)(nid + i) * 32 + tin * 2) = make_uint2(o0, o1);
        }
    }
}

// ---------------- fused gather epilogues ----------------

// layer 1: x = dinv2[c]*sum(val*hs[row]) + cself*hs[c] + bias; LN; ReLU
// writes h2 (fp32), h2hf (UNIT fp16 for layer-2 sims), nrm (layer-2 norms)
__global__ __launch_bounds__(256) void gather_ln_k(const float* __restrict__ hs,
    const int2* __restrict__ kv, const int* __restrict__ startAll,
    const int* __restrict__ cntK, const float* __restrict__ dinv2,
    const float* __restrict__ cself, const float* __restrict__ bias,
    const float* __restrict__ g, const float* __restrict__ bln,
    float* __restrict__ outbuf, u32* __restrict__ outhf,
    float* __restrict__ nrm, int n) {
    int wid  = (blockIdx.x * 256 + threadIdx.x) >> 6;
    int lane = threadIdx.x & 63;
    if (wid >= n) return;
    int s0 = startAll[wid], k = cntK[wid];
    float a0 = 0.f, a1 = 0.f;
    int j = 0;
    for (; j + 7 < k; j += 8) {
        int2 p0 = kv[s0+j],   p1 = kv[s0+j+1], p2 = kv[s0+j+2], p3 = kv[s0+j+3];
        int2 p4 = kv[s0+j+4], p5 = kv[s0+j+5], p6 = kv[s0+j+6], p7 = kv[s0+j+7];
        float2 h0 = *(const float2*)(hs + (size_t)p0.x * 128 + lane * 2);
        float2 h1 = *(const float2*)(hs + (size_t)p1.x * 128 + lane * 2);
        float2 h2v = *(const float2*)(hs + (size_t)p2.x * 128 + lane * 2);
        float2 h3 = *(const float2*)(hs + (size_t)p3.x * 128 + lane * 2);
        float2 h4 = *(const float2*)(hs + (size_t)p4.x * 128 + lane * 2);
        float2 h5 = *(const float2*)(hs + (size_t)p5.x * 128 + lane * 2);
        float2 h6 = *(const float2*)(hs + (size_t)p6.x * 128 + lane * 2);
        float2 h7 = *(const float2*)(hs + (size_t)p7.x * 128 + lane * 2);
        float v0 = __int_as_float(p0.y), v1 = __int_as_float(p1.y);
        float v2 = __int_as_float(p2.y), v3 = __int_as_float(p3.y);
        float v4 = __int_as_float(p4.y), v5 = __int_as_float(p5.y);
        float v6 = __int_as_float(p6.y), v7 = __int_as_float(p7.y);
        a0 += v0*h0.x + v1*h1.x + v2*h2v.x + v3*h3.x
            + v4*h4.x + v5*h5.x + v6*h6.x + v7*h7.x;
        a1 += v0*h0.y + v1*h1.y + v2*h2v.y + v3*h3.y
            + v4*h4.y + v5*h5.y + v6*h6.y + v7*h7.y;
    }
    for (; j < k; ++j) {
        int2 p0 = kv[s0 + j];
        float2 h0 = *(const float2*)(hs + (size_t)p0.x * 128 + lane * 2);
        float v0 = __int_as_float(p0.y);
        a0 += v0 * h0.x; a1 += v0 * h0.y;
    }
    float di = dinv2[wid], cs = cself[wid];
    float2 hsv = *(const float2*)(hs + (size_t)wid * 128 + lane * 2);
    float2 vb  = *(const float2*)(bias + lane * 2);
    float x0 = di * a0 + cs * hsv.x + vb.x;
    float x1 = di * a1 + cs * hsv.y + vb.y;
    float s = x0 + x1;
    #pragma unroll
    for (int off = 32; off; off >>= 1) s += __shfl_xor(s, off, 64);
    float mu = s * (1.0f / 128.0f);
    float d0 = x0 - mu, d1 = x1 - mu;
    float vv = d0 * d0 + d1 * d1;
    #pragma unroll
    for (int off = 32; off; off >>= 1) vv += __shfl_xor(vv, off, 64);
    float rstd = 1.0f / sqrtf(vv * (1.0f / 128.0f) + LN_EPS);
    float2 vg  = *(const float2*)(g + lane * 2);
    float2 vbl = *(const float2*)(bln + lane * 2);
    float y0 = fmaxf(d0 * rstd * vg.x + vbl.x, 0.0f);
    float y1 = fmaxf(d1 * rstd * vg.y + vbl.y, 0.0f);
    *(float2*)(outbuf + (size_t)wid * 128 + lane * 2) = make_float2(y0, y1);
    float ns = y0 * y0 + y1 * y1;
    #pragma unroll
    for (int off = 32; off; off >>= 1) ns += __shfl_xor(ns, off, 64);
    float nv = fmaxf(sqrtf(ns), EPSF);
    float inv = 1.0f / nv;
    outhf[(size_t)wid * 64 + lane] = pack_h2(y0 * inv, y1 * inv);
    if (lane == 0) nrm[wid] = nv;
}

// layer 2: v = dinv2[c]*sum(val*g2s[row]) + cself*g2s[c] + b2; log_softmax
// g2s is fp16 (pre-scaled by dinv2[row]); 8 gathers in flight
__global__ __launch_bounds__(256) void gather_lsm_hf_k(const u16* __restrict__ g2s,
    const int2* __restrict__ kv, const int* __restrict__ startAll,
    const int* __restrict__ cntK, const float* __restrict__ dinv2,
    const float* __restrict__ cself, const float* __restrict__ b2,
    float* __restrict__ out, int n) {
    int wid  = (blockIdx.x * 256 + threadIdx.x) >> 6;
    int lane = threadIdx.x & 63;
    if (wid >= n) return;
    int s0 = startAll[wid], k = cntK[wid];
    float acc = 0.f;
    int j = 0;
    for (; j + 7 < k; j += 8) {
        int2 p0 = kv[s0+j],   p1 = kv[s0+j+1], p2 = kv[s0+j+2], p3 = kv[s0+j+3];
        int2 p4 = kv[s0+j+4], p5 = kv[s0+j+5], p6 = kv[s0+j+6], p7 = kv[s0+j+7];
        float g0 = h2f(g2s[(size_t)p0.x * 64 + lane]);
        float g1 = h2f(g2s[(size_t)p1.x * 64 + lane]);
        float g2 = h2f(g2s[(size_t)p2.x * 64 + lane]);
        float g3 = h2f(g2s[(size_t)p3.x * 64 + lane]);
        float g4 = h2f(g2s[(size_t)p4.x * 64 + lane]);
        float g5 = h2f(g2s[(size_t)p5.x * 64 + lane]);
        float g6 = h2f(g2s[(size_t)p6.x * 64 + lane]);
        float g7 = h2f(g2s[(size_t)p7.x * 64 + lane]);
        acc += __int_as_float(p0.y)*g0 + __int_as_float(p1.y)*g1
             + __int_as_float(p2.y)*g2 + __int_as_float(p3.y)*g3
             + __int_as_float(p4.y)*g4 + __int_as_float(p5.y)*g5
             + __int_as_float(p6.y)*g6 + __int_as_float(p7.y)*g7;
    }
    for (; j < k; ++j) {
        int2 p0 = kv[s0 + j];
        acc += __int_as_float(p0.y) * h2f(g2s[(size_t)p0.x * 64 + lane]);
    }
    float gs = h2f(g2s[(size_t)wid * 64 + lane]);
    float v = dinv2[wid] * acc + cself[wid] * gs + b2[lane];
    float m = v;
    #pragma unroll
    for (int off = 32; off; off >>= 1) m = fmaxf(m, __shfl_xor(m, off, 64));
    float e = expf(v - m);
    float s = e;
    #pragma unroll
    for (int off = 32; off; off >>= 1) s += __shfl_xor(s, off, 64);
    out[(size_t)wid * 64 + lane] = v - m - logf(s);
}

// ---------------- launch ----------------

extern "C" void kernel_launch(void* const* d_in, const int* in_sizes, int n_in,
                              void* d_out, int out_size, void* d_ws, size_t ws_size,
                              hipStream_t stream) {
    (void)n_in; (void)out_size; (void)ws_size;
    const float* x   = (const float*)d_in[0];
    const int*   row = (const int*)d_in[1];
    const int*   col = (const int*)d_in[2];
    const float* W1  = (const float*)d_in[3];
    const float* b1  = (const float*)d_in[4];
    const float* lng = (const float*)d_in[5];
    const float* lnb = (const float*)d_in[6];
    const float* W2  = (const float*)d_in[7];
    const float* b2  = (const float*)d_in[8];
    float* out = (float*)d_out;

    const int N = in_sizes[0] / 128;
    const int E = in_sizes[1];

    int*   cntAll   = (int*)d_ws;
    int*   startAll = cntAll + N;
    int*   bsum     = startAll + N;            // 512 ints
    float* nrm      = (float*)(bsum + 512);
    float* deg1     = nrm + N;                 // zeroed per layer
    float* dinv2    = deg1 + N;
    float* cself    = dinv2 + N;
    int*   cntK     = (int*)(cself + N);       // CSR-build cursor, then kept counts
    int*   rowAll   = cntK + N;                // [E]
    int2*  kvp      = (int2*)(rowAll + E);     // [E] packed (row, val)
    u32*   fhf      = (u32*)(kvp + E);         // [64N] u32 = [128N] fp16; reused as h2hf
    u16*   g2shf    = (u16*)(fhf + (size_t)64 * N);  // [64N] fp16
    float* big      = (float*)(g2shf + (size_t)64 * N);
    float* sims     = big;                     // [E]  (dead before hs is written)
    float* hs       = big;                     // [128N] layer-1 scaled h
    float* h2       = big + (size_t)128 * N;   // [128N] layer-1 output (persists)

    const int nodeBlocks = (N + 255) / 256;
    const int waveBlocks = (N + 3) / 4;
    const int edgeBlocks = (E + 255) / 256;
    const int scanBlocks = nodeBlocks;         // <= 512 for N <= 131072

    // ---- one-time CSR build (shared by both layers) ----
    hipMemsetAsync(cntAll, 0, (size_t)N * sizeof(int), stream);
    count_k<<<edgeBlocks, 256, 0, stream>>>(col, cntAll, E);
    scan1_k<<<scanBlocks, 256, 0, stream>>>(cntAll, startAll, bsum, N);
    scan2_k<<<1, 512, 0, stream>>>(bsum, scanBlocks);
    scan3_k<<<scanBlocks, 256, 0, stream>>>(startAll, bsum, N);
    hipMemsetAsync(cntK, 0, (size_t)N * sizeof(int), stream);
    fill_k<<<edgeBlocks, 256, 0, stream>>>(row, col, startAll, cntK, rowAll, E);

    // ================= layer 1 =================
    hipMemsetAsync(deg1, 0, (size_t)N * sizeof(float), stream);
    cast_norm_k<<<waveBlocks, 256, 0, stream>>>(x, fhf, nrm, N);
    edge_dot_hf_k<<<waveBlocks, 256, 0, stream>>>(fhf, x, rowAll, startAll, cntAll, nrm,
                                                  sims, deg1, N);
    edge_c_csr_k<<<waveBlocks, 256, 0, stream>>>(sims, rowAll, startAll, cntAll, deg1,
                                                 kvp, cntK, dinv2, cself, N);
    gemm128_k<<<(N + 31) / 32, 256, 0, stream>>>(x, W1, dinv2, hs, N);
    gather_ln_k<<<waveBlocks, 256, 0, stream>>>(hs, kvp, startAll, cntK, dinv2, cself,
                                                b1, lng, lnb, h2, fhf, nrm, N);

    // ================= layer 2 =================
    hipMemsetAsync(deg1, 0, (size_t)N * sizeof(float), stream);
    edge_dot_hf_k<<<waveBlocks, 256, 0, stream>>>(fhf, h2, rowAll, startAll, cntAll, nrm,
                                                  sims, deg1, N);
    edge_c_csr_k<<<waveBlocks, 256, 0, stream>>>(sims, rowAll, startAll, cntAll, deg1,
                                                 kvp, cntK, dinv2, cself, N);
    gemm64_hf_k<<<(N + 63) / 64, 256, 0, stream>>>(h2, W2, dinv2, (u32*)g2shf, N);
    gather_lsm_hf_k<<<waveBlocks, 256, 0, stream>>>(g2shf, kvp, startAll, cntK, dinv2,
                                                    cself, b2, out, N);
}

// Round 9
// 748.111 us; speedup vs baseline: 2.0337x; 1.0149x over previous
//
#include <hip/hip_runtime.h>
#include <math.h>

#define EPSF 1e-8f
#define LN_EPS 1e-5f
#define BL_MARGIN 0.002f   // > bound on fp16 unit-vector cosine-sim error (~1.5e-3)

typedef unsigned int  u32;
typedef unsigned short u16;
typedef _Float16 h2_t __attribute__((ext_vector_type(2)));

static __device__ inline u32 pack_h2(float a, float b) {
    h2_t h; h.x = (_Float16)a; h.y = (_Float16)b;
    return __builtin_bit_cast(u32, h);
}
static __device__ inline float h2f(u16 h) {
    return (float)__builtin_bit_cast(_Float16, h);
}
static __device__ inline float fdot2_u32(u32 a, u32 b, float c) {
    return __builtin_amdgcn_fdot2(__builtin_bit_cast(h2_t, a),
                                  __builtin_bit_cast(h2_t, b), c, false);
}

// ---------------- layer-1 prep: norms + UNIT-vector fp16 cast ----------------
__global__ __launch_bounds__(256) void cast_norm_k(const float* __restrict__ feat,
    u32* __restrict__ fhf, float* __restrict__ nrm, int n) {
    int wid  = (blockIdx.x * 256 + threadIdx.x) >> 6;
    int lane = threadIdx.x & 63;
    if (wid >= n) return;
    float2 v = *(const float2*)(feat + (size_t)wid * 128 + lane * 2);
    float s = v.x * v.x + v.y * v.y;
    #pragma unroll
    for (int off = 32; off; off >>= 1) s += __shfl_xor(s, off, 64);
    float nv = fmaxf(sqrtf(s), EPSF);
    float inv = 1.0f / nv;
    fhf[(size_t)wid * 64 + lane] = pack_h2(v.x * inv, v.y * inv);
    if (lane == 0) nrm[wid] = nv;
}

// ---------------- one-time CSR build ----------------

__global__ __launch_bounds__(256) void count_k(const int* __restrict__ col,
                                               int* __restrict__ cntAll, int ecnt) {
    int e = blockIdx.x * 256 + threadIdx.x;
    if (e < ecnt) atomicAdd(&cntAll[col[e]], 1);
}

__global__ __launch_bounds__(256) void scan1_k(const int* __restrict__ cnt,
    int* __restrict__ colStart, int* __restrict__ bsum, int n) {
    __shared__ int tmp[256];
    int i = blockIdx.x * 256 + threadIdx.x;
    int v = (i < n) ? cnt[i] : 0;
    tmp[threadIdx.x] = v; __syncthreads();
    for (int off = 1; off < 256; off <<= 1) {
        int t = (threadIdx.x >= off) ? tmp[threadIdx.x - off] : 0;
        __syncthreads();
        tmp[threadIdx.x] += t;
        __syncthreads();
    }
    if (i < n) colStart[i] = tmp[threadIdx.x] - v;   // exclusive
    if (threadIdx.x == 255) bsum[blockIdx.x] = tmp[255];
}

__global__ __launch_bounds__(512) void scan2_k(int* __restrict__ bsum, int nb) {
    __shared__ int tmp[512];
    int v = (threadIdx.x < nb) ? bsum[threadIdx.x] : 0;
    tmp[threadIdx.x] = v; __syncthreads();
    for (int off = 1; off < 512; off <<= 1) {
        int t = (threadIdx.x >= off) ? tmp[threadIdx.x - off] : 0;
        __syncthreads();
        tmp[threadIdx.x] += t;
        __syncthreads();
    }
    if (threadIdx.x < nb) bsum[threadIdx.x] = tmp[threadIdx.x] - v;  // exclusive
}

__global__ __launch_bounds__(256) void scan3_k(int* __restrict__ colStart,
    const int* __restrict__ bsum, int n) {
    int i = blockIdx.x * 256 + threadIdx.x;
    if (i < n) colStart[i] += bsum[blockIdx.x];
}

__global__ __launch_bounds__(256) void fill_k(const int* __restrict__ row,
    const int* __restrict__ col, const int* __restrict__ startAll,
    int* __restrict__ cur, int* __restrict__ rowAll, int ecnt) {
    int e = blockIdx.x * 256 + threadIdx.x;
    if (e >= ecnt) return;
    int c = col[e];
    int p = startAll[c] + atomicAdd(&cur[c], 1);
    rowAll[p] = row[e];
}

// ---------------- edge phase A: fp16 unit-vector sims, 8 edges in flight --------
__global__ __launch_bounds__(256) void edge_dot_hf_k(const u32* __restrict__ fhf,
    const float* __restrict__ feat32,
    const int* __restrict__ rowAll, const int* __restrict__ startAll,
    const int* __restrict__ cntAll, const float* __restrict__ nrm,
    float* __restrict__ sims, float* __restrict__ deg1, int n) {
    int wid  = (blockIdx.x * 256 + threadIdx.x) >> 6;
    int lane = threadIdx.x & 63;
    if (wid >= n) return;
    int s0 = startAll[wid], cnt = cntAll[wid];
    if (cnt == 0) return;
    int q = lane >> 4, l = lane & 15;
    uint4 fc = *(const uint4*)(fhf + (size_t)wid * 64 + l * 4);
    float nc = nrm[wid];
    int cm1 = cnt - 1;
    for (int jj = 0; jj < cnt; jj += 8) {
        int j0 = jj + q, j1 = jj + 4 + q;
        bool a0 = j0 < cnt, a1 = j1 < cnt;
        int r0 = rowAll[s0 + min(j0, cm1)];
        int r1 = rowAll[s0 + min(j1, cm1)];
        uint4 f0 = *(const uint4*)(fhf + (size_t)r0 * 64 + l * 4);
        uint4 f1 = *(const uint4*)(fhf + (size_t)r1 * 64 + l * 4);
        float p0 = fdot2_u32(f0.x, fc.x, 0.0f);
        float p1 = fdot2_u32(f1.x, fc.x, 0.0f);
        p0 = fdot2_u32(f0.y, fc.y, p0);
        p1 = fdot2_u32(f1.y, fc.y, p1);
        p0 = fdot2_u32(f0.z, fc.z, p0);
        p1 = fdot2_u32(f1.z, fc.z, p1);
        p0 = fdot2_u32(f0.w, fc.w, p0);
        p1 = fdot2_u32(f1.w, fc.w, p1);
        #pragma unroll
        for (int off = 8; off; off >>= 1) {
            p0 += __shfl_xor(p0, off, 64);
            p1 += __shfl_xor(p1, off, 64);
        }
        if (a0 && fabsf(p0 - 0.1f) < BL_MARGIN) {
            const float4* fr = (const float4*)(feat32 + (size_t)r0 * 128);
            const float4* fq = (const float4*)(feat32 + (size_t)wid * 128);
            float4 x0 = fr[l * 2], x1 = fr[l * 2 + 1];
            float4 y0 = fq[l * 2], y1 = fq[l * 2 + 1];
            float s2 = x0.x*y0.x + x0.y*y0.y + x0.z*y0.z + x0.w*y0.w
                     + x1.x*y1.x + x1.y*y1.y + x1.z*y1.z + x1.w*y1.w;
            #pragma unroll
            for (int off = 8; off; off >>= 1) s2 += __shfl_xor(s2, off, 64);
            p0 = s2 / (nrm[r0] * nc);
        }
        if (a1 && fabsf(p1 - 0.1f) < BL_MARGIN) {
            const float4* fr = (const float4*)(feat32 + (size_t)r1 * 128);
            const float4* fq = (const float4*)(feat32 + (size_t)wid * 128);
            float4 x0 = fr[l * 2], x1 = fr[l * 2 + 1];
            float4 y0 = fq[l * 2], y1 = fq[l * 2 + 1];
            float s2 = x0.x*y0.x + x0.y*y0.y + x0.z*y0.z + x0.w*y0.w
                     + x1.x*y1.x + x1.y*y1.y + x1.z*y1.z + x1.w*y1.w;
            #pragma unroll
            for (int off = 8; off; off >>= 1) s2 += __shfl_xor(s2, off, 64);
            p1 = s2 / (nrm[r1] * nc);
        }
        if (l == 0) {
            if (a0) {
                float kv = (p0 >= 0.1f) ? p0 : 0.0f;
                sims[s0 + j0] = kv;
                if (kv > 0.0f) atomicAdd(&deg1[r0], kv);
            }
            if (a1) {
                float kv = (p1 >= 0.1f) ? p1 : 0.0f;
                sims[s0 + j1] = kv;
                if (kv > 0.0f) atomicAdd(&deg1[r1], kv);
            }
        }
    }
}

// ---------------- edge phase B: vals + in-wave deg2 + compaction ----------------
__global__ __launch_bounds__(256) void edge_c_csr_k(const float* __restrict__ sims,
    const int* __restrict__ rowAll, const int* __restrict__ startAll,
    const int* __restrict__ cntAll, const float* __restrict__ deg1,
    int2* __restrict__ kv, int* __restrict__ cntK, float* __restrict__ dinv2,
    float* __restrict__ cself, int n) {
    int wid  = (blockIdx.x * 256 + threadIdx.x) >> 6;
    int lane = threadIdx.x & 63;
    if (wid >= n) return;
    int s0 = startAll[wid], cnt = cntAll[wid];
    float degc = deg1[wid];
    float d1c = (degc > 0.0f) ? 1.0f / sqrtf(degc) : 0.0f;
    float vsum = 0.0f; int kc = 0;
    for (int jj = 0; jj < cnt; jj += 64) {
        int j = jj + lane;
        bool keep = false; int r = 0; float v = 0.0f;
        if (j < cnt) {
            float s = sims[s0 + j];
            if (s > 0.0f) {
                r = rowAll[s0 + j];
                float dr = 1.0f / sqrtf(deg1[r]);     // deg1[r] >= s >= 0.1
                v = expf(dr * s * d1c);
                keep = true;
            }
        }
        unsigned long long m = __ballot(keep ? 1 : 0);
        if (keep) {
            int pre = __popcll(m & ((1ull << lane) - 1ull));
            int2 pk; pk.x = r; pk.y = __float_as_int(v);
            kv[s0 + kc + pre] = pk;
            vsum += v;
        }
        kc += __popcll(m);
    }
    #pragma unroll
    for (int off = 32; off; off >>= 1) vsum += __shfl_xor(vsum, off, 64);
    if (lane == 0) {
        float ws_ = expf(1.0f / ((float)kc + 1.0f));   // self-loop weight
        float dg = ws_ + vsum;                         // always > 0
        float di = 1.0f / sqrtf(dg);
        dinv2[wid] = di;
        cself[wid] = di * ws_;      // self term uses dinv2-scaled h, so one di here
        cntK[wid]  = kc;
    }
}

// ---------------- GEMMs (K=128), register-tiled + COLUMN-TILED LDS ----------------
// r8: 64 KiB LDS capped occupancy at 2 blocks/CU (18.6%), VALU 36%. Column tiles
// shrink LDS to 32/16 KiB -> 5/8 blocks per CU. Accumulation order unchanged.

// 64-col tile of W1 in LDS; grid = (nodeTiles, 2). 4 nodes x 4 cols / thread.
__global__ __launch_bounds__(256) void gemm128_k(const float* __restrict__ A,
    const float* __restrict__ W, const float* __restrict__ scale,
    float* __restrict__ out, int n) {
    __shared__ float Ws[128 * 64];
    int colBase = blockIdx.y * 64;
    for (int i = threadIdx.x; i < 128 * 64 / 4; i += 256) {
        int k = i >> 4, c4 = i & 15;
        ((float4*)Ws)[i] = *(const float4*)(W + k * 128 + colBase + c4 * 4);
    }
    __syncthreads();
    const int TPN = 16;
    int group = threadIdx.x / TPN;            // 16 groups -> 64 nodes/block
    int tin   = threadIdx.x % TPN;
    int nid   = (blockIdx.x * 16 + group) * 4;
    if (nid >= n) return;
    int dbase = tin * 4;
    int nm1 = n - 1;
    const float4* a0 = (const float4*)(A + (size_t)min(nid,     nm1) * 128);
    const float4* a1 = (const float4*)(A + (size_t)min(nid + 1, nm1) * 128);
    const float4* a2 = (const float4*)(A + (size_t)min(nid + 2, nm1) * 128);
    const float4* a3 = (const float4*)(A + (size_t)min(nid + 3, nm1) * 128);
    float4 acc0 = {0,0,0,0}, acc1 = {0,0,0,0}, acc2 = {0,0,0,0}, acc3 = {0,0,0,0};
    #pragma unroll 2
    for (int k4 = 0; k4 < 32; ++k4) {
        const float* wr = Ws + (k4 * 4) * 64 + dbase;
        float4 w0 = *(const float4*)(wr);
        float4 w1 = *(const float4*)(wr + 64);
        float4 w2 = *(const float4*)(wr + 128);
        float4 w3 = *(const float4*)(wr + 192);
        float4 v0 = a0[k4], v1 = a1[k4], v2 = a2[k4], v3 = a3[k4];
        acc0.x += v0.x*w0.x + v0.y*w1.x + v0.z*w2.x + v0.w*w3.x;
        acc0.y += v0.x*w0.y + v0.y*w1.y + v0.z*w2.y + v0.w*w3.y;
        acc0.z += v0.x*w0.z + v0.y*w1.z + v0.z*w2.z + v0.w*w3.z;
        acc0.w += v0.x*w0.w + v0.y*w1.w + v0.z*w2.w + v0.w*w3.w;
        acc1.x += v1.x*w0.x + v1.y*w1.x + v1.z*w2.x + v1.w*w3.x;
        acc1.y += v1.x*w0.y + v1.y*w1.y + v1.z*w2.y + v1.w*w3.y;
        acc1.z += v1.x*w0.z + v1.y*w1.z + v1.z*w2.z + v1.w*w3.z;
        acc1.w += v1.x*w0.w + v1.y*w1.w + v1.z*w2.w + v1.w*w3.w;
        acc2.x += v2.x*w0.x + v2.y*w1.x + v2.z*w2.x + v2.w*w3.x;
        acc2.y += v2.x*w0.y + v2.y*w1.y + v2.z*w2.y + v2.w*w3.y;
        acc2.z += v2.x*w0.z + v2.y*w1.z + v2.z*w2.z + v2.w*w3.z;
        acc2.w += v2.x*w0.w + v2.y*w1.w + v2.z*w2.w + v2.w*w3.w;
        acc3.x += v3.x*w0.x + v3.y*w1.x + v3.z*w2.x + v3.w*w3.x;
        acc3.y += v3.x*w0.y + v3.y*w1.y + v3.z*w2.y + v3.w*w3.y;
        acc3.z += v3.x*w0.z + v3.y*w1.z + v3.z*w2.z + v3.w*w3.z;
        acc3.w += v3.x*w0.w + v3.y*w1.w + v3.z*w2.w + v3.w*w3.w;
    }
    float4 accs[4] = {acc0, acc1, acc2, acc3};
    #pragma unroll
    for (int i = 0; i < 4; ++i) {
        if (nid + i < n) {
            float sc = scale[nid + i];
            float4 r; r.x = accs[i].x * sc; r.y = accs[i].y * sc;
            r.z = accs[i].z * sc; r.w = accs[i].w * sc;
            *(float4*)(out + (size_t)(nid + i) * 128 + colBase + dbase) = r;
        }
    }
}

// DOUT=64, fp16 output; 32-col tile of W2 in LDS (16 KiB); grid = (nodeTiles, 2)
__global__ __launch_bounds__(256) void gemm64_hf_k(const float* __restrict__ A,
    const float* __restrict__ W, const float* __restrict__ scale,
    u32* __restrict__ outhf, int n) {
    __shared__ float Ws[128 * 32];
    int colBase = blockIdx.y * 32;
    for (int i = threadIdx.x; i < 128 * 32 / 4; i += 256) {
        int k = i >> 3, c4 = i & 7;
        ((float4*)Ws)[i] = *(const float4*)(W + k * 64 + colBase + c4 * 4);
    }
    __syncthreads();
    const int TPN = 8;
    int group = threadIdx.x / TPN;            // 32 groups -> 128 nodes/block
    int tin   = threadIdx.x % TPN;
    int nid   = (blockIdx.x * 32 + group) * 4;
    if (nid >= n) return;
    int dbase = tin * 4;
    int nm1 = n - 1;
    const float4* a0 = (const float4*)(A + (size_t)min(nid,     nm1) * 128);
    const float4* a1 = (const float4*)(A + (size_t)min(nid + 1, nm1) * 128);
    const float4* a2 = (const float4*)(A + (size_t)min(nid + 2, nm1) * 128);
    const float4* a3 = (const float4*)(A + (size_t)min(nid + 3, nm1) * 128);
    float4 acc0 = {0,0,0,0}, acc1 = {0,0,0,0}, acc2 = {0,0,0,0}, acc3 = {0,0,0,0};
    #pragma unroll 2
    for (int k4 = 0; k4 < 32; ++k4) {
        const float* wr = Ws + (k4 * 4) * 32 + dbase;
        float4 w0 = *(const float4*)(wr);
        float4 w1 = *(const float4*)(wr + 32);
        float4 w2 = *(const float4*)(wr + 64);
        float4 w3 = *(const float4*)(wr + 96);
        float4 v0 = a0[k4], v1 = a1[k4], v2 = a2[k4], v3 = a3[k4];
        acc0.x += v0.x*w0.x + v0.y*w1.x + v0.z*w2.x + v0.w*w3.x;
        acc0.y += v0.x*w0.y + v0.y*w1.y + v0.z*w2.y + v0.w*w3.y;
        acc0.z += v0.x*w0.z + v0.y*w1.z + v0.z*w2.z + v0.w*w3.z;
        acc0.w += v0.x*w0.w + v0.y*w1.w + v0.z*w2.w + v0.w*w3.w;
        acc1.x += v1.x*w0.x + v1.y*w1.x + v1.z*w2.x + v1.w*w3.x;
        acc1.y += v1.x*w0.y + v1.y*w1.y + v1.z*w2.y + v1.w*w3.y;
        acc1.z += v1.x*w0.z + v1.y*w1.z + v1.z*w2.z + v1.w*w3.z;
        acc1.w += v1.x*w0.w + v1.y*w1.w + v1.z*w2.w + v1.w*w3.w;
        acc2.x += v2.x*w0.x + v2.y*w1.x + v2.z*w2.x + v2.w*w3.x;
        acc2.y += v2.x*w0.y + v2.y*w1.y + v2.z*w2.y + v2.w*w3.y;
        acc2.z += v2.x*w0.z + v2.y*w1.z + v2.z*w2.z + v2.w*w3.z;
        acc2.w += v2.x*w0.w + v2.y*w1.w + v2.z*w2.w + v2.w*w3.w;
        acc3.x += v3.x*w0.x + v3.y*w1.x + v3.z*w2.x + v3.w*w3.x;
        acc3.y += v3.x*w0.y + v3.y*w1.y + v3.z*w2.y + v3.w*w3.y;
        acc3.z += v3.x*w0.z + v3.y*w1.z + v3.z*w2.z + v3.w*w3.z;
        acc3.w += v3.x*w0.w + v3.y*w1.w + v3.z*w2.w + v3.w*w3.w;
    }
    float4 accs[4] = {acc0, acc1, acc2, acc3};
    #pragma unroll
    for (int i = 0; i < 4; ++i) {
        if (nid + i < n) {
            float sc = scale[nid + i];
            u32 o0 = pack_h2(accs[i].x * sc, accs[i].y * sc);
            u32 o1 = pack_h2(accs[i].z * sc, accs[i].w * sc);
            *(uint2*)(outhf + (size_t)(nid + i) * 32 + (colBase >> 1) + tin * 2)
                = make_uint2(o0, o1);
        }
    }
}

// ---------------- fused gather epilogues ----------------

// layer 1: x = dinv2[c]*sum(val*hs[row]) + cself*hs[c] + bias; LN; ReLU
__global__ __launch_bounds__(256) void gather_ln_k(const float* __restrict__ hs,
    const int2* __restrict__ kv, const int* __restrict__ startAll,
    const int* __restrict__ cntK, const float* __restrict__ dinv2,
    const float* __restrict__ cself, const float* __restrict__ bias,
    const float* __restrict__ g, const float* __restrict__ bln,
    float* __restrict__ outbuf, u32* __restrict__ outhf,
    float* __restrict__ nrm, int n) {
    int wid  = (blockIdx.x * 256 + threadIdx.x) >> 6;
    int lane = threadIdx.x & 63;
    if (wid >= n) return;
    int s0 = startAll[wid], k = cntK[wid];
    float a0 = 0.f, a1 = 0.f;
    int j = 0;
    for (; j + 7 < k; j += 8) {
        int2 p0 = kv[s0+j],   p1 = kv[s0+j+1], p2 = kv[s0+j+2], p3 = kv[s0+j+3];
        int2 p4 = kv[s0+j+4], p5 = kv[s0+j+5], p6 = kv[s0+j+6], p7 = kv[s0+j+7];
        float2 h0 = *(const float2*)(hs + (size_t)p0.x * 128 + lane * 2);
        float2 h1 = *(const float2*)(hs + (size_t)p1.x * 128 + lane * 2);
        float2 h2v = *(const float2*)(hs + (size_t)p2.x * 128 + lane * 2);
        float2 h3 = *(const float2*)(hs + (size_t)p3.x * 128 + lane * 2);
        float2 h4 = *(const float2*)(hs + (size_t)p4.x * 128 + lane * 2);
        float2 h5 = *(const float2*)(hs + (size_t)p5.x * 128 + lane * 2);
        float2 h6 = *(const float2*)(hs + (size_t)p6.x * 128 + lane * 2);
        float2 h7 = *(const float2*)(hs + (size_t)p7.x * 128 + lane * 2);
        float v0 = __int_as_float(p0.y), v1 = __int_as_float(p1.y);
        float v2 = __int_as_float(p2.y), v3 = __int_as_float(p3.y);
        float v4 = __int_as_float(p4.y), v5 = __int_as_float(p5.y);
        float v6 = __int_as_float(p6.y), v7 = __int_as_float(p7.y);
        a0 += v0*h0.x + v1*h1.x + v2*h2v.x + v3*h3.x
            + v4*h4.x + v5*h5.x + v6*h6.x + v7*h7.x;
        a1 += v0*h0.y + v1*h1.y + v2*h2v.y + v3*h3.y
            + v4*h4.y + v5*h5.y + v6*h6.y + v7*h7.y;
    }
    for (; j < k; ++j) {
        int2 p0 = kv[s0 + j];
        float2 h0 = *(const float2*)(hs + (size_t)p0.x * 128 + lane * 2);
        float v0 = __int_as_float(p0.y);
        a0 += v0 * h0.x; a1 += v0 * h0.y;
    }
    float di = dinv2[wid], cs = cself[wid];
    float2 hsv = *(const float2*)(hs + (size_t)wid * 128 + lane * 2);
    float2 vb  = *(const float2*)(bias + lane * 2);
    float x0 = di * a0 + cs * hsv.x + vb.x;
    float x1 = di * a1 + cs * hsv.y + vb.y;
    float s = x0 + x1;
    #pragma unroll
    for (int off = 32; off; off >>= 1) s += __shfl_xor(s, off, 64);
    float mu = s * (1.0f / 128.0f);
    float d0 = x0 - mu, d1 = x1 - mu;
    float vv = d0 * d0 + d1 * d1;
    #pragma unroll
    for (int off = 32; off; off >>= 1) vv += __shfl_xor(vv, off, 64);
    float rstd = 1.0f / sqrtf(vv * (1.0f / 128.0f) + LN_EPS);
    float2 vg  = *(const float2*)(g + lane * 2);
    float2 vbl = *(const float2*)(bln + lane * 2);
    float y0 = fmaxf(d0 * rstd * vg.x + vbl.x, 0.0f);
    float y1 = fmaxf(d1 * rstd * vg.y + vbl.y, 0.0f);
    *(float2*)(outbuf + (size_t)wid * 128 + lane * 2) = make_float2(y0, y1);
    float ns = y0 * y0 + y1 * y1;
    #pragma unroll
    for (int off = 32; off; off >>= 1) ns += __shfl_xor(ns, off, 64);
    float nv = fmaxf(sqrtf(ns), EPSF);
    float inv = 1.0f / nv;
    outhf[(size_t)wid * 64 + lane] = pack_h2(y0 * inv, y1 * inv);
    if (lane == 0) nrm[wid] = nv;
}

// layer 2: v = dinv2[c]*sum(val*g2s[row]) + cself*g2s[c] + b2; log_softmax
__global__ __launch_bounds__(256) void gather_lsm_hf_k(const u16* __restrict__ g2s,
    const int2* __restrict__ kv, const int* __restrict__ startAll,
    const int* __restrict__ cntK, const float* __restrict__ dinv2,
    const float* __restrict__ cself, const float* __restrict__ b2,
    float* __restrict__ out, int n) {
    int wid  = (blockIdx.x * 256 + threadIdx.x) >> 6;
    int lane = threadIdx.x & 63;
    if (wid >= n) return;
    int s0 = startAll[wid], k = cntK[wid];
    float acc = 0.f;
    int j = 0;
    for (; j + 7 < k; j += 8) {
        int2 p0 = kv[s0+j],   p1 = kv[s0+j+1], p2 = kv[s0+j+2], p3 = kv[s0+j+3];
        int2 p4 = kv[s0+j+4], p5 = kv[s0+j+5], p6 = kv[s0+j+6], p7 = kv[s0+j+7];
        float g0 = h2f(g2s[(size_t)p0.x * 64 + lane]);
        float g1 = h2f(g2s[(size_t)p1.x * 64 + lane]);
        float g2 = h2f(g2s[(size_t)p2.x * 64 + lane]);
        float g3 = h2f(g2s[(size_t)p3.x * 64 + lane]);
        float g4 = h2f(g2s[(size_t)p4.x * 64 + lane]);
        float g5 = h2f(g2s[(size_t)p5.x * 64 + lane]);
        float g6 = h2f(g2s[(size_t)p6.x * 64 + lane]);
        float g7 = h2f(g2s[(size_t)p7.x * 64 + lane]);
        acc += __int_as_float(p0.y)*g0 + __int_as_float(p1.y)*g1
             + __int_as_float(p2.y)*g2 + __int_as_float(p3.y)*g3
             + __int_as_float(p4.y)*g4 + __int_as_float(p5.y)*g5
             + __int_as_float(p6.y)*g6 + __int_as_float(p7.y)*g7;
    }
    for (; j < k; ++j) {
        int2 p0 = kv[s0 + j];
        acc += __int_as_float(p0.y) * h2f(g2s[(size_t)p0.x * 64 + lane]);
    }
    float gs = h2f(g2s[(size_t)wid * 64 + lane]);
    float v = dinv2[wid] * acc + cself[wid] * gs + b2[lane];
    float m = v;
    #pragma unroll
    for (int off = 32; off; off >>= 1) m = fmaxf(m, __shfl_xor(m, off, 64));
    float e = expf(v - m);
    float s = e;
    #pragma unroll
    for (int off = 32; off; off >>= 1) s += __shfl_xor(s, off, 64);
    out[(size_t)wid * 64 + lane] = v - m - logf(s);
}

// ---------------- launch ----------------

extern "C" void kernel_launch(void* const* d_in, const int* in_sizes, int n_in,
                              void* d_out, int out_size, void* d_ws, size_t ws_size,
                              hipStream_t stream) {
    (void)n_in; (void)out_size; (void)ws_size;
    const float* x   = (const float*)d_in[0];
    const int*   row = (const int*)d_in[1];
    const int*   col = (const int*)d_in[2];
    const float* W1  = (const float*)d_in[3];
    const float* b1  = (const float*)d_in[4];
    const float* lng = (const float*)d_in[5];
    const float* lnb = (const float*)d_in[6];
    const float* W2  = (const float*)d_in[7];
    const float* b2  = (const float*)d_in[8];
    float* out = (float*)d_out;

    const int N = in_sizes[0] / 128;
    const int E = in_sizes[1];

    int*   cntAll   = (int*)d_ws;
    int*   startAll = cntAll + N;
    int*   bsum     = startAll + N;            // 512 ints
    float* nrm      = (float*)(bsum + 512);
    float* deg1     = nrm + N;                 // zeroed per layer
    float* dinv2    = deg1 + N;
    float* cself    = dinv2 + N;
    int*   cntK     = (int*)(cself + N);       // CSR-build cursor, then kept counts
    int*   rowAll   = cntK + N;                // [E]
    int2*  kvp      = (int2*)(rowAll + E);     // [E] packed (row, val)
    u32*   fhf      = (u32*)(kvp + E);         // [64N] u32 = [128N] fp16; reused as h2hf
    u16*   g2shf    = (u16*)(fhf + (size_t)64 * N);  // [64N] fp16
    float* big      = (float*)(g2shf + (size_t)64 * N);
    float* sims     = big;                     // [E]  (dead before hs is written)
    float* hs       = big;                     // [128N] layer-1 scaled h
    float* h2       = big + (size_t)128 * N;   // [128N] layer-1 output (persists)

    const int nodeBlocks = (N + 255) / 256;
    const int waveBlocks = (N + 3) / 4;
    const int edgeBlocks = (E + 255) / 256;
    const int scanBlocks = nodeBlocks;         // <= 512 for N <= 131072

    // ---- one-time CSR build (shared by both layers) ----
    hipMemsetAsync(cntAll, 0, (size_t)N * sizeof(int), stream);
    count_k<<<edgeBlocks, 256, 0, stream>>>(col, cntAll, E);
    scan1_k<<<scanBlocks, 256, 0, stream>>>(cntAll, startAll, bsum, N);
    scan2_k<<<1, 512, 0, stream>>>(bsum, scanBlocks);
    scan3_k<<<scanBlocks, 256, 0, stream>>>(startAll, bsum, N);
    hipMemsetAsync(cntK, 0, (size_t)N * sizeof(int), stream);
    fill_k<<<edgeBlocks, 256, 0, stream>>>(row, col, startAll, cntK, rowAll, E);

    // ================= layer 1 =================
    hipMemsetAsync(deg1, 0, (size_t)N * sizeof(float), stream);
    cast_norm_k<<<waveBlocks, 256, 0, stream>>>(x, fhf, nrm, N);
    edge_dot_hf_k<<<waveBlocks, 256, 0, stream>>>(fhf, x, rowAll, startAll, cntAll, nrm,
                                                  sims, deg1, N);
    edge_c_csr_k<<<waveBlocks, 256, 0, stream>>>(sims, rowAll, startAll, cntAll, deg1,
                                                 kvp, cntK, dinv2, cself, N);
    gemm128_k<<<dim3((N + 63) / 64, 2), 256, 0, stream>>>(x, W1, dinv2, hs, N);
    gather_ln_k<<<waveBlocks, 256, 0, stream>>>(hs, kvp, startAll, cntK, dinv2, cself,
                                                b1, lng, lnb, h2, fhf, nrm, N);

    // ================= layer 2 =================
    hipMemsetAsync(deg1, 0, (size_t)N * sizeof(float), stream);
    edge_dot_hf_k<<<waveBlocks, 256, 0, stream>>>(fhf, h2, rowAll, startAll, cntAll, nrm,
                                                  sims, deg1, N);
    edge_c_csr_k<<<waveBlocks, 256, 0, stream>>>(sims, rowAll, startAll, cntAll, deg1,
                                                 kvp, cntK, dinv2, cself, N);
    gemm64_hf_k<<<dim3((N + 127) / 128, 2), 256, 0, stream>>>(h2, W2, dinv2,
                                                              (u32*)g2shf, N);
    gather_lsm_hf_k<<<waveBlocks, 256, 0, stream>>>(g2shf, kvp, startAll, cntK, dinv2,
                                                    cself, b2, out, N);
}

// Round 10
// 705.399 us; speedup vs baseline: 2.1568x; 1.0605x over previous
//
#include <hip/hip_runtime.h>
#include <math.h>

#define EPSF 1e-8f
#define LN_EPS 1e-5f
#define BL_MARGIN 0.002f   // > bound on fp16 unit-vector cosine-sim error (~1.5e-3)

typedef unsigned int  u32;
typedef unsigned short u16;
typedef _Float16 h2_t __attribute__((ext_vector_type(2)));

static __device__ inline u32 pack_h2(float a, float b) {
    h2_t h; h.x = (_Float16)a; h.y = (_Float16)b;
    return __builtin_bit_cast(u32, h);
}
static __device__ inline float h2lo(u32 u) {
    return (float)__builtin_bit_cast(h2_t, u).x;
}
static __device__ inline float h2hi(u32 u) {
    return (float)__builtin_bit_cast(h2_t, u).y;
}
static __device__ inline float fdot2_u32(u32 a, u32 b, float c) {
    return __builtin_amdgcn_fdot2(__builtin_bit_cast(h2_t, a),
                                  __builtin_bit_cast(h2_t, b), c, false);
}

// ---------------- layer-1 prep: norms + UNIT-vector fp16 cast ----------------
__global__ __launch_bounds__(256) void cast_norm_k(const float* __restrict__ feat,
    u32* __restrict__ fhf, float* __restrict__ nrm, int n) {
    int wid  = (blockIdx.x * 256 + threadIdx.x) >> 6;
    int lane = threadIdx.x & 63;
    if (wid >= n) return;
    float2 v = *(const float2*)(feat + (size_t)wid * 128 + lane * 2);
    float s = v.x * v.x + v.y * v.y;
    #pragma unroll
    for (int off = 32; off; off >>= 1) s += __shfl_xor(s, off, 64);
    float nv = fmaxf(sqrtf(s), EPSF);
    float inv = 1.0f / nv;
    fhf[(size_t)wid * 64 + lane] = pack_h2(v.x * inv, v.y * inv);
    if (lane == 0) nrm[wid] = nv;
}

// ---------------- one-time CSR build ----------------

__global__ __launch_bounds__(256) void count_k(const int* __restrict__ col,
                                               int* __restrict__ cntAll, int ecnt) {
    int e = blockIdx.x * 256 + threadIdx.x;
    if (e < ecnt) atomicAdd(&cntAll[col[e]], 1);
}

__global__ __launch_bounds__(256) void scan1_k(const int* __restrict__ cnt,
    int* __restrict__ colStart, int* __restrict__ bsum, int n) {
    __shared__ int tmp[256];
    int i = blockIdx.x * 256 + threadIdx.x;
    int v = (i < n) ? cnt[i] : 0;
    tmp[threadIdx.x] = v; __syncthreads();
    for (int off = 1; off < 256; off <<= 1) {
        int t = (threadIdx.x >= off) ? tmp[threadIdx.x - off] : 0;
        __syncthreads();
        tmp[threadIdx.x] += t;
        __syncthreads();
    }
    if (i < n) colStart[i] = tmp[threadIdx.x] - v;   // exclusive
    if (threadIdx.x == 255) bsum[blockIdx.x] = tmp[255];
}

__global__ __launch_bounds__(512) void scan2_k(int* __restrict__ bsum, int nb) {
    __shared__ int tmp[512];
    int v = (threadIdx.x < nb) ? bsum[threadIdx.x] : 0;
    tmp[threadIdx.x] = v; __syncthreads();
    for (int off = 1; off < 512; off <<= 1) {
        int t = (threadIdx.x >= off) ? tmp[threadIdx.x - off] : 0;
        __syncthreads();
        tmp[threadIdx.x] += t;
        __syncthreads();
    }
    if (threadIdx.x < nb) bsum[threadIdx.x] = tmp[threadIdx.x] - v;  // exclusive
}

__global__ __launch_bounds__(256) void scan3_k(int* __restrict__ colStart,
    const int* __restrict__ bsum, int n) {
    int i = blockIdx.x * 256 + threadIdx.x;
    if (i < n) colStart[i] += bsum[blockIdx.x];
}

__global__ __launch_bounds__(256) void fill_k(const int* __restrict__ row,
    const int* __restrict__ col, const int* __restrict__ startAll,
    int* __restrict__ cur, int* __restrict__ rowAll, int ecnt) {
    int e = blockIdx.x * 256 + threadIdx.x;
    if (e >= ecnt) return;
    int c = col[e];
    int p = startAll[c] + atomicAdd(&cur[c], 1);
    rowAll[p] = row[e];
}

// ---------------- edge phase A: fp16 unit sims, 16 edges in flight per wave -----
// one wave per col node; 4 edges per 16-lane group (avg in-degree is 16, so one
// iteration covers a typical segment). Borderline edges recomputed inline in fp32.
__global__ __launch_bounds__(256) void edge_dot_hf_k(const u32* __restrict__ fhf,
    const float* __restrict__ feat32,
    const int* __restrict__ rowAll, const int* __restrict__ startAll,
    const int* __restrict__ cntAll, const float* __restrict__ nrm,
    float* __restrict__ sims, float* __restrict__ deg1, int n) {
    int wid  = (blockIdx.x * 256 + threadIdx.x) >> 6;
    int lane = threadIdx.x & 63;
    if (wid >= n) return;
    int s0 = startAll[wid], cnt = cntAll[wid];
    if (cnt == 0) return;
    int q = lane >> 4, l = lane & 15;
    uint4 fc = *(const uint4*)(fhf + (size_t)wid * 64 + l * 4);
    float nc = nrm[wid];
    int cm1 = cnt - 1;
    for (int jj = 0; jj < cnt; jj += 16) {
        int j0 = jj + q, j1 = j0 + 4, j2 = j0 + 8, j3 = j0 + 12;
        bool a0 = j0 < cnt, a1 = j1 < cnt, a2 = j2 < cnt, a3 = j3 < cnt;
        int r0 = rowAll[s0 + min(j0, cm1)];
        int r1 = rowAll[s0 + min(j1, cm1)];
        int r2 = rowAll[s0 + min(j2, cm1)];
        int r3 = rowAll[s0 + min(j3, cm1)];
        uint4 f0 = *(const uint4*)(fhf + (size_t)r0 * 64 + l * 4);
        uint4 f1 = *(const uint4*)(fhf + (size_t)r1 * 64 + l * 4);
        uint4 f2 = *(const uint4*)(fhf + (size_t)r2 * 64 + l * 4);
        uint4 f3 = *(const uint4*)(fhf + (size_t)r3 * 64 + l * 4);
        float p0 = fdot2_u32(f0.x, fc.x, 0.0f);
        float p1 = fdot2_u32(f1.x, fc.x, 0.0f);
        float p2 = fdot2_u32(f2.x, fc.x, 0.0f);
        float p3 = fdot2_u32(f3.x, fc.x, 0.0f);
        p0 = fdot2_u32(f0.y, fc.y, p0); p1 = fdot2_u32(f1.y, fc.y, p1);
        p2 = fdot2_u32(f2.y, fc.y, p2); p3 = fdot2_u32(f3.y, fc.y, p3);
        p0 = fdot2_u32(f0.z, fc.z, p0); p1 = fdot2_u32(f1.z, fc.z, p1);
        p2 = fdot2_u32(f2.z, fc.z, p2); p3 = fdot2_u32(f3.z, fc.z, p3);
        p0 = fdot2_u32(f0.w, fc.w, p0); p1 = fdot2_u32(f1.w, fc.w, p1);
        p2 = fdot2_u32(f2.w, fc.w, p2); p3 = fdot2_u32(f3.w, fc.w, p3);
        #pragma unroll
        for (int off = 8; off; off >>= 1) {
            p0 += __shfl_xor(p0, off, 64);
            p1 += __shfl_xor(p1, off, 64);
            p2 += __shfl_xor(p2, off, 64);
            p3 += __shfl_xor(p3, off, 64);
        }
        // rare fp32 recheck for borderline sims
        if (a0 && fabsf(p0 - 0.1f) < BL_MARGIN) {
            const float4* fr = (const float4*)(feat32 + (size_t)r0 * 128);
            const float4* fq = (const float4*)(feat32 + (size_t)wid * 128);
            float4 x0 = fr[l*2], x1 = fr[l*2+1], y0 = fq[l*2], y1 = fq[l*2+1];
            float s2 = x0.x*y0.x + x0.y*y0.y + x0.z*y0.z + x0.w*y0.w
                     + x1.x*y1.x + x1.y*y1.y + x1.z*y1.z + x1.w*y1.w;
            #pragma unroll
            for (int off = 8; off; off >>= 1) s2 += __shfl_xor(s2, off, 64);
            p0 = s2 / (nrm[r0] * nc);
        }
        if (a1 && fabsf(p1 - 0.1f) < BL_MARGIN) {
            const float4* fr = (const float4*)(feat32 + (size_t)r1 * 128);
            const float4* fq = (const float4*)(feat32 + (size_t)wid * 128);
            float4 x0 = fr[l*2], x1 = fr[l*2+1], y0 = fq[l*2], y1 = fq[l*2+1];
            float s2 = x0.x*y0.x + x0.y*y0.y + x0.z*y0.z + x0.w*y0.w
                     + x1.x*y1.x + x1.y*y1.y + x1.z*y1.z + x1.w*y1.w;
            #pragma unroll
            for (int off = 8; off; off >>= 1) s2 += __shfl_xor(s2, off, 64);
            p1 = s2 / (nrm[r1] * nc);
        }
        if (a2 && fabsf(p2 - 0.1f) < BL_MARGIN) {
            const float4* fr = (const float4*)(feat32 + (size_t)r2 * 128);
            const float4* fq = (const float4*)(feat32 + (size_t)wid * 128);
            float4 x0 = fr[l*2], x1 = fr[l*2+1], y0 = fq[l*2], y1 = fq[l*2+1];
            float s2 = x0.x*y0.x + x0.y*y0.y + x0.z*y0.z + x0.w*y0.w
                     + x1.x*y1.x + x1.y*y1.y + x1.z*y1.z + x1.w*y1.w;
            #pragma unroll
            for (int off = 8; off; off >>= 1) s2 += __shfl_xor(s2, off, 64);
            p2 = s2 / (nrm[r2] * nc);
        }
        if (a3 && fabsf(p3 - 0.1f) < BL_MARGIN) {
            const float4* fr = (const float4*)(feat32 + (size_t)r3 * 128);
            const float4* fq = (const float4*)(feat32 + (size_t)wid * 128);
            float4 x0 = fr[l*2], x1 = fr[l*2+1], y0 = fq[l*2], y1 = fq[l*2+1];
            float s2 = x0.x*y0.x + x0.y*y0.y + x0.z*y0.z + x0.w*y0.w
                     + x1.x*y1.x + x1.y*y1.y + x1.z*y1.z + x1.w*y1.w;
            #pragma unroll
            for (int off = 8; off; off >>= 1) s2 += __shfl_xor(s2, off, 64);
            p3 = s2 / (nrm[r3] * nc);
        }
        if (l == 0) {
            if (a0) {
                float kv = (p0 >= 0.1f) ? p0 : 0.0f;
                sims[s0 + j0] = kv;
                if (kv > 0.0f) atomicAdd(&deg1[r0], kv);
            }
            if (a1) {
                float kv = (p1 >= 0.1f) ? p1 : 0.0f;
                sims[s0 + j1] = kv;
                if (kv > 0.0f) atomicAdd(&deg1[r1], kv);
            }
            if (a2) {
                float kv = (p2 >= 0.1f) ? p2 : 0.0f;
                sims[s0 + j2] = kv;
                if (kv > 0.0f) atomicAdd(&deg1[r2], kv);
            }
            if (a3) {
                float kv = (p3 >= 0.1f) ? p3 : 0.0f;
                sims[s0 + j3] = kv;
                if (kv > 0.0f) atomicAdd(&deg1[r3], kv);
            }
        }
    }
}

// ---------------- edge phase B: vals + in-wave deg2 + compaction ----------------
__global__ __launch_bounds__(256) void edge_c_csr_k(const float* __restrict__ sims,
    const int* __restrict__ rowAll, const int* __restrict__ startAll,
    const int* __restrict__ cntAll, const float* __restrict__ deg1,
    int2* __restrict__ kv, int* __restrict__ cntK, float* __restrict__ dinv2,
    float* __restrict__ cself, int n) {
    int wid  = (blockIdx.x * 256 + threadIdx.x) >> 6;
    int lane = threadIdx.x & 63;
    if (wid >= n) return;
    int s0 = startAll[wid], cnt = cntAll[wid];
    float degc = deg1[wid];
    float d1c = (degc > 0.0f) ? 1.0f / sqrtf(degc) : 0.0f;
    float vsum = 0.0f; int kc = 0;
    for (int jj = 0; jj < cnt; jj += 64) {
        int j = jj + lane;
        bool keep = false; int r = 0; float v = 0.0f;
        if (j < cnt) {
            float s = sims[s0 + j];
            if (s > 0.0f) {
                r = rowAll[s0 + j];
                float dr = 1.0f / sqrtf(deg1[r]);     // deg1[r] >= s >= 0.1
                v = expf(dr * s * d1c);
                keep = true;
            }
        }
        unsigned long long m = __ballot(keep ? 1 : 0);
        if (keep) {
            int pre = __popcll(m & ((1ull << lane) - 1ull));
            int2 pk; pk.x = r; pk.y = __float_as_int(v);
            kv[s0 + kc + pre] = pk;
            vsum += v;
        }
        kc += __popcll(m);
    }
    #pragma unroll
    for (int off = 32; off; off >>= 1) vsum += __shfl_xor(vsum, off, 64);
    if (lane == 0) {
        float ws_ = expf(1.0f / ((float)kc + 1.0f));   // self-loop weight
        float dg = ws_ + vsum;                         // always > 0
        float di = 1.0f / sqrtf(dg);
        dinv2[wid] = di;
        cself[wid] = di * ws_;      // self term uses dinv2-scaled h, so one di here
        cntK[wid]  = kc;
    }
}

// ---------------- GEMMs (K=128), register-tiled + column-tiled LDS ----------------

// 64-col tile of W1 in LDS (32 KiB); grid = (nodeTiles, 2). 4 nodes x 4 cols / thread.
__global__ __launch_bounds__(256) void gemm128_k(const float* __restrict__ A,
    const float* __restrict__ W, const float* __restrict__ scale,
    float* __restrict__ out, int n) {
    __shared__ float Ws[128 * 64];
    int colBase = blockIdx.y * 64;
    for (int i = threadIdx.x; i < 128 * 64 / 4; i += 256) {
        int k = i >> 4, c4 = i & 15;
        ((float4*)Ws)[i] = *(const float4*)(W + k * 128 + colBase + c4 * 4);
    }
    __syncthreads();
    const int TPN = 16;
    int group = threadIdx.x / TPN;            // 16 groups -> 64 nodes/block
    int tin   = threadIdx.x % TPN;
    int nid   = (blockIdx.x * 16 + group) * 4;
    if (nid >= n) return;
    int dbase = tin * 4;
    int nm1 = n - 1;
    const float4* a0 = (const float4*)(A + (size_t)min(nid,     nm1) * 128);
    const float4* a1 = (const float4*)(A + (size_t)min(nid + 1, nm1) * 128);
    const float4* a2 = (const float4*)(A + (size_t)min(nid + 2, nm1) * 128);
    const float4* a3 = (const float4*)(A + (size_t)min(nid + 3, nm1) * 128);
    float4 acc0 = {0,0,0,0}, acc1 = {0,0,0,0}, acc2 = {0,0,0,0}, acc3 = {0,0,0,0};
    #pragma unroll 2
    for (int k4 = 0; k4 < 32; ++k4) {
        const float* wr = Ws + (k4 * 4) * 64 + dbase;
        float4 w0 = *(const float4*)(wr);
        float4 w1 = *(const float4*)(wr + 64);
        float4 w2 = *(const float4*)(wr + 128);
        float4 w3 = *(const float4*)(wr + 192);
        float4 v0 = a0[k4], v1 = a1[k4], v2 = a2[k4], v3 = a3[k4];
        acc0.x += v0.x*w0.x + v0.y*w1.x + v0.z*w2.x + v0.w*w3.x;
        acc0.y += v0.x*w0.y + v0.y*w1.y + v0.z*w2.y + v0.w*w3.y;
        acc0.z += v0.x*w0.z + v0.y*w1.z + v0.z*w2.z + v0.w*w3.z;
        acc0.w += v0.x*w0.w + v0.y*w1.w + v0.z*w2.w + v0.w*w3.w;
        acc1.x += v1.x*w0.x + v1.y*w1.x + v1.z*w2.x + v1.w*w3.x;
        acc1.y += v1.x*w0.y + v1.y*w1.y + v1.z*w2.y + v1.w*w3.y;
        acc1.z += v1.x*w0.z + v1.y*w1.z + v1.z*w2.z + v1.w*w3.z;
        acc1.w += v1.x*w0.w + v1.y*w1.w + v1.z*w2.w + v1.w*w3.w;
        acc2.x += v2.x*w0.x + v2.y*w1.x + v2.z*w2.x + v2.w*w3.x;
        acc2.y += v2.x*w0.y + v2.y*w1.y + v2.z*w2.y + v2.w*w3.y;
        acc2.z += v2.x*w0.z + v2.y*w1.z + v2.z*w2.z + v2.w*w3.z;
        acc2.w += v2.x*w0.w + v2.y*w1.w + v2.z*w2.w + v2.w*w3.w;
        acc3.x += v3.x*w0.x + v3.y*w1.x + v3.z*w2.x + v3.w*w3.x;
        acc3.y += v3.x*w0.y + v3.y*w1.y + v3.z*w2.y + v3.w*w3.y;
        acc3.z += v3.x*w0.z + v3.y*w1.z + v3.z*w2.z + v3.w*w3.z;
        acc3.w += v3.x*w0.w + v3.y*w1.w + v3.z*w2.w + v3.w*w3.w;
    }
    float4 accs[4] = {acc0, acc1, acc2, acc3};
    #pragma unroll
    for (int i = 0; i < 4; ++i) {
        if (nid + i < n) {
            float sc = scale[nid + i];
            float4 r; r.x = accs[i].x * sc; r.y = accs[i].y * sc;
            r.z = accs[i].z * sc; r.w = accs[i].w * sc;
            *(float4*)(out + (size_t)(nid + i) * 128 + colBase + dbase) = r;
        }
    }
}

// DOUT=64, fp16 output; 32-col tile of W2 in LDS (16 KiB); grid = (nodeTiles, 2)
__global__ __launch_bounds__(256) void gemm64_hf_k(const float* __restrict__ A,
    const float* __restrict__ W, const float* __restrict__ scale,
    u32* __restrict__ outhf, int n) {
    __shared__ float Ws[128 * 32];
    int colBase = blockIdx.y * 32;
    for (int i = threadIdx.x; i < 128 * 32 / 4; i += 256) {
        int k = i >> 3, c4 = i & 7;
        ((float4*)Ws)[i] = *(const float4*)(W + k * 64 + colBase + c4 * 4);
    }
    __syncthreads();
    const int TPN = 8;
    int group = threadIdx.x / TPN;            // 32 groups -> 128 nodes/block
    int tin   = threadIdx.x % TPN;
    int nid   = (blockIdx.x * 32 + group) * 4;
    if (nid >= n) return;
    int dbase = tin * 4;
    int nm1 = n - 1;
    const float4* a0 = (const float4*)(A + (size_t)min(nid,     nm1) * 128);
    const float4* a1 = (const float4*)(A + (size_t)min(nid + 1, nm1) * 128);
    const float4* a2 = (const float4*)(A + (size_t)min(nid + 2, nm1) * 128);
    const float4* a3 = (const float4*)(A + (size_t)min(nid + 3, nm1) * 128);
    float4 acc0 = {0,0,0,0}, acc1 = {0,0,0,0}, acc2 = {0,0,0,0}, acc3 = {0,0,0,0};
    #pragma unroll 2
    for (int k4 = 0; k4 < 32; ++k4) {
        const float* wr = Ws + (k4 * 4) * 32 + dbase;
        float4 w0 = *(const float4*)(wr);
        float4 w1 = *(const float4*)(wr + 32);
        float4 w2 = *(const float4*)(wr + 64);
        float4 w3 = *(const float4*)(wr + 96);
        float4 v0 = a0[k4], v1 = a1[k4], v2 = a2[k4], v3 = a3[k4];
        acc0.x += v0.x*w0.x + v0.y*w1.x + v0.z*w2.x + v0.w*w3.x;
        acc0.y += v0.x*w0.y + v0.y*w1.y + v0.z*w2.y + v0.w*w3.y;
        acc0.z += v0.x*w0.z + v0.y*w1.z + v0.z*w2.z + v0.w*w3.z;
        acc0.w += v0.x*w0.w + v0.y*w1.w + v0.z*w2.w + v0.w*w3.w;
        acc1.x += v1.x*w0.x + v1.y*w1.x + v1.z*w2.x + v1.w*w3.x;
        acc1.y += v1.x*w0.y + v1.y*w1.y + v1.z*w2.y + v1.w*w3.y;
        acc1.z += v1.x*w0.z + v1.y*w1.z + v1.z*w2.z + v1.w*w3.z;
        acc1.w += v1.x*w0.w + v1.y*w1.w + v1.z*w2.w + v1.w*w3.w;
        acc2.x += v2.x*w0.x + v2.y*w1.x + v2.z*w2.x + v2.w*w3.x;
        acc2.y += v2.x*w0.y + v2.y*w1.y + v2.z*w2.y + v2.w*w3.y;
        acc2.z += v2.x*w0.z + v2.y*w1.z + v2.z*w2.z + v2.w*w3.z;
        acc2.w += v2.x*w0.w + v2.y*w1.w + v2.z*w2.w + v2.w*w3.w;
        acc3.x += v3.x*w0.x + v3.y*w1.x + v3.z*w2.x + v3.w*w3.x;
        acc3.y += v3.x*w0.y + v3.y*w1.y + v3.z*w2.y + v3.w*w3.y;
        acc3.z += v3.x*w0.z + v3.y*w1.z + v3.z*w2.z + v3.w*w3.z;
        acc3.w += v3.x*w0.w + v3.y*w1.w + v3.z*w2.w + v3.w*w3.w;
    }
    float4 accs[4] = {acc0, acc1, acc2, acc3};
    #pragma unroll
    for (int i = 0; i < 4; ++i) {
        if (nid + i < n) {
            float sc = scale[nid + i];
            u32 o0 = pack_h2(accs[i].x * sc, accs[i].y * sc);
            u32 o1 = pack_h2(accs[i].z * sc, accs[i].w * sc);
            *(uint2*)(outhf + (size_t)(nid + i) * 32 + (colBase >> 1) + tin * 2)
                = make_uint2(o0, o1);
        }
    }
}

// ---------------- fused gather epilogues (half-wave per node) ----------------

// layer 1: half-wave (32 lanes) per node, float4 (4 dims) per lane.
// x = dinv2[c]*sum(val*hs[row]) + cself*hs[c] + bias; LN; ReLU
__global__ __launch_bounds__(256) void gather_ln_k(const float* __restrict__ hs,
    const int2* __restrict__ kv, const int* __restrict__ startAll,
    const int* __restrict__ cntK, const float* __restrict__ dinv2,
    const float* __restrict__ cself, const float* __restrict__ bias,
    const float* __restrict__ g, const float* __restrict__ bln,
    float* __restrict__ outbuf, u32* __restrict__ outhf,
    float* __restrict__ nrm, int n) {
    int wid = (blockIdx.x * 256 + threadIdx.x) >> 5;
    int l   = threadIdx.x & 31;
    if (wid >= n) return;
    int s0 = startAll[wid], k = cntK[wid];
    float4 acc = {0,0,0,0};
    int j = 0;
    for (; j + 7 < k; j += 8) {
        int2 p0 = kv[s0+j],   p1 = kv[s0+j+1], p2 = kv[s0+j+2], p3 = kv[s0+j+3];
        int2 p4 = kv[s0+j+4], p5 = kv[s0+j+5], p6 = kv[s0+j+6], p7 = kv[s0+j+7];
        float4 h0 = *(const float4*)(hs + (size_t)p0.x * 128 + l * 4);
        float4 h1 = *(const float4*)(hs + (size_t)p1.x * 128 + l * 4);
        float4 h2v = *(const float4*)(hs + (size_t)p2.x * 128 + l * 4);
        float4 h3 = *(const float4*)(hs + (size_t)p3.x * 128 + l * 4);
        float4 h4 = *(const float4*)(hs + (size_t)p4.x * 128 + l * 4);
        float4 h5 = *(const float4*)(hs + (size_t)p5.x * 128 + l * 4);
        float4 h6 = *(const float4*)(hs + (size_t)p6.x * 128 + l * 4);
        float4 h7 = *(const float4*)(hs + (size_t)p7.x * 128 + l * 4);
        float v0 = __int_as_float(p0.y), v1 = __int_as_float(p1.y);
        float v2 = __int_as_float(p2.y), v3 = __int_as_float(p3.y);
        float v4 = __int_as_float(p4.y), v5 = __int_as_float(p5.y);
        float v6 = __int_as_float(p6.y), v7 = __int_as_float(p7.y);
        acc.x += v0*h0.x + v1*h1.x + v2*h2v.x + v3*h3.x
               + v4*h4.x + v5*h5.x + v6*h6.x + v7*h7.x;
        acc.y += v0*h0.y + v1*h1.y + v2*h2v.y + v3*h3.y
               + v4*h4.y + v5*h5.y + v6*h6.y + v7*h7.y;
        acc.z += v0*h0.z + v1*h1.z + v2*h2v.z + v3*h3.z
               + v4*h4.z + v5*h5.z + v6*h6.z + v7*h7.z;
        acc.w += v0*h0.w + v1*h1.w + v2*h2v.w + v3*h3.w
               + v4*h4.w + v5*h5.w + v6*h6.w + v7*h7.w;
    }
    for (; j < k; ++j) {
        int2 p0 = kv[s0 + j];
        float4 h0 = *(const float4*)(hs + (size_t)p0.x * 128 + l * 4);
        float v0 = __int_as_float(p0.y);
        acc.x += v0*h0.x; acc.y += v0*h0.y; acc.z += v0*h0.z; acc.w += v0*h0.w;
    }
    float di = dinv2[wid], cs = cself[wid];
    float4 hsv = *(const float4*)(hs + (size_t)wid * 128 + l * 4);
    float4 vb  = *(const float4*)(bias + l * 4);
    float x0 = di*acc.x + cs*hsv.x + vb.x;
    float x1 = di*acc.y + cs*hsv.y + vb.y;
    float x2 = di*acc.z + cs*hsv.z + vb.z;
    float x3 = di*acc.w + cs*hsv.w + vb.w;
    float s = x0 + x1 + x2 + x3;
    #pragma unroll
    for (int off = 16; off; off >>= 1) s += __shfl_xor(s, off, 64);
    float mu = s * (1.0f / 128.0f);
    float d0 = x0 - mu, d1 = x1 - mu, d2 = x2 - mu, d3 = x3 - mu;
    float vv = d0*d0 + d1*d1 + d2*d2 + d3*d3;
    #pragma unroll
    for (int off = 16; off; off >>= 1) vv += __shfl_xor(vv, off, 64);
    float rstd = 1.0f / sqrtf(vv * (1.0f / 128.0f) + LN_EPS);
    float4 vg  = *(const float4*)(g + l * 4);
    float4 vbl = *(const float4*)(bln + l * 4);
    float y0 = fmaxf(d0 * rstd * vg.x + vbl.x, 0.0f);
    float y1 = fmaxf(d1 * rstd * vg.y + vbl.y, 0.0f);
    float y2 = fmaxf(d2 * rstd * vg.z + vbl.z, 0.0f);
    float y3 = fmaxf(d3 * rstd * vg.w + vbl.w, 0.0f);
    float4 yo; yo.x = y0; yo.y = y1; yo.z = y2; yo.w = y3;
    *(float4*)(outbuf + (size_t)wid * 128 + l * 4) = yo;
    float ns = y0*y0 + y1*y1 + y2*y2 + y3*y3;
    #pragma unroll
    for (int off = 16; off; off >>= 1) ns += __shfl_xor(ns, off, 64);
    float nv = fmaxf(sqrtf(ns), EPSF);
    float inv = 1.0f / nv;
    uint2 oh; oh.x = pack_h2(y0 * inv, y1 * inv); oh.y = pack_h2(y2 * inv, y3 * inv);
    *(uint2*)(outhf + (size_t)wid * 64 + l * 2) = oh;
    if (l == 0) nrm[wid] = nv;
}

// layer 2: half-wave per node, 2 dims (u32) per lane.
// v = dinv2[c]*sum(val*g2s[row]) + cself*g2s[c] + b2; log_softmax
__global__ __launch_bounds__(256) void gather_lsm_hf_k(const u32* __restrict__ g2s,
    const int2* __restrict__ kv, const int* __restrict__ startAll,
    const int* __restrict__ cntK, const float* __restrict__ dinv2,
    const float* __restrict__ cself, const float* __restrict__ b2,
    float* __restrict__ out, int n) {
    int wid = (blockIdx.x * 256 + threadIdx.x) >> 5;
    int l   = threadIdx.x & 31;
    if (wid >= n) return;
    int s0 = startAll[wid], k = cntK[wid];
    float acc0 = 0.f, acc1 = 0.f;
    int j = 0;
    for (; j + 7 < k; j += 8) {
        int2 p0 = kv[s0+j],   p1 = kv[s0+j+1], p2 = kv[s0+j+2], p3 = kv[s0+j+3];
        int2 p4 = kv[s0+j+4], p5 = kv[s0+j+5], p6 = kv[s0+j+6], p7 = kv[s0+j+7];
        u32 g0 = g2s[(size_t)p0.x * 32 + l];
        u32 g1 = g2s[(size_t)p1.x * 32 + l];
        u32 g2 = g2s[(size_t)p2.x * 32 + l];
        u32 g3 = g2s[(size_t)p3.x * 32 + l];
        u32 g4 = g2s[(size_t)p4.x * 32 + l];
        u32 g5 = g2s[(size_t)p5.x * 32 + l];
        u32 g6 = g2s[(size_t)p6.x * 32 + l];
        u32 g7 = g2s[(size_t)p7.x * 32 + l];
        float v0 = __int_as_float(p0.y), v1 = __int_as_float(p1.y);
        float v2 = __int_as_float(p2.y), v3 = __int_as_float(p3.y);
        float v4 = __int_as_float(p4.y), v5 = __int_as_float(p5.y);
        float v6 = __int_as_float(p6.y), v7 = __int_as_float(p7.y);
        acc0 += v0*h2lo(g0) + v1*h2lo(g1) + v2*h2lo(g2) + v3*h2lo(g3)
              + v4*h2lo(g4) + v5*h2lo(g5) + v6*h2lo(g6) + v7*h2lo(g7);
        acc1 += v0*h2hi(g0) + v1*h2hi(g1) + v2*h2hi(g2) + v3*h2hi(g3)
              + v4*h2hi(g4) + v5*h2hi(g5) + v6*h2hi(g6) + v7*h2hi(g7);
    }
    for (; j < k; ++j) {
        int2 p0 = kv[s0 + j];
        u32 g0 = g2s[(size_t)p0.x * 32 + l];
        float v0 = __int_as_float(p0.y);
        acc0 += v0 * h2lo(g0); acc1 += v0 * h2hi(g0);
    }
    float di = dinv2[wid], cs = cself[wid];
    u32 gsu = g2s[(size_t)wid * 32 + l];
    float2 vb = *(const float2*)(b2 + l * 2);
    float v0 = di * acc0 + cs * h2lo(gsu) + vb.x;
    float v1 = di * acc1 + cs * h2hi(gsu) + vb.y;
    float m = fmaxf(v0, v1);
    #pragma unroll
    for (int off = 16; off; off >>= 1) m = fmaxf(m, __shfl_xor(m, off, 64));
    float e = expf(v0 - m) + expf(v1 - m);
    #pragma unroll
    for (int off = 16; off; off >>= 1) e += __shfl_xor(e, off, 64);
    float lse = m + logf(e);
    *(float2*)(out + (size_t)wid * 64 + l * 2) = make_float2(v0 - lse, v1 - lse);
}

// ---------------- launch ----------------

extern "C" void kernel_launch(void* const* d_in, const int* in_sizes, int n_in,
                              void* d_out, int out_size, void* d_ws, size_t ws_size,
                              hipStream_t stream) {
    (void)n_in; (void)out_size; (void)ws_size;
    const float* x   = (const float*)d_in[0];
    const int*   row = (const int*)d_in[1];
    const int*   col = (const int*)d_in[2];
    const float* W1  = (const float*)d_in[3];
    const float* b1  = (const float*)d_in[4];
    const float* lng = (const float*)d_in[5];
    const float* lnb = (const float*)d_in[6];
    const float* W2  = (const float*)d_in[7];
    const float* b2  = (const float*)d_in[8];
    float* out = (float*)d_out;

    const int N = in_sizes[0] / 128;
    const int E = in_sizes[1];

    int*   cntAll   = (int*)d_ws;
    int*   startAll = cntAll + N;
    int*   bsum     = startAll + N;            // 512 ints
    float* nrm      = (float*)(bsum + 512);
    float* deg1     = nrm + N;                 // zeroed per layer
    float* dinv2    = deg1 + N;
    float* cself    = dinv2 + N;
    int*   cntK     = (int*)(cself + N);       // CSR-build cursor, then kept counts
    int*   rowAll   = cntK + N;                // [E]
    int2*  kvp      = (int2*)(rowAll + E);     // [E] packed (row, val)
    u32*   fhf      = (u32*)(kvp + E);         // [64N] u32 = [128N] fp16; reused as h2hf
    u32*   g2shf    = fhf + (size_t)64 * N;    // [32N] u32 = [64N] fp16
    float* big      = (float*)(g2shf + (size_t)32 * N);
    float* sims     = big;                     // [E]  (dead before hs is written)
    float* hs       = big;                     // [128N] layer-1 scaled h
    float* h2       = big + (size_t)128 * N;   // [128N] layer-1 output (persists)

    const int nodeBlocks  = (N + 255) / 256;
    const int waveBlocks  = (N + 3) / 4;       // 1 wave/node
    const int halfBlocks  = (N + 7) / 8;       // half-wave/node
    const int edgeBlocks  = (E + 255) / 256;
    const int scanBlocks  = nodeBlocks;        // <= 512 for N <= 131072

    // ---- one-time CSR build (shared by both layers) ----
    hipMemsetAsync(cntAll, 0, (size_t)N * sizeof(int), stream);
    count_k<<<edgeBlocks, 256, 0, stream>>>(col, cntAll, E);
    scan1_k<<<scanBlocks, 256, 0, stream>>>(cntAll, startAll, bsum, N);
    scan2_k<<<1, 512, 0, stream>>>(bsum, scanBlocks);
    scan3_k<<<scanBlocks, 256, 0, stream>>>(startAll, bsum, N);
    hipMemsetAsync(cntK, 0, (size_t)N * sizeof(int), stream);
    fill_k<<<edgeBlocks, 256, 0, stream>>>(row, col, startAll, cntK, rowAll, E);

    // ================= layer 1 =================
    hipMemsetAsync(deg1, 0, (size_t)N * sizeof(float), stream);
    cast_norm_k<<<waveBlocks, 256, 0, stream>>>(x, fhf, nrm, N);
    edge_dot_hf_k<<<waveBlocks, 256, 0, stream>>>(fhf, x, rowAll, startAll, cntAll, nrm,
                                                  sims, deg1, N);
    edge_c_csr_k<<<waveBlocks, 256, 0, stream>>>(sims, rowAll, startAll, cntAll, deg1,
                                                 kvp, cntK, dinv2, cself, N);
    gemm128_k<<<dim3((N + 63) / 64, 2), 256, 0, stream>>>(x, W1, dinv2, hs, N);
    gather_ln_k<<<halfBlocks, 256, 0, stream>>>(hs, kvp, startAll, cntK, dinv2, cself,
                                                b1, lng, lnb, h2, fhf, nrm, N);

    // ================= layer 2 =================
    hipMemsetAsync(deg1, 0, (size_t)N * sizeof(float), stream);
    edge_dot_hf_k<<<waveBlocks, 256, 0, stream>>>(fhf, h2, rowAll, startAll, cntAll, nrm,
                                                  sims, deg1, N);
    edge_c_csr_k<<<waveBlocks, 256, 0, stream>>>(sims, rowAll, startAll, cntAll, deg1,
                                                 kvp, cntK, dinv2, cself, N);
    gemm64_hf_k<<<dim3((N + 127) / 128, 2), 256, 0, stream>>>(h2, W2, dinv2, g2shf, N);
    gather_lsm_hf_k<<<halfBlocks, 256, 0, stream>>>(g2shf, kvp, startAll, cntK, dinv2,
                                                    cself, b2, out, N);
}